// Round 1
// baseline (4563.792 us; speedup 1.0000x reference)
//
#include <hip/hip_runtime.h>

#define N_NODES 50000
#define N_REL 4
#define N_EDGES 400000

// ---------------------------------------------------------------------------
// Degree counting: cnt_out[r][n] = #edges with src==n, cnt_in[r][n] = #dst==n
// ---------------------------------------------------------------------------
__global__ __launch_bounds__(256) void k_degree(const int* __restrict__ src,
                                                const int* __restrict__ dst,
                                                int* __restrict__ cnt_out,
                                                int* __restrict__ cnt_in) {
  int idx = blockIdx.x * 256 + threadIdx.x;
  if (idx >= N_REL * N_EDGES) return;
  int r = idx / N_EDGES;
  int s = src[idx];
  int d = dst[idx];
  atomicAdd(&cnt_out[r * N_NODES + s], 1);
  atomicAdd(&cnt_in[r * N_NODES + d], 1);
}

// In-place: int count -> float rsqrt(max(count,1))
__global__ __launch_bounds__(256) void k_rsqrt(int* __restrict__ buf, int n) {
  int i = blockIdx.x * 256 + threadIdx.x;
  if (i >= n) return;
  int c = buf[i];
  if (c < 1) c = 1;
  float f = rsqrtf((float)c);
  ((float*)buf)[i] = f;
}

// ---------------------------------------------------------------------------
// C[M,NCOLS] = A[M,128] @ W[128,NCOLS], fp32, W staged in LDS.
// 256 threads/block, 64 rows/block, 8 cols/thread.
// ---------------------------------------------------------------------------
template <int NCOLS>
__global__ __launch_bounds__(256) void k_gemm(const float* __restrict__ A,
                                              const float* __restrict__ W,
                                              float* __restrict__ C, int M) {
  __shared__ float Wlds[128 * NCOLS];
  for (int i = threadIdx.x; i < 128 * NCOLS; i += 256) Wlds[i] = W[i];
  __syncthreads();

  constexpr int CG = NCOLS / 8;    // col groups of 8
  constexpr int RPP = 256 / CG;    // rows per pass
  const int cg = threadIdx.x % CG;
  const int r0 = threadIdx.x / CG;
  const int rowBase = blockIdx.x * 64;

  for (int pass = 0; pass < 64 / RPP; ++pass) {
    const int row = rowBase + pass * RPP + r0;
    if (row >= M) continue;
    float acc[8];
#pragma unroll
    for (int j = 0; j < 8; ++j) acc[j] = 0.f;

    const float4* A4 = reinterpret_cast<const float4*>(A + (size_t)row * 128);
#pragma unroll 4
    for (int k4 = 0; k4 < 32; ++k4) {
      float4 a = A4[k4];
#pragma unroll
      for (int kk = 0; kk < 4; ++kk) {
        float av = (&a.x)[kk];
        const float* wr = &Wlds[(k4 * 4 + kk) * NCOLS + cg * 8];
#pragma unroll
        for (int j = 0; j < 8; ++j) acc[j] = fmaf(av, wr[j], acc[j]);
      }
    }
    float4* c4 = reinterpret_cast<float4*>(C + (size_t)row * NCOLS + cg * 8);
    c4[0] = make_float4(acc[0], acc[1], acc[2], acc[3]);
    c4[1] = make_float4(acc[4], acc[5], acc[6], acc[7]);
  }
}

// ---------------------------------------------------------------------------
// Edge scatter: out[dst] += Y[src] * dso[src] * dsi[dst]
// FQ = features/4 (32 for 128-f, 16 for 64-f). One float4 per thread.
// ---------------------------------------------------------------------------
template <int FQ>
__global__ __launch_bounds__(256) void k_edge_scatter(
    const float* __restrict__ Y, const float* __restrict__ dso,
    const float* __restrict__ dsi, const int* __restrict__ src,
    const int* __restrict__ dst, float* __restrict__ out) {
  int idx = blockIdx.x * 256 + threadIdx.x;
  if (idx >= N_EDGES * FQ) return;
  int e = idx / FQ;
  int fq = idx % FQ;
  int s = src[e];
  int d = dst[e];
  float w = dso[s] * dsi[d];
  float4 y = reinterpret_cast<const float4*>(Y)[s * FQ + fq];
  float* o = out + (size_t)d * (FQ * 4) + fq * 4;
  atomicAdd(o + 0, y.x * w);
  atomicAdd(o + 1, y.y * w);
  atomicAdd(o + 2, y.z * w);
  atomicAdd(o + 3, y.w * w);
}

// ---------------------------------------------------------------------------
// h[i] += sum_r b[r][f]; optional ReLU
// ---------------------------------------------------------------------------
template <int F, bool RELU>
__global__ __launch_bounds__(256) void k_bias(float* __restrict__ h,
                                              const float* __restrict__ b,
                                              int n) {
  int i = blockIdx.x * 256 + threadIdx.x;
  if (i >= n) return;
  int f = i % F;
  float v = h[i] + b[f] + b[F + f] + b[2 * F + f] + b[3 * F + f];
  if (RELU) v = fmaxf(v, 0.f);
  h[i] = v;
}

extern "C" void kernel_launch(void* const* d_in, const int* in_sizes, int n_in,
                              void* d_out, int out_size, void* d_ws,
                              size_t ws_size, hipStream_t stream) {
  const float* x  = (const float*)d_in[0];   // [N_NODES,128]
  const int* src  = (const int*)d_in[1];     // [4,N_EDGES]
  const int* dst  = (const int*)d_in[2];     // [4,N_EDGES]
  const float* W1 = (const float*)d_in[3];   // [4,128,128]
  const float* b1 = (const float*)d_in[4];   // [4,128]
  const float* W2 = (const float*)d_in[5];   // [4,128,64]
  const float* b2 = (const float*)d_in[6];   // [4,64]
  float* out = (float*)d_out;                // [N_NODES,64]

  // Workspace layout (floats):
  //   dso [4*N_NODES] | dsi [4*N_NODES] | Y [N_NODES*128] | h1 [N_NODES*128]
  float* ws = (float*)d_ws;
  float* dso = ws;
  float* dsi = ws + 4 * N_NODES;
  float* Y = ws + 8 * N_NODES;
  float* h1 = Y + (size_t)N_NODES * 128;

  hipMemsetAsync(dso, 0, (size_t)8 * N_NODES * sizeof(int), stream);
  hipMemsetAsync(h1, 0, (size_t)N_NODES * 128 * sizeof(float), stream);
  hipMemsetAsync(out, 0, (size_t)N_NODES * 64 * sizeof(float), stream);

  k_degree<<<(N_REL * N_EDGES + 255) / 256, 256, 0, stream>>>(
      src, dst, (int*)dso, (int*)dsi);
  k_rsqrt<<<(8 * N_NODES + 255) / 256, 256, 0, stream>>>((int*)dso,
                                                         8 * N_NODES);

  // Layer 1: h1 = sum_r scatter(x @ W1[r])
  for (int r = 0; r < N_REL; ++r) {
    k_gemm<128><<<(N_NODES + 63) / 64, 256, 0, stream>>>(
        x, W1 + (size_t)r * 128 * 128, Y, N_NODES);
    k_edge_scatter<32><<<(N_EDGES * 32) / 256, 256, 0, stream>>>(
        Y, dso + r * N_NODES, dsi + r * N_NODES, src + r * N_EDGES,
        dst + r * N_EDGES, h1);
  }
  k_bias<128, true><<<(N_NODES * 128 + 255) / 256, 256, 0, stream>>>(
      h1, b1, N_NODES * 128);

  // Layer 2: out = sum_r scatter(h1 @ W2[r])
  for (int r = 0; r < N_REL; ++r) {
    k_gemm<64><<<(N_NODES + 63) / 64, 256, 0, stream>>>(
        h1, W2 + (size_t)r * 128 * 64, Y, N_NODES);
    k_edge_scatter<16><<<(N_EDGES * 16) / 256, 256, 0, stream>>>(
        Y, dso + r * N_NODES, dsi + r * N_NODES, src + r * N_EDGES,
        dst + r * N_EDGES, out);
  }
  k_bias<64, false><<<(N_NODES * 64 + 255) / 256, 256, 0, stream>>>(
      out, b2, N_NODES * 64);
}

// Round 2
// 927.865 us; speedup vs baseline: 4.9186x; 4.9186x over previous
//
#include <hip/hip_runtime.h>

#define N_NODES 50000
#define N_REL 4
#define N_EDGES 400000
#define CHUNK 1024
#define NCHUNK ((N_NODES + CHUNK - 1) / CHUNK)  // 49

// ---------------------------------------------------------------------------
// Degree counting: cnt_out[r][n] = #src==n, cnt_in[r][n] = #dst==n (ints)
// ---------------------------------------------------------------------------
__global__ __launch_bounds__(256) void k_degree(const int* __restrict__ src,
                                                const int* __restrict__ dst,
                                                int* __restrict__ cnt_out,
                                                int* __restrict__ cnt_in) {
  int idx = blockIdx.x * 256 + threadIdx.x;
  if (idx >= N_REL * N_EDGES) return;
  int r = idx / N_EDGES;
  atomicAdd(&cnt_out[r * N_NODES + src[idx]], 1);
  atomicAdd(&cnt_in[r * N_NODES + dst[idx]], 1);
}

// ---------------------------------------------------------------------------
// Scan stage 1: per-(relation,chunk) sums of cnt_in
// ---------------------------------------------------------------------------
__global__ __launch_bounds__(256) void k_chunk_sums(
    const int* __restrict__ cnt_in, int* __restrict__ chunkSums) {
  int r = blockIdx.x / NCHUNK;
  int c = blockIdx.x % NCHUNK;
  int t = threadIdx.x;
  int base = c * CHUNK + t * 4;
  int s = 0;
#pragma unroll
  for (int j = 0; j < 4; ++j) {
    int n = base + j;
    if (n < N_NODES) s += cnt_in[r * N_NODES + n];
  }
  __shared__ int lds[256];
  lds[t] = s;
  __syncthreads();
  for (int off = 128; off > 0; off >>= 1) {
    if (t < off) lds[t] += lds[t + off];
    __syncthreads();
  }
  if (t == 0) chunkSums[r * 64 + c] = lds[0];
}

// ---------------------------------------------------------------------------
// Scan stage 2: exclusive scan of chunk sums (tiny, serial per relation)
// ---------------------------------------------------------------------------
__global__ __launch_bounds__(64) void k_scan_chunks(int* __restrict__ chunkSums,
                                                    int* __restrict__ row_ptr) {
  int t = threadIdx.x;
  if (t < N_REL) {
    int running = 0;
    for (int c = 0; c < NCHUNK; ++c) {
      int v = chunkSums[t * 64 + c];
      chunkSums[t * 64 + c] = running;
      running += v;
    }
    row_ptr[t * (N_NODES + 1) + N_NODES] = N_EDGES;
  }
}

// ---------------------------------------------------------------------------
// Scan stage 3: within-chunk exclusive scan -> row_ptr and cursor
// ---------------------------------------------------------------------------
__global__ __launch_bounds__(256) void k_scan_within(
    const int* __restrict__ cnt_in, const int* __restrict__ chunkOff,
    int* __restrict__ row_ptr, int* __restrict__ cursor) {
  int r = blockIdx.x / NCHUNK;
  int c = blockIdx.x % NCHUNK;
  int t = threadIdx.x;
  int base = c * CHUNK + t * 4;
  int v[4];
#pragma unroll
  for (int j = 0; j < 4; ++j) {
    int n = base + j;
    v[j] = (n < N_NODES) ? cnt_in[r * N_NODES + n] : 0;
  }
  int total = v[0] + v[1] + v[2] + v[3];
  __shared__ int lds[256];
  lds[t] = total;
  __syncthreads();
  // Hillis-Steele inclusive scan over 256 thread totals
  for (int off = 1; off < 256; off <<= 1) {
    int add = (t >= off) ? lds[t - off] : 0;
    __syncthreads();
    lds[t] += add;
    __syncthreads();
  }
  int thrExcl = lds[t] - total + chunkOff[r * 64 + c];
  int pre = 0;
#pragma unroll
  for (int j = 0; j < 4; ++j) {
    int n = base + j;
    if (n < N_NODES) {
      int val = thrExcl + pre;
      row_ptr[r * (N_NODES + 1) + n] = val;
      cursor[r * N_NODES + n] = val;
    }
    pre += v[j];
  }
}

// In-place: int count -> float rsqrt(max(count,1))
__global__ __launch_bounds__(256) void k_rsqrt(int* __restrict__ buf, int n) {
  int i = blockIdx.x * 256 + threadIdx.x;
  if (i >= n) return;
  int c = buf[i];
  if (c < 1) c = 1;
  ((float*)buf)[i] = rsqrtf((float)c);
}

// ---------------------------------------------------------------------------
// Bucket fill: sorted_src[r][row_ptr[d] + k] = src of k-th edge into d
// ---------------------------------------------------------------------------
__global__ __launch_bounds__(256) void k_fill(const int* __restrict__ src,
                                              const int* __restrict__ dst,
                                              int* __restrict__ cursor,
                                              int* __restrict__ sorted_src) {
  int idx = blockIdx.x * 256 + threadIdx.x;
  if (idx >= N_REL * N_EDGES) return;
  int r = idx / N_EDGES;
  int d = dst[idx];
  int pos = atomicAdd(&cursor[r * N_NODES + d], 1);
  sorted_src[r * N_EDGES + pos] = src[idx];
}

// ---------------------------------------------------------------------------
// C[M,NCOLS] = (A[M,128] @ W[128,NCOLS]) * dso[row], fp32, W in LDS.
// ---------------------------------------------------------------------------
template <int NCOLS>
__global__ __launch_bounds__(256) void k_gemm(const float* __restrict__ A,
                                              const float* __restrict__ W,
                                              const float* __restrict__ dso,
                                              float* __restrict__ C, int M) {
  __shared__ float Wlds[128 * NCOLS];
  for (int i = threadIdx.x; i < 128 * NCOLS; i += 256) Wlds[i] = W[i];
  __syncthreads();

  constexpr int CG = NCOLS / 8;
  constexpr int RPP = 256 / CG;
  const int cg = threadIdx.x % CG;
  const int r0 = threadIdx.x / CG;
  const int rowBase = blockIdx.x * 64;

  for (int pass = 0; pass < 64 / RPP; ++pass) {
    const int row = rowBase + pass * RPP + r0;
    if (row >= M) continue;
    float acc[8];
#pragma unroll
    for (int j = 0; j < 8; ++j) acc[j] = 0.f;

    const float4* A4 = reinterpret_cast<const float4*>(A + (size_t)row * 128);
#pragma unroll 4
    for (int k4 = 0; k4 < 32; ++k4) {
      float4 a = A4[k4];
#pragma unroll
      for (int kk = 0; kk < 4; ++kk) {
        float av = (&a.x)[kk];
        const float* wr = &Wlds[(k4 * 4 + kk) * NCOLS + cg * 8];
#pragma unroll
        for (int j = 0; j < 8; ++j) acc[j] = fmaf(av, wr[j], acc[j]);
      }
    }
    float sc = dso[row];
    float4* c4 = reinterpret_cast<float4*>(C + (size_t)row * NCOLS + cg * 8);
    c4[0] = make_float4(acc[0] * sc, acc[1] * sc, acc[2] * sc, acc[3] * sc);
    c4[1] = make_float4(acc[4] * sc, acc[5] * sc, acc[6] * sc, acc[7] * sc);
  }
}

// ---------------------------------------------------------------------------
// Gather-aggregate: out[d] += dsi[d] * sum_{e in seg(d)} Y[src_e]
// One wave (64 lanes) per destination node. F = 128 (float2/lane) or 64.
// ---------------------------------------------------------------------------
template <int F>
__global__ __launch_bounds__(256) void k_gather(
    const float* __restrict__ Y, const int* __restrict__ row_ptr,
    const int* __restrict__ sorted_src, const float* __restrict__ dsi,
    float* __restrict__ out) {
  int wave = threadIdx.x >> 6;
  int lane = threadIdx.x & 63;
  int node = blockIdx.x * 4 + wave;
  if (node >= N_NODES) return;
  int beg = row_ptr[node];
  int end = row_ptr[node + 1];
  if (beg == end) return;
  float w = dsi[node];

  if (F == 128) {
    const float2* Y2 = reinterpret_cast<const float2*>(Y);
    float2 a0 = make_float2(0.f, 0.f), a1 = make_float2(0.f, 0.f);
    int e = beg;
    for (; e + 1 < end; e += 2) {
      int s0 = sorted_src[e], s1 = sorted_src[e + 1];
      float2 y0 = Y2[(size_t)s0 * 64 + lane];
      float2 y1 = Y2[(size_t)s1 * 64 + lane];
      a0.x += y0.x; a0.y += y0.y;
      a1.x += y1.x; a1.y += y1.y;
    }
    if (e < end) {
      int s = sorted_src[e];
      float2 y = Y2[(size_t)s * 64 + lane];
      a0.x += y.x; a0.y += y.y;
    }
    float2* O = reinterpret_cast<float2*>(out) + (size_t)node * 64 + lane;
    float2 cur = *O;
    cur.x += (a0.x + a1.x) * w;
    cur.y += (a0.y + a1.y) * w;
    *O = cur;
  } else {
    float a0 = 0.f, a1 = 0.f;
    int e = beg;
    for (; e + 1 < end; e += 2) {
      int s0 = sorted_src[e], s1 = sorted_src[e + 1];
      a0 += Y[(size_t)s0 * 64 + lane];
      a1 += Y[(size_t)s1 * 64 + lane];
    }
    if (e < end) a0 += Y[(size_t)sorted_src[e] * 64 + lane];
    float* O = out + (size_t)node * 64 + lane;
    *O = *O + (a0 + a1) * w;
  }
}

// ---------------------------------------------------------------------------
// h[i] += sum_r b[r][f]; optional ReLU
// ---------------------------------------------------------------------------
template <int F, bool RELU>
__global__ __launch_bounds__(256) void k_bias(float* __restrict__ h,
                                              const float* __restrict__ b,
                                              int n) {
  int i = blockIdx.x * 256 + threadIdx.x;
  if (i >= n) return;
  int f = i % F;
  float v = h[i] + b[f] + b[F + f] + b[2 * F + f] + b[3 * F + f];
  if (RELU) v = fmaxf(v, 0.f);
  h[i] = v;
}

extern "C" void kernel_launch(void* const* d_in, const int* in_sizes, int n_in,
                              void* d_out, int out_size, void* d_ws,
                              size_t ws_size, hipStream_t stream) {
  const float* x  = (const float*)d_in[0];
  const int* src  = (const int*)d_in[1];
  const int* dst  = (const int*)d_in[2];
  const float* W1 = (const float*)d_in[3];
  const float* b1 = (const float*)d_in[4];
  const float* W2 = (const float*)d_in[5];
  const float* b2 = (const float*)d_in[6];
  float* out = (float*)d_out;

  // Workspace layout (4-byte units):
  char* ws = (char*)d_ws;
  int*   cnt_out   = (int*)ws;                          // 4*N_NODES
  int*   cnt_in    = cnt_out + 4 * N_NODES;             // 4*N_NODES
  int*   row_ptr   = cnt_in + 4 * N_NODES;              // 4*(N_NODES+1)
  int*   cursor    = row_ptr + 4 * (N_NODES + 1);       // 4*N_NODES
  int*   chunkSums = cursor + 4 * N_NODES;              // 4*64
  int*   sorted    = chunkSums + 4 * 64;                // 4*N_EDGES
  float* Y         = (float*)(sorted + 4 * N_EDGES);    // N_NODES*128
  float* h1        = Y + (size_t)N_NODES * 128;         // N_NODES*128
  float* dso       = (float*)cnt_out;  // after k_rsqrt, in place
  float* dsi       = (float*)cnt_in;

  hipMemsetAsync(cnt_out, 0, (size_t)8 * N_NODES * sizeof(int), stream);
  hipMemsetAsync(h1, 0, (size_t)N_NODES * 128 * sizeof(float), stream);
  hipMemsetAsync(out, 0, (size_t)N_NODES * 64 * sizeof(float), stream);

  k_degree<<<(N_REL * N_EDGES + 255) / 256, 256, 0, stream>>>(src, dst,
                                                              cnt_out, cnt_in);
  k_chunk_sums<<<N_REL * NCHUNK, 256, 0, stream>>>(cnt_in, chunkSums);
  k_scan_chunks<<<1, 64, 0, stream>>>(chunkSums, row_ptr);
  k_scan_within<<<N_REL * NCHUNK, 256, 0, stream>>>(cnt_in, chunkSums, row_ptr,
                                                    cursor);
  k_rsqrt<<<(8 * N_NODES + 255) / 256, 256, 0, stream>>>(cnt_out,
                                                         8 * N_NODES);
  k_fill<<<(N_REL * N_EDGES + 255) / 256, 256, 0, stream>>>(src, dst, cursor,
                                                            sorted);

  // Layer 1
  for (int r = 0; r < N_REL; ++r) {
    k_gemm<128><<<(N_NODES + 63) / 64, 256, 0, stream>>>(
        x, W1 + (size_t)r * 128 * 128, dso + r * N_NODES, Y, N_NODES);
    k_gather<128><<<(N_NODES + 3) / 4, 256, 0, stream>>>(
        Y, row_ptr + r * (N_NODES + 1), sorted + r * N_EDGES,
        dsi + r * N_NODES, h1);
  }
  k_bias<128, true><<<(N_NODES * 128 + 255) / 256, 256, 0, stream>>>(
      h1, b1, N_NODES * 128);

  // Layer 2
  for (int r = 0; r < N_REL; ++r) {
    k_gemm<64><<<(N_NODES + 63) / 64, 256, 0, stream>>>(
        h1, W2 + (size_t)r * 128 * 64, dso + r * N_NODES, Y, N_NODES);
    k_gather<64><<<(N_NODES + 3) / 4, 256, 0, stream>>>(
        Y, row_ptr + r * (N_NODES + 1), sorted + r * N_EDGES,
        dsi + r * N_NODES, out);
  }
  k_bias<64, false><<<(N_NODES * 64 + 255) / 256, 256, 0, stream>>>(
      out, b2, N_NODES * 64);
}

// Round 3
// 682.270 us; speedup vs baseline: 6.6891x; 1.3600x over previous
//
#include <hip/hip_runtime.h>

#define N_NODES 50000
#define N_REL 4
#define N_EDGES 400000
#define CHUNK 1024
#define NCHUNK ((N_NODES + CHUNK - 1) / CHUNK)  // 49

// ---------------------------------------------------------------------------
// Degree counting
// ---------------------------------------------------------------------------
__global__ __launch_bounds__(256) void k_degree(const int* __restrict__ src,
                                                const int* __restrict__ dst,
                                                int* __restrict__ cnt_out,
                                                int* __restrict__ cnt_in) {
  int idx = blockIdx.x * 256 + threadIdx.x;
  if (idx >= N_REL * N_EDGES) return;
  int r = idx / N_EDGES;
  atomicAdd(&cnt_out[r * N_NODES + src[idx]], 1);
  atomicAdd(&cnt_in[r * N_NODES + dst[idx]], 1);
}

// ---------------------------------------------------------------------------
// Scan stage 1: per-(relation,chunk) sums of cnt_in
// ---------------------------------------------------------------------------
__global__ __launch_bounds__(256) void k_chunk_sums(
    const int* __restrict__ cnt_in, int* __restrict__ chunkSums) {
  int r = blockIdx.x / NCHUNK;
  int c = blockIdx.x % NCHUNK;
  int t = threadIdx.x;
  int base = c * CHUNK + t * 4;
  int s = 0;
#pragma unroll
  for (int j = 0; j < 4; ++j) {
    int n = base + j;
    if (n < N_NODES) s += cnt_in[r * N_NODES + n];
  }
  __shared__ int lds[256];
  lds[t] = s;
  __syncthreads();
  for (int off = 128; off > 0; off >>= 1) {
    if (t < off) lds[t] += lds[t + off];
    __syncthreads();
  }
  if (t == 0) chunkSums[r * 64 + c] = lds[0];
}

// ---------------------------------------------------------------------------
// Scan stage 2: exclusive scan of chunk sums
// ---------------------------------------------------------------------------
__global__ __launch_bounds__(64) void k_scan_chunks(int* __restrict__ chunkSums,
                                                    int* __restrict__ row_ptr) {
  int t = threadIdx.x;
  if (t < N_REL) {
    int running = 0;
    for (int c = 0; c < NCHUNK; ++c) {
      int v = chunkSums[t * 64 + c];
      chunkSums[t * 64 + c] = running;
      running += v;
    }
    row_ptr[t * (N_NODES + 1) + N_NODES] = N_EDGES;
  }
}

// ---------------------------------------------------------------------------
// Scan stage 3: within-chunk exclusive scan -> row_ptr and cursor
// ---------------------------------------------------------------------------
__global__ __launch_bounds__(256) void k_scan_within(
    const int* __restrict__ cnt_in, const int* __restrict__ chunkOff,
    int* __restrict__ row_ptr, int* __restrict__ cursor) {
  int r = blockIdx.x / NCHUNK;
  int c = blockIdx.x % NCHUNK;
  int t = threadIdx.x;
  int base = c * CHUNK + t * 4;
  int v[4];
#pragma unroll
  for (int j = 0; j < 4; ++j) {
    int n = base + j;
    v[j] = (n < N_NODES) ? cnt_in[r * N_NODES + n] : 0;
  }
  int total = v[0] + v[1] + v[2] + v[3];
  __shared__ int lds[256];
  lds[t] = total;
  __syncthreads();
  for (int off = 1; off < 256; off <<= 1) {
    int add = (t >= off) ? lds[t - off] : 0;
    __syncthreads();
    lds[t] += add;
    __syncthreads();
  }
  int thrExcl = lds[t] - total + chunkOff[r * 64 + c];
  int pre = 0;
#pragma unroll
  for (int j = 0; j < 4; ++j) {
    int n = base + j;
    if (n < N_NODES) {
      int val = thrExcl + pre;
      row_ptr[r * (N_NODES + 1) + n] = val;
      cursor[r * N_NODES + n] = val;
    }
    pre += v[j];
  }
}

// In-place: int count -> float rsqrt(max(count,1))
__global__ __launch_bounds__(256) void k_rsqrt(int* __restrict__ buf, int n) {
  int i = blockIdx.x * 256 + threadIdx.x;
  if (i >= n) return;
  int c = buf[i];
  if (c < 1) c = 1;
  ((float*)buf)[i] = rsqrtf((float)c);
}

// ---------------------------------------------------------------------------
// Bucket fill
// ---------------------------------------------------------------------------
__global__ __launch_bounds__(256) void k_fill(const int* __restrict__ src,
                                              const int* __restrict__ dst,
                                              int* __restrict__ cursor,
                                              int* __restrict__ sorted_src) {
  int idx = blockIdx.x * 256 + threadIdx.x;
  if (idx >= N_REL * N_EDGES) return;
  int r = idx / N_EDGES;
  int d = dst[idx];
  int pos = atomicAdd(&cursor[r * N_NODES + d], 1);
  sorted_src[r * N_EDGES + pos] = src[idx];
}

// ---------------------------------------------------------------------------
// Fused multi-relation GEMM: C[row][c] = (A[row] . W[r][:,cc]) * dso[r][row]
// where c = r*REL_COLS + cc, NC = REL_COLS*NRELS = 256.
// Block: 64 rows x 256 cols, 256 threads, 8x8 register tile per thread.
// ---------------------------------------------------------------------------
template <int REL_COLS, int NRELS>
__global__ __launch_bounds__(256, 4) void k_gemm_fused(
    const float* __restrict__ A, const float* __restrict__ Wbase,
    const float* __restrict__ dsoBase, float* __restrict__ C, int M) {
  constexpr int NC = REL_COLS * NRELS;  // 256
  __shared__ float At[32][64];
  __shared__ float Wc[32][NC];
  const int tid = threadIdx.x;
  const int rg = tid >> 5;  // row group 0..7
  const int cg = tid & 31;  // col group 0..31
  const int rowBase = blockIdx.x * 64;

  float acc[8][8];
#pragma unroll
  for (int i = 0; i < 8; ++i)
#pragma unroll
    for (int j = 0; j < 8; ++j) acc[i][j] = 0.f;

  for (int k0 = 0; k0 < 128; k0 += 32) {
    __syncthreads();
    // stage A^T chunk: At[kk][row], kk in [0,32), row in [0,64)
    {
      int i = tid;
#pragma unroll
      for (int rep = 0; rep < 2; ++rep, i += 256) {
        int row = i >> 3, fp = i & 7;
        float4 a = make_float4(0.f, 0.f, 0.f, 0.f);
        int grow = rowBase + row;
        if (grow < M)
          a = *(const float4*)(A + (size_t)grow * 128 + k0 + fp * 4);
        At[fp * 4 + 0][row] = a.x;
        At[fp * 4 + 1][row] = a.y;
        At[fp * 4 + 2][row] = a.z;
        At[fp * 4 + 3][row] = a.w;
      }
    }
    // stage W chunk: Wc[kk][c], c = r*REL_COLS + cc
    {
#pragma unroll
      for (int rep = 0; rep < 8; ++rep) {
        int i = tid + rep * 256;  // 2048 float4 jobs
        int k = i >> 6;
        int c = (i & 63) << 2;
        int r = c / REL_COLS;
        int cc = c % REL_COLS;
        float4 w = *(const float4*)(Wbase + (size_t)r * 128 * REL_COLS +
                                    (size_t)(k0 + k) * REL_COLS + cc);
        *(float4*)&Wc[k][c] = w;
      }
    }
    __syncthreads();
#pragma unroll 8
    for (int kk = 0; kk < 32; ++kk) {
      float4 a0 = *(const float4*)&At[kk][rg * 8];
      float4 a1 = *(const float4*)&At[kk][rg * 8 + 4];
      float4 w0 = *(const float4*)&Wc[kk][cg * 8];
      float4 w1 = *(const float4*)&Wc[kk][cg * 8 + 4];
      float a[8] = {a0.x, a0.y, a0.z, a0.w, a1.x, a1.y, a1.z, a1.w};
      float w[8] = {w0.x, w0.y, w0.z, w0.w, w1.x, w1.y, w1.z, w1.w};
#pragma unroll
      for (int i = 0; i < 8; ++i)
#pragma unroll
        for (int j = 0; j < 8; ++j) acc[i][j] = fmaf(a[i], w[j], acc[i][j]);
    }
  }
  const int rsel = (cg * 8) / REL_COLS;
  const float* dso = dsoBase + (size_t)rsel * N_NODES;
#pragma unroll
  for (int i = 0; i < 8; ++i) {
    int row = rowBase + rg * 8 + i;
    if (row >= M) break;
    float s = dso[row];
    float* cp = C + (size_t)row * NC + cg * 8;
    *(float4*)cp =
        make_float4(acc[i][0] * s, acc[i][1] * s, acc[i][2] * s, acc[i][3] * s);
    *(float4*)(cp + 4) =
        make_float4(acc[i][4] * s, acc[i][5] * s, acc[i][6] * s, acc[i][7] * s);
  }
}

// ---------------------------------------------------------------------------
// Gather layer 1 (2 relations per pass; pass 1 adds bias+ReLU, single write)
// Y layout [node][2][128]; one wave per node, float2 per lane.
// ---------------------------------------------------------------------------
__global__ __launch_bounds__(256) void k_gather1(
    const float* __restrict__ Y, const int* __restrict__ row_ptr,
    const int* __restrict__ sorted, const float* __restrict__ dsi,
    const float* __restrict__ b1, float* __restrict__ h1, int pass) {
  int wave = threadIdx.x >> 6, lane = threadIdx.x & 63;
  int node = blockIdx.x * 4 + wave;
  if (node >= N_NODES) return;
  const float2* Y2 = (const float2*)Y;
  float2 tot = make_float2(0.f, 0.f);
#pragma unroll
  for (int rp = 0; rp < 2; ++rp) {
    int beg = row_ptr[rp * (N_NODES + 1) + node];
    int end = row_ptr[rp * (N_NODES + 1) + node + 1];
    const int* ss = sorted + (size_t)rp * N_EDGES;
    float2 a0 = make_float2(0.f, 0.f), a1 = make_float2(0.f, 0.f);
    int e = beg;
    for (; e + 1 < end; e += 2) {
      int s0 = ss[e], s1 = ss[e + 1];
      float2 y0 = Y2[((size_t)s0 * 2 + rp) * 64 + lane];
      float2 y1 = Y2[((size_t)s1 * 2 + rp) * 64 + lane];
      a0.x += y0.x; a0.y += y0.y;
      a1.x += y1.x; a1.y += y1.y;
    }
    if (e < end) {
      float2 y = Y2[((size_t)ss[e] * 2 + rp) * 64 + lane];
      a0.x += y.x; a0.y += y.y;
    }
    float w = dsi[rp * N_NODES + node];
    tot.x += (a0.x + a1.x) * w;
    tot.y += (a0.y + a1.y) * w;
  }
  float2* H = (float2*)h1 + (size_t)node * 64 + lane;
  if (pass == 0) {
    *H = tot;
  } else {
    const float2* B = (const float2*)b1;
    float2 b = make_float2(0.f, 0.f);
#pragma unroll
    for (int r = 0; r < 4; ++r) {
      float2 bb = B[r * 64 + lane];
      b.x += bb.x; b.y += bb.y;
    }
    float2 cur = *H;
    float vx = cur.x + tot.x + b.x;
    float vy = cur.y + tot.y + b.y;
    *H = make_float2(fmaxf(vx, 0.f), fmaxf(vy, 0.f));
  }
}

// ---------------------------------------------------------------------------
// Gather layer 2 (all 4 relations, + bias, single write). Y [node][4][64].
// ---------------------------------------------------------------------------
__global__ __launch_bounds__(256) void k_gather2(
    const float* __restrict__ Y, const int* __restrict__ row_ptr,
    const int* __restrict__ sorted, const float* __restrict__ dsi,
    const float* __restrict__ b2, float* __restrict__ out) {
  int wave = threadIdx.x >> 6, lane = threadIdx.x & 63;
  int node = blockIdx.x * 4 + wave;
  if (node >= N_NODES) return;
  float tot = 0.f;
#pragma unroll
  for (int r = 0; r < 4; ++r) {
    int beg = row_ptr[r * (N_NODES + 1) + node];
    int end = row_ptr[r * (N_NODES + 1) + node + 1];
    const int* ss = sorted + (size_t)r * N_EDGES;
    float a0 = 0.f, a1 = 0.f;
    int e = beg;
    for (; e + 1 < end; e += 2) {
      int s0 = ss[e], s1 = ss[e + 1];
      a0 += Y[((size_t)s0 * 4 + r) * 64 + lane];
      a1 += Y[((size_t)s1 * 4 + r) * 64 + lane];
    }
    if (e < end) a0 += Y[((size_t)ss[e] * 4 + r) * 64 + lane];
    tot += (a0 + a1) * dsi[r * N_NODES + node];
  }
  float b = b2[lane] + b2[64 + lane] + b2[128 + lane] + b2[192 + lane];
  out[(size_t)node * 64 + lane] = tot + b;
}

extern "C" void kernel_launch(void* const* d_in, const int* in_sizes, int n_in,
                              void* d_out, int out_size, void* d_ws,
                              size_t ws_size, hipStream_t stream) {
  const float* x  = (const float*)d_in[0];
  const int* src  = (const int*)d_in[1];
  const int* dst  = (const int*)d_in[2];
  const float* W1 = (const float*)d_in[3];
  const float* b1 = (const float*)d_in[4];
  const float* W2 = (const float*)d_in[5];
  const float* b2 = (const float*)d_in[6];
  float* out = (float*)d_out;

  // Workspace (4-byte units):
  int*   cnt_out   = (int*)d_ws;                        // 4*N_NODES
  int*   cnt_in    = cnt_out + 4 * N_NODES;             // 4*N_NODES
  int*   row_ptr   = cnt_in + 4 * N_NODES;              // 4*(N_NODES+1)
  int*   cursor    = row_ptr + 4 * (N_NODES + 1);       // 4*N_NODES
  int*   chunkSums = cursor + 4 * N_NODES;              // 256
  int*   sorted    = chunkSums + 256;                   // 4*N_EDGES
  float* Y         = (float*)(sorted + 4 * N_EDGES);    // N_NODES*256 (51.2MB)
  float* h1        = Y + (size_t)N_NODES * 256;         // N_NODES*128 (25.6MB)
  float* dso       = (float*)cnt_out;
  float* dsi       = (float*)cnt_in;

  hipMemsetAsync(cnt_out, 0, (size_t)8 * N_NODES * sizeof(int), stream);

  k_degree<<<(N_REL * N_EDGES + 255) / 256, 256, 0, stream>>>(src, dst,
                                                              cnt_out, cnt_in);
  k_chunk_sums<<<N_REL * NCHUNK, 256, 0, stream>>>(cnt_in, chunkSums);
  k_scan_chunks<<<1, 64, 0, stream>>>(chunkSums, row_ptr);
  k_scan_within<<<N_REL * NCHUNK, 256, 0, stream>>>(cnt_in, chunkSums, row_ptr,
                                                    cursor);
  k_rsqrt<<<(8 * N_NODES + 255) / 256, 256, 0, stream>>>(cnt_out, 8 * N_NODES);
  k_fill<<<(N_REL * N_EDGES + 255) / 256, 256, 0, stream>>>(src, dst, cursor,
                                                            sorted);

  const int gemmGrid = (N_NODES + 63) / 64;
  // Layer 1: two relation-pairs, Y reused between passes
  for (int p = 0; p < 2; ++p) {
    k_gemm_fused<128, 2><<<gemmGrid, 256, 0, stream>>>(
        x, W1 + (size_t)p * 2 * 128 * 128, dso + p * 2 * N_NODES, Y, N_NODES);
    k_gather1<<<(N_NODES + 3) / 4, 256, 0, stream>>>(
        Y, row_ptr + p * 2 * (N_NODES + 1), sorted + (size_t)p * 2 * N_EDGES,
        dsi + p * 2 * N_NODES, b1, h1, p);
  }
  // Layer 2: all 4 relations in one GEMM + one gather
  k_gemm_fused<64, 4><<<gemmGrid, 256, 0, stream>>>(h1, W2, dso, Y, N_NODES);
  k_gather2<<<(N_NODES + 3) / 4, 256, 0, stream>>>(Y, row_ptr, sorted, dsi, b2,
                                                   out);
}

// Round 4
// 666.988 us; speedup vs baseline: 6.8424x; 1.0229x over previous
//
#include <hip/hip_runtime.h>

#define N_NODES 50000
#define N_REL 4
#define N_EDGES 400000
#define CHUNK 1024
#define NCHUNK ((N_NODES + CHUNK - 1) / CHUNK)  // 49

#define EB 16                 // edge chunks per relation
#define ECH (N_EDGES / EB)    // 25000 edges per chunk
#define NR 4                  // node ranges
#define RNG (N_NODES / NR)    // 12500 nodes per range

// ---------------------------------------------------------------------------
// Atomic-free histograms: per (rel, edge-chunk, node-range) block counts
// src and dst occurrences into packed 16-bit LDS counters, stores ushort
// slices H_src/H_dst[rel][chunk][node]. Per-chunk count <= 25000 < 65536.
// ---------------------------------------------------------------------------
__global__ __launch_bounds__(256) void k_hist(const int* __restrict__ src,
                                              const int* __restrict__ dst,
                                              unsigned short* __restrict__ Hs,
                                              unsigned short* __restrict__ Hd) {
  const int range = blockIdx.x % NR;
  const int chunk = (blockIdx.x / NR) % EB;
  const int rel = blockIdx.x / (NR * EB);
  __shared__ unsigned int ldsS[RNG / 2], ldsD[RNG / 2];
  for (int i = threadIdx.x; i < RNG / 2; i += 256) {
    ldsS[i] = 0u;
    ldsD[i] = 0u;
  }
  __syncthreads();
  const int n0 = range * RNG;
  const int* sp = src + (size_t)rel * N_EDGES + chunk * ECH;
  const int* dp = dst + (size_t)rel * N_EDGES + chunk * ECH;
  for (int e = threadIdx.x; e < ECH; e += 256) {
    int s = sp[e] - n0;
    if ((unsigned)s < RNG) atomicAdd(&ldsS[s >> 1], 1u << ((s & 1) * 16));
    int d = dp[e] - n0;
    if ((unsigned)d < RNG) atomicAdd(&ldsD[d >> 1], 1u << ((d & 1) * 16));
  }
  __syncthreads();
  unsigned int* HsO =
      (unsigned int*)(Hs + ((size_t)rel * EB + chunk) * N_NODES + n0);
  unsigned int* HdO =
      (unsigned int*)(Hd + ((size_t)rel * EB + chunk) * N_NODES + n0);
  for (int i = threadIdx.x; i < RNG / 2; i += 256) {
    HsO[i] = ldsS[i];
    HdO[i] = ldsD[i];
  }
}

// ---------------------------------------------------------------------------
// Reduce per-chunk histograms: cnt_in (int, for scan) and dso = rsqrt(deg_out)
// ---------------------------------------------------------------------------
__global__ __launch_bounds__(256) void k_reduce(
    const unsigned short* __restrict__ Hs, const unsigned short* __restrict__ Hd,
    int* __restrict__ cnt_in, float* __restrict__ dso) {
  int idx = blockIdx.x * 256 + threadIdx.x;
  if (idx >= N_REL * N_NODES) return;
  int rel = idx / N_NODES, n = idx % N_NODES;
  int so = 0, di = 0;
#pragma unroll
  for (int b = 0; b < EB; ++b) {
    so += Hs[((size_t)rel * EB + b) * N_NODES + n];
    di += Hd[((size_t)rel * EB + b) * N_NODES + n];
  }
  cnt_in[idx] = di;
  dso[idx] = rsqrtf((float)(so < 1 ? 1 : so));
}

// ---------------------------------------------------------------------------
// Scan stage 1: per-(relation,chunk) sums of cnt_in
// ---------------------------------------------------------------------------
__global__ __launch_bounds__(256) void k_chunk_sums(
    const int* __restrict__ cnt_in, int* __restrict__ chunkSums) {
  int r = blockIdx.x / NCHUNK;
  int c = blockIdx.x % NCHUNK;
  int t = threadIdx.x;
  int base = c * CHUNK + t * 4;
  int s = 0;
#pragma unroll
  for (int j = 0; j < 4; ++j) {
    int n = base + j;
    if (n < N_NODES) s += cnt_in[r * N_NODES + n];
  }
  __shared__ int lds[256];
  lds[t] = s;
  __syncthreads();
  for (int off = 128; off > 0; off >>= 1) {
    if (t < off) lds[t] += lds[t + off];
    __syncthreads();
  }
  if (t == 0) chunkSums[r * 64 + c] = lds[0];
}

// ---------------------------------------------------------------------------
// Scan stage 2: exclusive scan of chunk sums
// ---------------------------------------------------------------------------
__global__ __launch_bounds__(64) void k_scan_chunks(int* __restrict__ chunkSums,
                                                    int* __restrict__ row_ptr) {
  int t = threadIdx.x;
  if (t < N_REL) {
    int running = 0;
    for (int c = 0; c < NCHUNK; ++c) {
      int v = chunkSums[t * 64 + c];
      chunkSums[t * 64 + c] = running;
      running += v;
    }
    row_ptr[t * (N_NODES + 1) + N_NODES] = N_EDGES;
  }
}

// ---------------------------------------------------------------------------
// Scan stage 3: within-chunk exclusive scan -> row_ptr
// ---------------------------------------------------------------------------
__global__ __launch_bounds__(256) void k_scan_within(
    const int* __restrict__ cnt_in, const int* __restrict__ chunkOff,
    int* __restrict__ row_ptr) {
  int r = blockIdx.x / NCHUNK;
  int c = blockIdx.x % NCHUNK;
  int t = threadIdx.x;
  int base = c * CHUNK + t * 4;
  int v[4];
#pragma unroll
  for (int j = 0; j < 4; ++j) {
    int n = base + j;
    v[j] = (n < N_NODES) ? cnt_in[r * N_NODES + n] : 0;
  }
  int total = v[0] + v[1] + v[2] + v[3];
  __shared__ int lds[256];
  lds[t] = total;
  __syncthreads();
  for (int off = 1; off < 256; off <<= 1) {
    int add = (t >= off) ? lds[t - off] : 0;
    __syncthreads();
    lds[t] += add;
    __syncthreads();
  }
  int thrExcl = lds[t] - total + chunkOff[r * 64 + c];
  int pre = 0;
#pragma unroll
  for (int j = 0; j < 4; ++j) {
    int n = base + j;
    if (n < N_NODES) row_ptr[r * (N_NODES + 1) + n] = thrExcl + pre;
    pre += v[j];
  }
}

// In-place: int count -> float rsqrt(max(count,1))
__global__ __launch_bounds__(256) void k_rsqrt(int* __restrict__ buf, int n) {
  int i = blockIdx.x * 256 + threadIdx.x;
  if (i >= n) return;
  int c = buf[i];
  if (c < 1) c = 1;
  ((float*)buf)[i] = rsqrtf((float)c);
}

// ---------------------------------------------------------------------------
// Atomic-free bucket fill: LDS cursors = row_ptr + prefix over earlier chunks,
// bump with LDS atomics, plain global write of sorted src.
// ---------------------------------------------------------------------------
__global__ __launch_bounds__(256) void k_fill2(const int* __restrict__ src,
                                               const int* __restrict__ dst,
                                               const unsigned short* __restrict__ Hd,
                                               const int* __restrict__ row_ptr,
                                               int* __restrict__ sorted) {
  const int range = blockIdx.x % NR;
  const int chunk = (blockIdx.x / NR) % EB;
  const int rel = blockIdx.x / (NR * EB);
  __shared__ unsigned int cur[RNG];
  const int n0 = range * RNG;
  const int* rp = row_ptr + (size_t)rel * (N_NODES + 1) + n0;
  for (int i = threadIdx.x; i < RNG; i += 256) {
    int base = rp[i];
    for (int b = 0; b < chunk; ++b)
      base += Hd[((size_t)rel * EB + b) * N_NODES + n0 + i];
    cur[i] = (unsigned)base;
  }
  __syncthreads();
  const int* sp = src + (size_t)rel * N_EDGES + chunk * ECH;
  const int* dp = dst + (size_t)rel * N_EDGES + chunk * ECH;
  int* so = sorted + (size_t)rel * N_EDGES;
  for (int e = threadIdx.x; e < ECH; e += 256) {
    int d = dp[e] - n0;
    if ((unsigned)d < RNG) {
      unsigned pos = atomicAdd(&cur[d], 1u);
      so[pos] = sp[e];
    }
  }
}

// ---------------------------------------------------------------------------
// Fused multi-relation GEMM (unchanged from round 3)
// ---------------------------------------------------------------------------
template <int REL_COLS, int NRELS>
__global__ __launch_bounds__(256, 4) void k_gemm_fused(
    const float* __restrict__ A, const float* __restrict__ Wbase,
    const float* __restrict__ dsoBase, float* __restrict__ C, int M) {
  constexpr int NC = REL_COLS * NRELS;  // 256
  __shared__ float At[32][64];
  __shared__ float Wc[32][NC];
  const int tid = threadIdx.x;
  const int rg = tid >> 5;
  const int cg = tid & 31;
  const int rowBase = blockIdx.x * 64;

  float acc[8][8];
#pragma unroll
  for (int i = 0; i < 8; ++i)
#pragma unroll
    for (int j = 0; j < 8; ++j) acc[i][j] = 0.f;

  for (int k0 = 0; k0 < 128; k0 += 32) {
    __syncthreads();
    {
      int i = tid;
#pragma unroll
      for (int rep = 0; rep < 2; ++rep, i += 256) {
        int row = i >> 3, fp = i & 7;
        float4 a = make_float4(0.f, 0.f, 0.f, 0.f);
        int grow = rowBase + row;
        if (grow < M)
          a = *(const float4*)(A + (size_t)grow * 128 + k0 + fp * 4);
        At[fp * 4 + 0][row] = a.x;
        At[fp * 4 + 1][row] = a.y;
        At[fp * 4 + 2][row] = a.z;
        At[fp * 4 + 3][row] = a.w;
      }
    }
    {
#pragma unroll
      for (int rep = 0; rep < 8; ++rep) {
        int i = tid + rep * 256;
        int k = i >> 6;
        int c = (i & 63) << 2;
        int r = c / REL_COLS;
        int cc = c % REL_COLS;
        float4 w = *(const float4*)(Wbase + (size_t)r * 128 * REL_COLS +
                                    (size_t)(k0 + k) * REL_COLS + cc);
        *(float4*)&Wc[k][c] = w;
      }
    }
    __syncthreads();
#pragma unroll 8
    for (int kk = 0; kk < 32; ++kk) {
      float4 a0 = *(const float4*)&At[kk][rg * 8];
      float4 a1 = *(const float4*)&At[kk][rg * 8 + 4];
      float4 w0 = *(const float4*)&Wc[kk][cg * 8];
      float4 w1 = *(const float4*)&Wc[kk][cg * 8 + 4];
      float a[8] = {a0.x, a0.y, a0.z, a0.w, a1.x, a1.y, a1.z, a1.w};
      float w[8] = {w0.x, w0.y, w0.z, w0.w, w1.x, w1.y, w1.z, w1.w};
#pragma unroll
      for (int i = 0; i < 8; ++i)
#pragma unroll
        for (int j = 0; j < 8; ++j) acc[i][j] = fmaf(a[i], w[j], acc[i][j]);
    }
  }
  const int rsel = (cg * 8) / REL_COLS;
  const float* dso = dsoBase + (size_t)rsel * N_NODES;
#pragma unroll
  for (int i = 0; i < 8; ++i) {
    int row = rowBase + rg * 8 + i;
    if (row >= M) break;
    float s = dso[row];
    float* cp = C + (size_t)row * NC + cg * 8;
    *(float4*)cp =
        make_float4(acc[i][0] * s, acc[i][1] * s, acc[i][2] * s, acc[i][3] * s);
    *(float4*)(cp + 4) =
        make_float4(acc[i][4] * s, acc[i][5] * s, acc[i][6] * s, acc[i][7] * s);
  }
}

// ---------------------------------------------------------------------------
// Gather layer 1 (unchanged)
// ---------------------------------------------------------------------------
__global__ __launch_bounds__(256) void k_gather1(
    const float* __restrict__ Y, const int* __restrict__ row_ptr,
    const int* __restrict__ sorted, const float* __restrict__ dsi,
    const float* __restrict__ b1, float* __restrict__ h1, int pass) {
  int wave = threadIdx.x >> 6, lane = threadIdx.x & 63;
  int node = blockIdx.x * 4 + wave;
  if (node >= N_NODES) return;
  const float2* Y2 = (const float2*)Y;
  float2 tot = make_float2(0.f, 0.f);
#pragma unroll
  for (int rp = 0; rp < 2; ++rp) {
    int beg = row_ptr[rp * (N_NODES + 1) + node];
    int end = row_ptr[rp * (N_NODES + 1) + node + 1];
    const int* ss = sorted + (size_t)rp * N_EDGES;
    float2 a0 = make_float2(0.f, 0.f), a1 = make_float2(0.f, 0.f);
    int e = beg;
    for (; e + 1 < end; e += 2) {
      int s0 = ss[e], s1 = ss[e + 1];
      float2 y0 = Y2[((size_t)s0 * 2 + rp) * 64 + lane];
      float2 y1 = Y2[((size_t)s1 * 2 + rp) * 64 + lane];
      a0.x += y0.x; a0.y += y0.y;
      a1.x += y1.x; a1.y += y1.y;
    }
    if (e < end) {
      float2 y = Y2[((size_t)ss[e] * 2 + rp) * 64 + lane];
      a0.x += y.x; a0.y += y.y;
    }
    float w = dsi[rp * N_NODES + node];
    tot.x += (a0.x + a1.x) * w;
    tot.y += (a0.y + a1.y) * w;
  }
  float2* H = (float2*)h1 + (size_t)node * 64 + lane;
  if (pass == 0) {
    *H = tot;
  } else {
    const float2* B = (const float2*)b1;
    float2 b = make_float2(0.f, 0.f);
#pragma unroll
    for (int r = 0; r < 4; ++r) {
      float2 bb = B[r * 64 + lane];
      b.x += bb.x; b.y += bb.y;
    }
    float2 cur = *H;
    float vx = cur.x + tot.x + b.x;
    float vy = cur.y + tot.y + b.y;
    *H = make_float2(fmaxf(vx, 0.f), fmaxf(vy, 0.f));
  }
}

// ---------------------------------------------------------------------------
// Gather layer 2 (unchanged)
// ---------------------------------------------------------------------------
__global__ __launch_bounds__(256) void k_gather2(
    const float* __restrict__ Y, const int* __restrict__ row_ptr,
    const int* __restrict__ sorted, const float* __restrict__ dsi,
    const float* __restrict__ b2, float* __restrict__ out) {
  int wave = threadIdx.x >> 6, lane = threadIdx.x & 63;
  int node = blockIdx.x * 4 + wave;
  if (node >= N_NODES) return;
  float tot = 0.f;
#pragma unroll
  for (int r = 0; r < 4; ++r) {
    int beg = row_ptr[r * (N_NODES + 1) + node];
    int end = row_ptr[r * (N_NODES + 1) + node + 1];
    const int* ss = sorted + (size_t)r * N_EDGES;
    float a0 = 0.f, a1 = 0.f;
    int e = beg;
    for (; e + 1 < end; e += 2) {
      int s0 = ss[e], s1 = ss[e + 1];
      a0 += Y[((size_t)s0 * 4 + r) * 64 + lane];
      a1 += Y[((size_t)s1 * 4 + r) * 64 + lane];
    }
    if (e < end) a0 += Y[((size_t)ss[e] * 4 + r) * 64 + lane];
    tot += (a0 + a1) * dsi[r * N_NODES + node];
  }
  float b = b2[lane] + b2[64 + lane] + b2[128 + lane] + b2[192 + lane];
  out[(size_t)node * 64 + lane] = tot + b;
}

extern "C" void kernel_launch(void* const* d_in, const int* in_sizes, int n_in,
                              void* d_out, int out_size, void* d_ws,
                              size_t ws_size, hipStream_t stream) {
  const float* x  = (const float*)d_in[0];
  const int* src  = (const int*)d_in[1];
  const int* dst  = (const int*)d_in[2];
  const float* W1 = (const float*)d_in[3];
  const float* b1 = (const float*)d_in[4];
  const float* W2 = (const float*)d_in[5];
  const float* b2 = (const float*)d_in[6];
  float* out = (float*)d_out;

  // Workspace layout:
  //   [0, 25.6MB)    h1 [50000][128] floats  -- ALIASED by Hs/Hd (dead before
  //                                             h1's first write in gather1)
  //   [25.6, 76.8MB) Y [50000][256] floats
  //   [76.8MB, ...)  cnt_in | dso | row_ptr | chunkSums | sorted
  char* wsb = (char*)d_ws;
  float* h1 = (float*)wsb;
  unsigned short* Hs = (unsigned short*)wsb;                        // 6.4MB
  unsigned short* Hd = Hs + (size_t)N_REL * EB * N_NODES;           // 6.4MB
  float* Y = (float*)(wsb + (size_t)N_NODES * 128 * 4);             // 51.2MB
  char* tail = wsb + (size_t)N_NODES * (128 + 256) * 4;
  int* cnt_in = (int*)tail;                                         // 800KB
  float* dso = (float*)(cnt_in + N_REL * N_NODES);                  // 800KB
  int* row_ptr = (int*)(dso + N_REL * N_NODES);                     // ~800KB
  int* chunkSums = row_ptr + N_REL * (N_NODES + 1);                 // 1KB
  int* sorted = chunkSums + 256;                                    // 6.4MB
  float* dsi = (float*)cnt_in;  // in place after k_rsqrt

  k_hist<<<N_REL * EB * NR, 256, 0, stream>>>(src, dst, Hs, Hd);
  k_reduce<<<(N_REL * N_NODES + 255) / 256, 256, 0, stream>>>(Hs, Hd, cnt_in,
                                                              dso);
  k_chunk_sums<<<N_REL * NCHUNK, 256, 0, stream>>>(cnt_in, chunkSums);
  k_scan_chunks<<<1, 64, 0, stream>>>(chunkSums, row_ptr);
  k_scan_within<<<N_REL * NCHUNK, 256, 0, stream>>>(cnt_in, chunkSums,
                                                    row_ptr);
  k_rsqrt<<<(N_REL * N_NODES + 255) / 256, 256, 0, stream>>>(cnt_in,
                                                             N_REL * N_NODES);
  k_fill2<<<N_REL * EB * NR, 256, 0, stream>>>(src, dst, Hd, row_ptr, sorted);

  const int gemmGrid = (N_NODES + 63) / 64;
  // Layer 1: two relation-pairs
  for (int p = 0; p < 2; ++p) {
    k_gemm_fused<128, 2><<<gemmGrid, 256, 0, stream>>>(
        x, W1 + (size_t)p * 2 * 128 * 128, dso + p * 2 * N_NODES, Y, N_NODES);
    k_gather1<<<(N_NODES + 3) / 4, 256, 0, stream>>>(
        Y, row_ptr + p * 2 * (N_NODES + 1), sorted + (size_t)p * 2 * N_EDGES,
        dsi + p * 2 * N_NODES, b1, h1, p);
  }
  // Layer 2: all 4 relations
  k_gemm_fused<64, 4><<<gemmGrid, 256, 0, stream>>>(h1, W2, dso, Y, N_NODES);
  k_gather2<<<(N_NODES + 3) / 4, 256, 0, stream>>>(Y, row_ptr, sorted, dsi, b2,
                                                   out);
}

// Round 5
// 522.332 us; speedup vs baseline: 8.7373x; 1.2769x over previous
//
#include <hip/hip_runtime.h>

#define N_NODES 50000
#define N_REL 4
#define N_EDGES 400000
#define CHUNK 1024
#define NCHUNK ((N_NODES + CHUNK - 1) / CHUNK)  // 49

#define EB 32                 // edge chunks per relation
#define ECH (N_EDGES / EB)    // 12500 edges per chunk
#define NR 8                  // node ranges
#define RNG (N_NODES / NR)    // 6250 nodes per range

// ---------------------------------------------------------------------------
// Atomic-free histograms: per (rel, edge-chunk, node-range) block counts
// src and dst into packed 16-bit LDS counters. Per-chunk count <= 12500.
// ---------------------------------------------------------------------------
__global__ __launch_bounds__(256) void k_hist(const int* __restrict__ src,
                                              const int* __restrict__ dst,
                                              unsigned short* __restrict__ Hs,
                                              unsigned short* __restrict__ Hd) {
  const int range = blockIdx.x % NR;
  const int chunk = (blockIdx.x / NR) % EB;
  const int rel = blockIdx.x / (NR * EB);
  __shared__ unsigned int ldsS[RNG / 2], ldsD[RNG / 2];
  for (int i = threadIdx.x; i < RNG / 2; i += 256) {
    ldsS[i] = 0u;
    ldsD[i] = 0u;
  }
  __syncthreads();
  const int n0 = range * RNG;
  const int* sp = src + (size_t)rel * N_EDGES + chunk * ECH;
  const int* dp = dst + (size_t)rel * N_EDGES + chunk * ECH;
  for (int e = threadIdx.x; e < ECH; e += 256) {
    int s = sp[e] - n0;
    if ((unsigned)s < RNG) atomicAdd(&ldsS[s >> 1], 1u << ((s & 1) * 16));
    int d = dp[e] - n0;
    if ((unsigned)d < RNG) atomicAdd(&ldsD[d >> 1], 1u << ((d & 1) * 16));
  }
  __syncthreads();
  unsigned int* HsO =
      (unsigned int*)(Hs + ((size_t)rel * EB + chunk) * N_NODES + n0);
  unsigned int* HdO =
      (unsigned int*)(Hd + ((size_t)rel * EB + chunk) * N_NODES + n0);
  for (int i = threadIdx.x; i < RNG / 2; i += 256) {
    HsO[i] = ldsS[i];
    HdO[i] = ldsD[i];
  }
}

// ---------------------------------------------------------------------------
// Reduce: cnt_in (for scan), dso = rsqrt(deg_out), and IN-PLACE exclusive
// prefix of Hd along the chunk axis (so fill needs a single read).
// ---------------------------------------------------------------------------
__global__ __launch_bounds__(256) void k_reduce(
    const unsigned short* __restrict__ Hs, unsigned short* __restrict__ Hd,
    int* __restrict__ cnt_in, float* __restrict__ dso) {
  int idx = blockIdx.x * 256 + threadIdx.x;
  if (idx >= N_REL * N_NODES) return;
  int rel = idx / N_NODES, n = idx % N_NODES;
  int so = 0;
#pragma unroll
  for (int b = 0; b < EB; ++b) so += Hs[((size_t)rel * EB + b) * N_NODES + n];
  int run = 0;
#pragma unroll
  for (int b = 0; b < EB; ++b) {
    size_t off = ((size_t)rel * EB + b) * N_NODES + n;
    int v = Hd[off];
    Hd[off] = (unsigned short)run;  // exclusive prefix (<= in-degree, fits)
    run += v;
  }
  cnt_in[idx] = run;
  dso[idx] = rsqrtf((float)(so < 1 ? 1 : so));
}

// ---------------------------------------------------------------------------
// Scan stage 1: per-(relation,chunk) sums of cnt_in
// ---------------------------------------------------------------------------
__global__ __launch_bounds__(256) void k_chunk_sums(
    const int* __restrict__ cnt_in, int* __restrict__ chunkSums) {
  int r = blockIdx.x / NCHUNK;
  int c = blockIdx.x % NCHUNK;
  int t = threadIdx.x;
  int base = c * CHUNK + t * 4;
  int s = 0;
#pragma unroll
  for (int j = 0; j < 4; ++j) {
    int n = base + j;
    if (n < N_NODES) s += cnt_in[r * N_NODES + n];
  }
  __shared__ int lds[256];
  lds[t] = s;
  __syncthreads();
  for (int off = 128; off > 0; off >>= 1) {
    if (t < off) lds[t] += lds[t + off];
    __syncthreads();
  }
  if (t == 0) chunkSums[r * 64 + c] = lds[0];
}

// ---------------------------------------------------------------------------
// Scan stage 2: exclusive scan of chunk sums
// ---------------------------------------------------------------------------
__global__ __launch_bounds__(64) void k_scan_chunks(int* __restrict__ chunkSums,
                                                    int* __restrict__ row_ptr) {
  int t = threadIdx.x;
  if (t < N_REL) {
    int running = 0;
    for (int c = 0; c < NCHUNK; ++c) {
      int v = chunkSums[t * 64 + c];
      chunkSums[t * 64 + c] = running;
      running += v;
    }
    row_ptr[t * (N_NODES + 1) + N_NODES] = N_EDGES;
  }
}

// ---------------------------------------------------------------------------
// Scan stage 3: within-chunk exclusive scan -> row_ptr; also dsi = rsqrt(deg)
// (dsi aliases cnt_in; safe: each element read once by its own thread first)
// ---------------------------------------------------------------------------
__global__ __launch_bounds__(256) void k_scan_within(
    int* __restrict__ cnt_in, const int* __restrict__ chunkOff,
    int* __restrict__ row_ptr) {
  int r = blockIdx.x / NCHUNK;
  int c = blockIdx.x % NCHUNK;
  int t = threadIdx.x;
  int base = c * CHUNK + t * 4;
  int v[4];
#pragma unroll
  for (int j = 0; j < 4; ++j) {
    int n = base + j;
    v[j] = (n < N_NODES) ? cnt_in[r * N_NODES + n] : 0;
  }
  int total = v[0] + v[1] + v[2] + v[3];
  __shared__ int lds[256];
  lds[t] = total;
  __syncthreads();
  for (int off = 1; off < 256; off <<= 1) {
    int add = (t >= off) ? lds[t - off] : 0;
    __syncthreads();
    lds[t] += add;
    __syncthreads();
  }
  int thrExcl = lds[t] - total + chunkOff[r * 64 + c];
  int pre = 0;
#pragma unroll
  for (int j = 0; j < 4; ++j) {
    int n = base + j;
    if (n < N_NODES) {
      row_ptr[r * (N_NODES + 1) + n] = thrExcl + pre;
      ((float*)cnt_in)[r * N_NODES + n] =
          rsqrtf((float)(v[j] < 1 ? 1 : v[j]));
    }
    pre += v[j];
  }
}

// ---------------------------------------------------------------------------
// Atomic-free bucket fill: cursor = row_ptr + precomputed chunk prefix,
// bump with LDS atomics, plain global write of sorted src.
// ---------------------------------------------------------------------------
__global__ __launch_bounds__(256) void k_fill2(const int* __restrict__ src,
                                               const int* __restrict__ dst,
                                               const unsigned short* __restrict__ Hd,
                                               const int* __restrict__ row_ptr,
                                               int* __restrict__ sorted) {
  const int range = blockIdx.x % NR;
  const int chunk = (blockIdx.x / NR) % EB;
  const int rel = blockIdx.x / (NR * EB);
  __shared__ unsigned int cur[RNG];
  const int n0 = range * RNG;
  const int* rp = row_ptr + (size_t)rel * (N_NODES + 1) + n0;
  const unsigned short* pref = Hd + ((size_t)rel * EB + chunk) * N_NODES + n0;
  for (int i = threadIdx.x; i < RNG; i += 256)
    cur[i] = (unsigned)(rp[i] + pref[i]);
  __syncthreads();
  const int* sp = src + (size_t)rel * N_EDGES + chunk * ECH;
  const int* dp = dst + (size_t)rel * N_EDGES + chunk * ECH;
  int* so = sorted + (size_t)rel * N_EDGES;
  for (int e = threadIdx.x; e < ECH; e += 256) {
    int d = dp[e] - n0;
    if ((unsigned)d < RNG) {
      unsigned pos = atomicAdd(&cur[d], 1u);
      so[pos] = sp[e];
    }
  }
}

// ---------------------------------------------------------------------------
// Fused multi-relation GEMM (unchanged)
// ---------------------------------------------------------------------------
template <int REL_COLS, int NRELS>
__global__ __launch_bounds__(256, 4) void k_gemm_fused(
    const float* __restrict__ A, const float* __restrict__ Wbase,
    const float* __restrict__ dsoBase, float* __restrict__ C, int M) {
  constexpr int NC = REL_COLS * NRELS;  // 256
  __shared__ float At[32][64];
  __shared__ float Wc[32][NC];
  const int tid = threadIdx.x;
  const int rg = tid >> 5;
  const int cg = tid & 31;
  const int rowBase = blockIdx.x * 64;

  float acc[8][8];
#pragma unroll
  for (int i = 0; i < 8; ++i)
#pragma unroll
    for (int j = 0; j < 8; ++j) acc[i][j] = 0.f;

  for (int k0 = 0; k0 < 128; k0 += 32) {
    __syncthreads();
    {
      int i = tid;
#pragma unroll
      for (int rep = 0; rep < 2; ++rep, i += 256) {
        int row = i >> 3, fp = i & 7;
        float4 a = make_float4(0.f, 0.f, 0.f, 0.f);
        int grow = rowBase + row;
        if (grow < M)
          a = *(const float4*)(A + (size_t)grow * 128 + k0 + fp * 4);
        At[fp * 4 + 0][row] = a.x;
        At[fp * 4 + 1][row] = a.y;
        At[fp * 4 + 2][row] = a.z;
        At[fp * 4 + 3][row] = a.w;
      }
    }
    {
#pragma unroll
      for (int rep = 0; rep < 8; ++rep) {
        int i = tid + rep * 256;
        int k = i >> 6;
        int c = (i & 63) << 2;
        int r = c / REL_COLS;
        int cc = c % REL_COLS;
        float4 w = *(const float4*)(Wbase + (size_t)r * 128 * REL_COLS +
                                    (size_t)(k0 + k) * REL_COLS + cc);
        *(float4*)&Wc[k][c] = w;
      }
    }
    __syncthreads();
#pragma unroll 8
    for (int kk = 0; kk < 32; ++kk) {
      float4 a0 = *(const float4*)&At[kk][rg * 8];
      float4 a1 = *(const float4*)&At[kk][rg * 8 + 4];
      float4 w0 = *(const float4*)&Wc[kk][cg * 8];
      float4 w1 = *(const float4*)&Wc[kk][cg * 8 + 4];
      float a[8] = {a0.x, a0.y, a0.z, a0.w, a1.x, a1.y, a1.z, a1.w};
      float w[8] = {w0.x, w0.y, w0.z, w0.w, w1.x, w1.y, w1.z, w1.w};
#pragma unroll
      for (int i = 0; i < 8; ++i)
#pragma unroll
        for (int j = 0; j < 8; ++j) acc[i][j] = fmaf(a[i], w[j], acc[i][j]);
    }
  }
  const int rsel = (cg * 8) / REL_COLS;
  const float* dso = dsoBase + (size_t)rsel * N_NODES;
#pragma unroll
  for (int i = 0; i < 8; ++i) {
    int row = rowBase + rg * 8 + i;
    if (row >= M) break;
    float s = dso[row];
    float* cp = C + (size_t)row * NC + cg * 8;
    *(float4*)cp =
        make_float4(acc[i][0] * s, acc[i][1] * s, acc[i][2] * s, acc[i][3] * s);
    *(float4*)(cp + 4) =
        make_float4(acc[i][4] * s, acc[i][5] * s, acc[i][6] * s, acc[i][7] * s);
  }
}

// ---------------------------------------------------------------------------
// Gather layer 1 (unchanged)
// ---------------------------------------------------------------------------
__global__ __launch_bounds__(256) void k_gather1(
    const float* __restrict__ Y, const int* __restrict__ row_ptr,
    const int* __restrict__ sorted, const float* __restrict__ dsi,
    const float* __restrict__ b1, float* __restrict__ h1, int pass) {
  int wave = threadIdx.x >> 6, lane = threadIdx.x & 63;
  int node = blockIdx.x * 4 + wave;
  if (node >= N_NODES) return;
  const float2* Y2 = (const float2*)Y;
  float2 tot = make_float2(0.f, 0.f);
#pragma unroll
  for (int rp = 0; rp < 2; ++rp) {
    int beg = row_ptr[rp * (N_NODES + 1) + node];
    int end = row_ptr[rp * (N_NODES + 1) + node + 1];
    const int* ss = sorted + (size_t)rp * N_EDGES;
    float2 a0 = make_float2(0.f, 0.f), a1 = make_float2(0.f, 0.f);
    int e = beg;
    for (; e + 1 < end; e += 2) {
      int s0 = ss[e], s1 = ss[e + 1];
      float2 y0 = Y2[((size_t)s0 * 2 + rp) * 64 + lane];
      float2 y1 = Y2[((size_t)s1 * 2 + rp) * 64 + lane];
      a0.x += y0.x; a0.y += y0.y;
      a1.x += y1.x; a1.y += y1.y;
    }
    if (e < end) {
      float2 y = Y2[((size_t)ss[e] * 2 + rp) * 64 + lane];
      a0.x += y.x; a0.y += y.y;
    }
    float w = dsi[rp * N_NODES + node];
    tot.x += (a0.x + a1.x) * w;
    tot.y += (a0.y + a1.y) * w;
  }
  float2* H = (float2*)h1 + (size_t)node * 64 + lane;
  if (pass == 0) {
    *H = tot;
  } else {
    const float2* B = (const float2*)b1;
    float2 b = make_float2(0.f, 0.f);
#pragma unroll
    for (int r = 0; r < 4; ++r) {
      float2 bb = B[r * 64 + lane];
      b.x += bb.x; b.y += bb.y;
    }
    float2 cur = *H;
    float vx = cur.x + tot.x + b.x;
    float vy = cur.y + tot.y + b.y;
    *H = make_float2(fmaxf(vx, 0.f), fmaxf(vy, 0.f));
  }
}

// ---------------------------------------------------------------------------
// Gather layer 2 (unchanged)
// ---------------------------------------------------------------------------
__global__ __launch_bounds__(256) void k_gather2(
    const float* __restrict__ Y, const int* __restrict__ row_ptr,
    const int* __restrict__ sorted, const float* __restrict__ dsi,
    const float* __restrict__ b2, float* __restrict__ out) {
  int wave = threadIdx.x >> 6, lane = threadIdx.x & 63;
  int node = blockIdx.x * 4 + wave;
  if (node >= N_NODES) return;
  float tot = 0.f;
#pragma unroll
  for (int r = 0; r < 4; ++r) {
    int beg = row_ptr[r * (N_NODES + 1) + node];
    int end = row_ptr[r * (N_NODES + 1) + node + 1];
    const int* ss = sorted + (size_t)r * N_EDGES;
    float a0 = 0.f, a1 = 0.f;
    int e = beg;
    for (; e + 1 < end; e += 2) {
      int s0 = ss[e], s1 = ss[e + 1];
      a0 += Y[((size_t)s0 * 4 + r) * 64 + lane];
      a1 += Y[((size_t)s1 * 4 + r) * 64 + lane];
    }
    if (e < end) a0 += Y[((size_t)ss[e] * 4 + r) * 64 + lane];
    tot += (a0 + a1) * dsi[r * N_NODES + node];
  }
  float b = b2[lane] + b2[64 + lane] + b2[128 + lane] + b2[192 + lane];
  out[(size_t)node * 64 + lane] = tot + b;
}

extern "C" void kernel_launch(void* const* d_in, const int* in_sizes, int n_in,
                              void* d_out, int out_size, void* d_ws,
                              size_t ws_size, hipStream_t stream) {
  const float* x  = (const float*)d_in[0];
  const int* src  = (const int*)d_in[1];
  const int* dst  = (const int*)d_in[2];
  const float* W1 = (const float*)d_in[3];
  const float* b1 = (const float*)d_in[4];
  const float* W2 = (const float*)d_in[5];
  const float* b2 = (const float*)d_in[6];
  float* out = (float*)d_out;

  // Workspace layout:
  //   [0, 25.6MB)    h1 [50000][128] -- ALIASED by Hs/Hd (dead before h1's
  //                                     first write in gather1 pass 0)
  //   [25.6, 76.8MB) Y [50000][256]
  //   tail: cnt_in(=dsi) | dso | row_ptr | chunkSums | sorted
  char* wsb = (char*)d_ws;
  float* h1 = (float*)wsb;
  unsigned short* Hs = (unsigned short*)wsb;                        // 12.8MB
  unsigned short* Hd = Hs + (size_t)N_REL * EB * N_NODES;           // 12.8MB
  float* Y = (float*)(wsb + (size_t)N_NODES * 128 * 4);             // 51.2MB
  char* tail = wsb + (size_t)N_NODES * (128 + 256) * 4;
  int* cnt_in = (int*)tail;                                         // 800KB
  float* dso = (float*)(cnt_in + N_REL * N_NODES);                  // 800KB
  int* row_ptr = (int*)(dso + N_REL * N_NODES);                     // ~800KB
  int* chunkSums = row_ptr + N_REL * (N_NODES + 1);                 // 1KB
  int* sorted = chunkSums + 256;                                    // 6.4MB
  float* dsi = (float*)cnt_in;  // written in k_scan_within

  k_hist<<<N_REL * EB * NR, 256, 0, stream>>>(src, dst, Hs, Hd);
  k_reduce<<<(N_REL * N_NODES + 255) / 256, 256, 0, stream>>>(Hs, Hd, cnt_in,
                                                              dso);
  k_chunk_sums<<<N_REL * NCHUNK, 256, 0, stream>>>(cnt_in, chunkSums);
  k_scan_chunks<<<1, 64, 0, stream>>>(chunkSums, row_ptr);
  k_scan_within<<<N_REL * NCHUNK, 256, 0, stream>>>(cnt_in, chunkSums,
                                                    row_ptr);
  k_fill2<<<N_REL * EB * NR, 256, 0, stream>>>(src, dst, Hd, row_ptr, sorted);

  const int gemmGrid = (N_NODES + 63) / 64;
  // Layer 1: two relation-pairs
  for (int p = 0; p < 2; ++p) {
    k_gemm_fused<128, 2><<<gemmGrid, 256, 0, stream>>>(
        x, W1 + (size_t)p * 2 * 128 * 128, dso + p * 2 * N_NODES, Y, N_NODES);
    k_gather1<<<(N_NODES + 3) / 4, 256, 0, stream>>>(
        Y, row_ptr + p * 2 * (N_NODES + 1), sorted + (size_t)p * 2 * N_EDGES,
        dsi + p * 2 * N_NODES, b1, h1, p);
  }
  // Layer 2: all 4 relations
  k_gemm_fused<64, 4><<<gemmGrid, 256, 0, stream>>>(h1, W2, dso, Y, N_NODES);
  k_gather2<<<(N_NODES + 3) / 4, 256, 0, stream>>>(Y, row_ptr, sorted, dsi, b2,
                                                   out);
}

// Round 6
// 431.134 us; speedup vs baseline: 10.5856x; 1.2115x over previous
//
#include <hip/hip_runtime.h>
#include <hip/hip_bf16.h>

#define N_NODES 50000
#define N_REL 4
#define N_EDGES 400000
#define CHUNK 1024
#define NCHUNK ((N_NODES + CHUNK - 1) / CHUNK)  // 49

#define EB 32                 // edge chunks per relation
#define ECH (N_EDGES / EB)    // 12500 edges per chunk
#define NR 8                  // node ranges
#define RNG (N_NODES / NR)    // 6250 nodes per range

// bf16 helpers (RNE pack, shift-unpack)
static __device__ inline unsigned short f2bf(float f) {
  unsigned u = __float_as_uint(f);
  unsigned r = (u + 0x7FFFu + ((u >> 16) & 1u)) >> 16;
  return (unsigned short)r;
}
static __device__ inline float bf2f(unsigned short b) {
  return __uint_as_float(((unsigned)b) << 16);
}

// ---------------------------------------------------------------------------
// Atomic-free histograms (unchanged)
// ---------------------------------------------------------------------------
__global__ __launch_bounds__(256) void k_hist(const int* __restrict__ src,
                                              const int* __restrict__ dst,
                                              unsigned short* __restrict__ Hs,
                                              unsigned short* __restrict__ Hd) {
  const int range = blockIdx.x % NR;
  const int chunk = (blockIdx.x / NR) % EB;
  const int rel = blockIdx.x / (NR * EB);
  __shared__ unsigned int ldsS[RNG / 2], ldsD[RNG / 2];
  for (int i = threadIdx.x; i < RNG / 2; i += 256) {
    ldsS[i] = 0u;
    ldsD[i] = 0u;
  }
  __syncthreads();
  const int n0 = range * RNG;
  const int* sp = src + (size_t)rel * N_EDGES + chunk * ECH;
  const int* dp = dst + (size_t)rel * N_EDGES + chunk * ECH;
  for (int e = threadIdx.x; e < ECH; e += 256) {
    int s = sp[e] - n0;
    if ((unsigned)s < RNG) atomicAdd(&ldsS[s >> 1], 1u << ((s & 1) * 16));
    int d = dp[e] - n0;
    if ((unsigned)d < RNG) atomicAdd(&ldsD[d >> 1], 1u << ((d & 1) * 16));
  }
  __syncthreads();
  unsigned int* HsO =
      (unsigned int*)(Hs + ((size_t)rel * EB + chunk) * N_NODES + n0);
  unsigned int* HdO =
      (unsigned int*)(Hd + ((size_t)rel * EB + chunk) * N_NODES + n0);
  for (int i = threadIdx.x; i < RNG / 2; i += 256) {
    HsO[i] = ldsS[i];
    HdO[i] = ldsD[i];
  }
}

// ---------------------------------------------------------------------------
// Reduce + in-place chunk prefix of Hd (unchanged)
// ---------------------------------------------------------------------------
__global__ __launch_bounds__(256) void k_reduce(
    const unsigned short* __restrict__ Hs, unsigned short* __restrict__ Hd,
    int* __restrict__ cnt_in, float* __restrict__ dso) {
  int idx = blockIdx.x * 256 + threadIdx.x;
  if (idx >= N_REL * N_NODES) return;
  int rel = idx / N_NODES, n = idx % N_NODES;
  int so = 0;
#pragma unroll
  for (int b = 0; b < EB; ++b) so += Hs[((size_t)rel * EB + b) * N_NODES + n];
  int run = 0;
#pragma unroll
  for (int b = 0; b < EB; ++b) {
    size_t off = ((size_t)rel * EB + b) * N_NODES + n;
    int v = Hd[off];
    Hd[off] = (unsigned short)run;
    run += v;
  }
  cnt_in[idx] = run;
  dso[idx] = rsqrtf((float)(so < 1 ? 1 : so));
}

__global__ __launch_bounds__(256) void k_chunk_sums(
    const int* __restrict__ cnt_in, int* __restrict__ chunkSums) {
  int r = blockIdx.x / NCHUNK;
  int c = blockIdx.x % NCHUNK;
  int t = threadIdx.x;
  int base = c * CHUNK + t * 4;
  int s = 0;
#pragma unroll
  for (int j = 0; j < 4; ++j) {
    int n = base + j;
    if (n < N_NODES) s += cnt_in[r * N_NODES + n];
  }
  __shared__ int lds[256];
  lds[t] = s;
  __syncthreads();
  for (int off = 128; off > 0; off >>= 1) {
    if (t < off) lds[t] += lds[t + off];
    __syncthreads();
  }
  if (t == 0) chunkSums[r * 64 + c] = lds[0];
}

__global__ __launch_bounds__(64) void k_scan_chunks(int* __restrict__ chunkSums,
                                                    int* __restrict__ row_ptr) {
  int t = threadIdx.x;
  if (t < N_REL) {
    int running = 0;
    for (int c = 0; c < NCHUNK; ++c) {
      int v = chunkSums[t * 64 + c];
      chunkSums[t * 64 + c] = running;
      running += v;
    }
    row_ptr[t * (N_NODES + 1) + N_NODES] = N_EDGES;
  }
}

__global__ __launch_bounds__(256) void k_scan_within(
    int* __restrict__ cnt_in, const int* __restrict__ chunkOff,
    int* __restrict__ row_ptr) {
  int r = blockIdx.x / NCHUNK;
  int c = blockIdx.x % NCHUNK;
  int t = threadIdx.x;
  int base = c * CHUNK + t * 4;
  int v[4];
#pragma unroll
  for (int j = 0; j < 4; ++j) {
    int n = base + j;
    v[j] = (n < N_NODES) ? cnt_in[r * N_NODES + n] : 0;
  }
  int total = v[0] + v[1] + v[2] + v[3];
  __shared__ int lds[256];
  lds[t] = total;
  __syncthreads();
  for (int off = 1; off < 256; off <<= 1) {
    int add = (t >= off) ? lds[t - off] : 0;
    __syncthreads();
    lds[t] += add;
    __syncthreads();
  }
  int thrExcl = lds[t] - total + chunkOff[r * 64 + c];
  int pre = 0;
#pragma unroll
  for (int j = 0; j < 4; ++j) {
    int n = base + j;
    if (n < N_NODES) {
      row_ptr[r * (N_NODES + 1) + n] = thrExcl + pre;
      ((float*)cnt_in)[r * N_NODES + n] =
          rsqrtf((float)(v[j] < 1 ? 1 : v[j]));
    }
    pre += v[j];
  }
}

__global__ __launch_bounds__(256) void k_fill2(const int* __restrict__ src,
                                               const int* __restrict__ dst,
                                               const unsigned short* __restrict__ Hd,
                                               const int* __restrict__ row_ptr,
                                               int* __restrict__ sorted) {
  const int range = blockIdx.x % NR;
  const int chunk = (blockIdx.x / NR) % EB;
  const int rel = blockIdx.x / (NR * EB);
  __shared__ unsigned int cur[RNG];
  const int n0 = range * RNG;
  const int* rp = row_ptr + (size_t)rel * (N_NODES + 1) + n0;
  const unsigned short* pref = Hd + ((size_t)rel * EB + chunk) * N_NODES + n0;
  for (int i = threadIdx.x; i < RNG; i += 256)
    cur[i] = (unsigned)(rp[i] + pref[i]);
  __syncthreads();
  const int* sp = src + (size_t)rel * N_EDGES + chunk * ECH;
  const int* dp = dst + (size_t)rel * N_EDGES + chunk * ECH;
  int* so = sorted + (size_t)rel * N_EDGES;
  for (int e = threadIdx.x; e < ECH; e += 256) {
    int d = dp[e] - n0;
    if ((unsigned)d < RNG) {
      unsigned pos = atomicAdd(&cur[d], 1u);
      so[pos] = sp[e];
    }
  }
}

// ---------------------------------------------------------------------------
// Fused multi-relation GEMM; epilogue scales by dso and writes bf16 Y.
// ---------------------------------------------------------------------------
template <int REL_COLS, int NRELS>
__global__ __launch_bounds__(256, 4) void k_gemm_fused(
    const float* __restrict__ A, const float* __restrict__ Wbase,
    const float* __restrict__ dsoBase, unsigned short* __restrict__ C, int M) {
  constexpr int NC = REL_COLS * NRELS;  // 256
  __shared__ float At[32][64];
  __shared__ float Wc[32][NC];
  const int tid = threadIdx.x;
  const int rg = tid >> 5;
  const int cg = tid & 31;
  const int rowBase = blockIdx.x * 64;

  float acc[8][8];
#pragma unroll
  for (int i = 0; i < 8; ++i)
#pragma unroll
    for (int j = 0; j < 8; ++j) acc[i][j] = 0.f;

  for (int k0 = 0; k0 < 128; k0 += 32) {
    __syncthreads();
    {
      int i = tid;
#pragma unroll
      for (int rep = 0; rep < 2; ++rep, i += 256) {
        int row = i >> 3, fp = i & 7;
        float4 a = make_float4(0.f, 0.f, 0.f, 0.f);
        int grow = rowBase + row;
        if (grow < M)
          a = *(const float4*)(A + (size_t)grow * 128 + k0 + fp * 4);
        At[fp * 4 + 0][row] = a.x;
        At[fp * 4 + 1][row] = a.y;
        At[fp * 4 + 2][row] = a.z;
        At[fp * 4 + 3][row] = a.w;
      }
    }
    {
#pragma unroll
      for (int rep = 0; rep < 8; ++rep) {
        int i = tid + rep * 256;
        int k = i >> 6;
        int c = (i & 63) << 2;
        int r = c / REL_COLS;
        int cc = c % REL_COLS;
        float4 w = *(const float4*)(Wbase + (size_t)r * 128 * REL_COLS +
                                    (size_t)(k0 + k) * REL_COLS + cc);
        *(float4*)&Wc[k][c] = w;
      }
    }
    __syncthreads();
#pragma unroll 8
    for (int kk = 0; kk < 32; ++kk) {
      float4 a0 = *(const float4*)&At[kk][rg * 8];
      float4 a1 = *(const float4*)&At[kk][rg * 8 + 4];
      float4 w0 = *(const float4*)&Wc[kk][cg * 8];
      float4 w1 = *(const float4*)&Wc[kk][cg * 8 + 4];
      float a[8] = {a0.x, a0.y, a0.z, a0.w, a1.x, a1.y, a1.z, a1.w};
      float w[8] = {w0.x, w0.y, w0.z, w0.w, w1.x, w1.y, w1.z, w1.w};
#pragma unroll
      for (int i = 0; i < 8; ++i)
#pragma unroll
        for (int j = 0; j < 8; ++j) acc[i][j] = fmaf(a[i], w[j], acc[i][j]);
    }
  }
  const int rsel = (cg * 8) / REL_COLS;
  const float* dso = dsoBase + (size_t)rsel * N_NODES;
#pragma unroll
  for (int i = 0; i < 8; ++i) {
    int row = rowBase + rg * 8 + i;
    if (row >= M) break;
    float s = dso[row];
    unsigned short pk[8];
#pragma unroll
    for (int j = 0; j < 8; ++j) pk[j] = f2bf(acc[i][j] * s);
    *(uint4*)(C + (size_t)row * NC + cg * 8) = *(uint4*)pk;
  }
}

// ---------------------------------------------------------------------------
// Gather layer 1: bf16 Y [node][2][128], fp32 accumulate; 4-deep unroll.
// ---------------------------------------------------------------------------
__global__ __launch_bounds__(256) void k_gather1(
    const unsigned short* __restrict__ Y, const int* __restrict__ row_ptr,
    const int* __restrict__ sorted, const float* __restrict__ dsi,
    const float* __restrict__ b1, float* __restrict__ h1, int pass) {
  int wave = threadIdx.x >> 6, lane = threadIdx.x & 63;
  int node = blockIdx.x * 4 + wave;
  if (node >= N_NODES) return;
  const ushort2* Y2 = (const ushort2*)Y;  // [node*2+rp][64] of ushort2
  float2 tot = make_float2(0.f, 0.f);
#pragma unroll
  for (int rp = 0; rp < 2; ++rp) {
    int beg = row_ptr[rp * (N_NODES + 1) + node];
    int end = row_ptr[rp * (N_NODES + 1) + node + 1];
    const int* ss = sorted + (size_t)rp * N_EDGES;
    float ax[4] = {0.f, 0.f, 0.f, 0.f}, ay[4] = {0.f, 0.f, 0.f, 0.f};
    int e = beg;
    for (; e + 3 < end; e += 4) {
#pragma unroll
      for (int u = 0; u < 4; ++u) {
        int s = ss[e + u];
        ushort2 y = Y2[((size_t)s * 2 + rp) * 64 + lane];
        ax[u] += bf2f(y.x);
        ay[u] += bf2f(y.y);
      }
    }
    for (; e < end; ++e) {
      int s = ss[e];
      ushort2 y = Y2[((size_t)s * 2 + rp) * 64 + lane];
      ax[0] += bf2f(y.x);
      ay[0] += bf2f(y.y);
    }
    float w = dsi[rp * N_NODES + node];
    tot.x += (ax[0] + ax[1] + ax[2] + ax[3]) * w;
    tot.y += (ay[0] + ay[1] + ay[2] + ay[3]) * w;
  }
  float2* H = (float2*)h1 + (size_t)node * 64 + lane;
  if (pass == 0) {
    *H = tot;
  } else {
    const float2* B = (const float2*)b1;
    float2 b = make_float2(0.f, 0.f);
#pragma unroll
    for (int r = 0; r < 4; ++r) {
      float2 bb = B[r * 64 + lane];
      b.x += bb.x; b.y += bb.y;
    }
    float2 cur = *H;
    float vx = cur.x + tot.x + b.x;
    float vy = cur.y + tot.y + b.y;
    *H = make_float2(fmaxf(vx, 0.f), fmaxf(vy, 0.f));
  }
}

// ---------------------------------------------------------------------------
// Gather layer 2: bf16 Y [node][4][64], fp32 accumulate; 4-deep unroll.
// ---------------------------------------------------------------------------
__global__ __launch_bounds__(256) void k_gather2(
    const unsigned short* __restrict__ Y, const int* __restrict__ row_ptr,
    const int* __restrict__ sorted, const float* __restrict__ dsi,
    const float* __restrict__ b2, float* __restrict__ out) {
  int wave = threadIdx.x >> 6, lane = threadIdx.x & 63;
  int node = blockIdx.x * 4 + wave;
  if (node >= N_NODES) return;
  float tot = 0.f;
#pragma unroll
  for (int r = 0; r < 4; ++r) {
    int beg = row_ptr[r * (N_NODES + 1) + node];
    int end = row_ptr[r * (N_NODES + 1) + node + 1];
    const int* ss = sorted + (size_t)r * N_EDGES;
    float a[4] = {0.f, 0.f, 0.f, 0.f};
    int e = beg;
    for (; e + 3 < end; e += 4) {
#pragma unroll
      for (int u = 0; u < 4; ++u) {
        int s = ss[e + u];
        a[u] += bf2f(Y[((size_t)s * 4 + r) * 64 + lane]);
      }
    }
    for (; e < end; ++e)
      a[0] += bf2f(Y[((size_t)ss[e] * 4 + r) * 64 + lane]);
    tot += (a[0] + a[1] + a[2] + a[3]) * dsi[r * N_NODES + node];
  }
  float b = b2[lane] + b2[64 + lane] + b2[128 + lane] + b2[192 + lane];
  out[(size_t)node * 64 + lane] = tot + b;
}

extern "C" void kernel_launch(void* const* d_in, const int* in_sizes, int n_in,
                              void* d_out, int out_size, void* d_ws,
                              size_t ws_size, hipStream_t stream) {
  const float* x  = (const float*)d_in[0];
  const int* src  = (const int*)d_in[1];
  const int* dst  = (const int*)d_in[2];
  const float* W1 = (const float*)d_in[3];
  const float* b1 = (const float*)d_in[4];
  const float* W2 = (const float*)d_in[5];
  const float* b2 = (const float*)d_in[6];
  float* out = (float*)d_out;

  // Workspace layout:
  //   [0, 25.6MB)    h1 [50000][128] fp32 -- ALIASED by Hs/Hd (dead before
  //                                          h1's first write in gather1 p0)
  //   [25.6, 51.2MB) Y bf16 [50000][256]
  //   tail: cnt_in(=dsi) | dso | row_ptr | chunkSums | sorted
  char* wsb = (char*)d_ws;
  float* h1 = (float*)wsb;
  unsigned short* Hs = (unsigned short*)wsb;                        // 12.8MB
  unsigned short* Hd = Hs + (size_t)N_REL * EB * N_NODES;           // 12.8MB
  unsigned short* Y = (unsigned short*)(wsb + (size_t)N_NODES * 128 * 4);
  char* tail = wsb + (size_t)N_NODES * 128 * 4 + (size_t)N_NODES * 256 * 2;
  int* cnt_in = (int*)tail;
  float* dso = (float*)(cnt_in + N_REL * N_NODES);
  int* row_ptr = (int*)(dso + N_REL * N_NODES);
  int* chunkSums = row_ptr + N_REL * (N_NODES + 1);
  int* sorted = chunkSums + 256;
  float* dsi = (float*)cnt_in;

  k_hist<<<N_REL * EB * NR, 256, 0, stream>>>(src, dst, Hs, Hd);
  k_reduce<<<(N_REL * N_NODES + 255) / 256, 256, 0, stream>>>(Hs, Hd, cnt_in,
                                                              dso);
  k_chunk_sums<<<N_REL * NCHUNK, 256, 0, stream>>>(cnt_in, chunkSums);
  k_scan_chunks<<<1, 64, 0, stream>>>(chunkSums, row_ptr);
  k_scan_within<<<N_REL * NCHUNK, 256, 0, stream>>>(cnt_in, chunkSums,
                                                    row_ptr);
  k_fill2<<<N_REL * EB * NR, 256, 0, stream>>>(src, dst, Hd, row_ptr, sorted);

  const int gemmGrid = (N_NODES + 63) / 64;
  for (int p = 0; p < 2; ++p) {
    k_gemm_fused<128, 2><<<gemmGrid, 256, 0, stream>>>(
        x, W1 + (size_t)p * 2 * 128 * 128, dso + p * 2 * N_NODES, Y, N_NODES);
    k_gather1<<<(N_NODES + 3) / 4, 256, 0, stream>>>(
        Y, row_ptr + p * 2 * (N_NODES + 1), sorted + (size_t)p * 2 * N_EDGES,
        dsi + p * 2 * N_NODES, b1, h1, p);
  }
  k_gemm_fused<64, 4><<<gemmGrid, 256, 0, stream>>>(h1, W2, dso, Y, N_NODES);
  k_gather2<<<(N_NODES + 3) / 4, 256, 0, stream>>>(Y, row_ptr, sorted, dsi, b2,
                                                   out);
}

// Round 7
// 371.281 us; speedup vs baseline: 12.2920x; 1.1612x over previous
//
#include <hip/hip_runtime.h>
#include <hip/hip_bf16.h>

#define N_NODES 50000
#define N_REL 4
#define N_EDGES 400000
#define CHUNK 1024
#define NCHUNK ((N_NODES + CHUNK - 1) / CHUNK)  // 49

#define EB 32                 // edge chunks per relation
#define ECH (N_EDGES / EB)    // 12500 edges per chunk
#define NR 8                  // node ranges
#define RNG (N_NODES / NR)    // 6250 nodes per range

// bf16 helpers (RNE pack, shift-unpack)
static __device__ inline unsigned short f2bf(float f) {
  unsigned u = __float_as_uint(f);
  unsigned r = (u + 0x7FFFu + ((u >> 16) & 1u)) >> 16;
  return (unsigned short)r;
}
static __device__ inline float bf2f(unsigned short b) {
  return __uint_as_float(((unsigned)b) << 16);
}

// ---------------------------------------------------------------------------
// Atomic-free histograms per (rel, edge-chunk, node-range); packed 16-bit LDS.
// ---------------------------------------------------------------------------
__global__ __launch_bounds__(256) void k_hist(const int* __restrict__ src,
                                              const int* __restrict__ dst,
                                              unsigned short* __restrict__ Hs,
                                              unsigned short* __restrict__ Hd) {
  const int range = blockIdx.x % NR;
  const int chunk = (blockIdx.x / NR) % EB;
  const int rel = blockIdx.x / (NR * EB);
  __shared__ unsigned int ldsS[RNG / 2], ldsD[RNG / 2];
  for (int i = threadIdx.x; i < RNG / 2; i += 256) {
    ldsS[i] = 0u;
    ldsD[i] = 0u;
  }
  __syncthreads();
  const int n0 = range * RNG;
  const int* sp = src + (size_t)rel * N_EDGES + chunk * ECH;
  const int* dp = dst + (size_t)rel * N_EDGES + chunk * ECH;
  for (int e = threadIdx.x; e < ECH; e += 256) {
    int s = sp[e] - n0;
    if ((unsigned)s < RNG) atomicAdd(&ldsS[s >> 1], 1u << ((s & 1) * 16));
    int d = dp[e] - n0;
    if ((unsigned)d < RNG) atomicAdd(&ldsD[d >> 1], 1u << ((d & 1) * 16));
  }
  __syncthreads();
  unsigned int* HsO =
      (unsigned int*)(Hs + ((size_t)rel * EB + chunk) * N_NODES + n0);
  unsigned int* HdO =
      (unsigned int*)(Hd + ((size_t)rel * EB + chunk) * N_NODES + n0);
  for (int i = threadIdx.x; i < RNG / 2; i += 256) {
    HsO[i] = ldsS[i];
    HdO[i] = ldsD[i];
  }
}

// ---------------------------------------------------------------------------
// Per node: dso[r] = rsqrt(out-deg), dsi[r] = rsqrt(in-deg), merged in-degree
// cnt_m, and IN-PLACE exclusive prefix of Hd along the combined (rel,chunk)
// axis (so fill needs one read). All reads coalesced across node axis.
// ---------------------------------------------------------------------------
__global__ __launch_bounds__(256) void k_reduce_m(
    const unsigned short* __restrict__ Hs, unsigned short* __restrict__ Hd,
    int* __restrict__ cnt_m, float* __restrict__ dso,
    float* __restrict__ dsi) {
  int n = blockIdx.x * 256 + threadIdx.x;
  if (n >= N_NODES) return;
#pragma unroll
  for (int r = 0; r < N_REL; ++r) {
    int so = 0;
#pragma unroll
    for (int b = 0; b < EB; ++b) so += Hs[((size_t)r * EB + b) * N_NODES + n];
    dso[r * N_NODES + n] = rsqrtf((float)(so < 1 ? 1 : so));
  }
  int run = 0;
#pragma unroll
  for (int r = 0; r < N_REL; ++r) {
    int start = run;
#pragma unroll
    for (int b = 0; b < EB; ++b) {
      size_t off = ((size_t)r * EB + b) * N_NODES + n;
      int v = Hd[off];
      Hd[off] = (unsigned short)run;  // merged prefix; <= total in-deg, fits
      run += v;
    }
    int di = run - start;
    dsi[r * N_NODES + n] = rsqrtf((float)(di < 1 ? 1 : di));
  }
  cnt_m[n] = run;
}

// ---------------------------------------------------------------------------
// 3-stage exclusive scan of merged counts -> row_ptr_m
// ---------------------------------------------------------------------------
__global__ __launch_bounds__(256) void k_chunk_sums(
    const int* __restrict__ cnt_m, int* __restrict__ chunkSums) {
  int c = blockIdx.x;
  int t = threadIdx.x;
  int base = c * CHUNK + t * 4;
  int s = 0;
#pragma unroll
  for (int j = 0; j < 4; ++j) {
    int n = base + j;
    if (n < N_NODES) s += cnt_m[n];
  }
  __shared__ int lds[256];
  lds[t] = s;
  __syncthreads();
  for (int off = 128; off > 0; off >>= 1) {
    if (t < off) lds[t] += lds[t + off];
    __syncthreads();
  }
  if (t == 0) chunkSums[c] = lds[0];
}

__global__ __launch_bounds__(64) void k_scan_chunks(int* __restrict__ chunkSums,
                                                    int* __restrict__ row_ptr) {
  if (threadIdx.x == 0) {
    int running = 0;
    for (int c = 0; c < NCHUNK; ++c) {
      int v = chunkSums[c];
      chunkSums[c] = running;
      running += v;
    }
    row_ptr[N_NODES] = N_REL * N_EDGES;
  }
}

__global__ __launch_bounds__(256) void k_scan_within(
    const int* __restrict__ cnt_m, const int* __restrict__ chunkOff,
    int* __restrict__ row_ptr) {
  int c = blockIdx.x;
  int t = threadIdx.x;
  int base = c * CHUNK + t * 4;
  int v[4];
#pragma unroll
  for (int j = 0; j < 4; ++j) {
    int n = base + j;
    v[j] = (n < N_NODES) ? cnt_m[n] : 0;
  }
  int total = v[0] + v[1] + v[2] + v[3];
  __shared__ int lds[256];
  lds[t] = total;
  __syncthreads();
  for (int off = 1; off < 256; off <<= 1) {
    int add = (t >= off) ? lds[t - off] : 0;
    __syncthreads();
    lds[t] += add;
    __syncthreads();
  }
  int thrExcl = lds[t] - total + chunkOff[c];
  int pre = 0;
#pragma unroll
  for (int j = 0; j < 4; ++j) {
    int n = base + j;
    if (n < N_NODES) row_ptr[n] = thrExcl + pre;
    pre += v[j];
  }
}

// ---------------------------------------------------------------------------
// Merged fill: sorted_m[row_ptr_m[d] + prefix(rel,chunk,d) + k] = (src<<2)|rel
// ---------------------------------------------------------------------------
__global__ __launch_bounds__(256) void k_fill2m(
    const int* __restrict__ src, const int* __restrict__ dst,
    const unsigned short* __restrict__ Hd, const int* __restrict__ row_ptr,
    int* __restrict__ sorted) {
  const int range = blockIdx.x % NR;
  const int chunk = (blockIdx.x / NR) % EB;
  const int rel = blockIdx.x / (NR * EB);
  __shared__ unsigned int cur[RNG];
  const int n0 = range * RNG;
  const int* rp = row_ptr + n0;
  const unsigned short* pref = Hd + ((size_t)rel * EB + chunk) * N_NODES + n0;
  for (int i = threadIdx.x; i < RNG; i += 256)
    cur[i] = (unsigned)(rp[i] + pref[i]);
  __syncthreads();
  const int* sp = src + (size_t)rel * N_EDGES + chunk * ECH;
  const int* dp = dst + (size_t)rel * N_EDGES + chunk * ECH;
  for (int e = threadIdx.x; e < ECH; e += 256) {
    int d = dp[e] - n0;
    if ((unsigned)d < RNG) {
      unsigned pos = atomicAdd(&cur[d], 1u);
      sorted[pos] = (sp[e] << 2) | rel;
    }
  }
}

// ---------------------------------------------------------------------------
// Fused multi-relation GEMM; epilogue scales by dso, writes bf16 at
// C + row*cstride (cstride in ushorts).
// ---------------------------------------------------------------------------
template <int REL_COLS, int NRELS>
__global__ __launch_bounds__(256, 4) void k_gemm_fused(
    const float* __restrict__ A, const float* __restrict__ Wbase,
    const float* __restrict__ dsoBase, unsigned short* __restrict__ C,
    int cstride, int M) {
  constexpr int NC = REL_COLS * NRELS;  // 256
  __shared__ float At[32][64];
  __shared__ float Wc[32][NC];
  const int tid = threadIdx.x;
  const int rg = tid >> 5;
  const int cg = tid & 31;
  const int rowBase = blockIdx.x * 64;

  float acc[8][8];
#pragma unroll
  for (int i = 0; i < 8; ++i)
#pragma unroll
    for (int j = 0; j < 8; ++j) acc[i][j] = 0.f;

  for (int k0 = 0; k0 < 128; k0 += 32) {
    __syncthreads();
    {
      int i = tid;
#pragma unroll
      for (int rep = 0; rep < 2; ++rep, i += 256) {
        int row = i >> 3, fp = i & 7;
        float4 a = make_float4(0.f, 0.f, 0.f, 0.f);
        int grow = rowBase + row;
        if (grow < M)
          a = *(const float4*)(A + (size_t)grow * 128 + k0 + fp * 4);
        At[fp * 4 + 0][row] = a.x;
        At[fp * 4 + 1][row] = a.y;
        At[fp * 4 + 2][row] = a.z;
        At[fp * 4 + 3][row] = a.w;
      }
    }
    {
#pragma unroll
      for (int rep = 0; rep < 8; ++rep) {
        int i = tid + rep * 256;
        int k = i >> 6;
        int c = (i & 63) << 2;
        int r = c / REL_COLS;
        int cc = c % REL_COLS;
        float4 w = *(const float4*)(Wbase + (size_t)r * 128 * REL_COLS +
                                    (size_t)(k0 + k) * REL_COLS + cc);
        *(float4*)&Wc[k][c] = w;
      }
    }
    __syncthreads();
#pragma unroll 8
    for (int kk = 0; kk < 32; ++kk) {
      float4 a0 = *(const float4*)&At[kk][rg * 8];
      float4 a1 = *(const float4*)&At[kk][rg * 8 + 4];
      float4 w0 = *(const float4*)&Wc[kk][cg * 8];
      float4 w1 = *(const float4*)&Wc[kk][cg * 8 + 4];
      float a[8] = {a0.x, a0.y, a0.z, a0.w, a1.x, a1.y, a1.z, a1.w};
      float w[8] = {w0.x, w0.y, w0.z, w0.w, w1.x, w1.y, w1.z, w1.w};
#pragma unroll
      for (int i = 0; i < 8; ++i)
#pragma unroll
        for (int j = 0; j < 8; ++j) acc[i][j] = fmaf(a[i], w[j], acc[i][j]);
    }
  }
  const int rsel = (cg * 8) / REL_COLS;
  const float* dso = dsoBase + (size_t)rsel * N_NODES;
#pragma unroll
  for (int i = 0; i < 8; ++i) {
    int row = rowBase + rg * 8 + i;
    if (row >= M) break;
    float s = dso[row];
    unsigned short pk[8];
#pragma unroll
    for (int j = 0; j < 8; ++j) pk[j] = f2bf(acc[i][j] * s);
    *(uint4*)(C + (size_t)row * cstride + cg * 8) = *(uint4*)pk;
  }
}

// dsi select by rel bits (uniform across the wave)
static __device__ inline float dsel(int r, float d0, float d1, float d2,
                                    float d3) {
  float lo = (r & 1) ? d1 : d0;
  float hi = (r & 1) ? d3 : d2;
  return (r & 2) ? hi : lo;
}

// ---------------------------------------------------------------------------
// Merged gather layer 1: Y [node][4][128] bf16; one wave per node; batch-64
// index load + shfl broadcast; unroll 8. Writes h1 once (+bias+ReLU).
// ---------------------------------------------------------------------------
__global__ __launch_bounds__(256) void k_gather1m(
    const unsigned short* __restrict__ Y, const int* __restrict__ row_ptr,
    const int* __restrict__ sortedm, const float* __restrict__ dsi,
    const float* __restrict__ b1, float* __restrict__ h1) {
  int wave = threadIdx.x >> 6, lane = threadIdx.x & 63;
  int node = blockIdx.x * 4 + wave;
  if (node >= N_NODES) return;
  int beg = row_ptr[node], end = row_ptr[node + 1];
  float d0 = dsi[node], d1 = dsi[N_NODES + node];
  float d2 = dsi[2 * N_NODES + node], d3 = dsi[3 * N_NODES + node];
  const ushort2* Y2 = (const ushort2*)Y;  // row u -> u*64 ushort2
  float ax[8] = {0, 0, 0, 0, 0, 0, 0, 0}, ay[8] = {0, 0, 0, 0, 0, 0, 0, 0};
  for (int base = beg; base < end; base += 64) {
    int n = end - base;
    if (n > 64) n = 64;
    int my = (lane < n) ? sortedm[base + lane] : 0;
    int j = 0;
    for (; j + 7 < n; j += 8) {
#pragma unroll
      for (int k = 0; k < 8; ++k) {
        int u = __shfl(my, j + k);
        float ds = dsel(u & 3, d0, d1, d2, d3);
        ushort2 y = Y2[(size_t)u * 64 + lane];
        ax[k] = fmaf(bf2f(y.x), ds, ax[k]);
        ay[k] = fmaf(bf2f(y.y), ds, ay[k]);
      }
    }
    for (; j < n; ++j) {
      int u = __shfl(my, j);
      float ds = dsel(u & 3, d0, d1, d2, d3);
      ushort2 y = Y2[(size_t)u * 64 + lane];
      ax[0] = fmaf(bf2f(y.x), ds, ax[0]);
      ay[0] = fmaf(bf2f(y.y), ds, ay[0]);
    }
  }
  float tx = ((ax[0] + ax[1]) + (ax[2] + ax[3])) +
             ((ax[4] + ax[5]) + (ax[6] + ax[7]));
  float ty = ((ay[0] + ay[1]) + (ay[2] + ay[3])) +
             ((ay[4] + ay[5]) + (ay[6] + ay[7]));
  const float2* B = (const float2*)b1;
  float bx = 0.f, by = 0.f;
#pragma unroll
  for (int r = 0; r < 4; ++r) {
    float2 bb = B[r * 64 + lane];
    bx += bb.x;
    by += bb.y;
  }
  float2* H = (float2*)h1 + (size_t)node * 64 + lane;
  *H = make_float2(fmaxf(tx + bx, 0.f), fmaxf(ty + by, 0.f));
}

// ---------------------------------------------------------------------------
// Merged gather layer 2: Y [node][4][64] bf16; + bias; single write.
// ---------------------------------------------------------------------------
__global__ __launch_bounds__(256) void k_gather2m(
    const unsigned short* __restrict__ Y, const int* __restrict__ row_ptr,
    const int* __restrict__ sortedm, const float* __restrict__ dsi,
    const float* __restrict__ b2, float* __restrict__ out) {
  int wave = threadIdx.x >> 6, lane = threadIdx.x & 63;
  int node = blockIdx.x * 4 + wave;
  if (node >= N_NODES) return;
  int beg = row_ptr[node], end = row_ptr[node + 1];
  float d0 = dsi[node], d1 = dsi[N_NODES + node];
  float d2 = dsi[2 * N_NODES + node], d3 = dsi[3 * N_NODES + node];
  float a[8] = {0, 0, 0, 0, 0, 0, 0, 0};
  for (int base = beg; base < end; base += 64) {
    int n = end - base;
    if (n > 64) n = 64;
    int my = (lane < n) ? sortedm[base + lane] : 0;
    int j = 0;
    for (; j + 7 < n; j += 8) {
#pragma unroll
      for (int k = 0; k < 8; ++k) {
        int u = __shfl(my, j + k);
        float ds = dsel(u & 3, d0, d1, d2, d3);
        a[k] = fmaf(bf2f(Y[(size_t)u * 64 + lane]), ds, a[k]);
      }
    }
    for (; j < n; ++j) {
      int u = __shfl(my, j);
      float ds = dsel(u & 3, d0, d1, d2, d3);
      a[0] = fmaf(bf2f(Y[(size_t)u * 64 + lane]), ds, a[0]);
    }
  }
  float tot = ((a[0] + a[1]) + (a[2] + a[3])) + ((a[4] + a[5]) + (a[6] + a[7]));
  float b = b2[lane] + b2[64 + lane] + b2[128 + lane] + b2[192 + lane];
  out[(size_t)node * 64 + lane] = tot + b;
}

extern "C" void kernel_launch(void* const* d_in, const int* in_sizes, int n_in,
                              void* d_out, int out_size, void* d_ws,
                              size_t ws_size, hipStream_t stream) {
  const float* x  = (const float*)d_in[0];
  const int* src  = (const int*)d_in[1];
  const int* dst  = (const int*)d_in[2];
  const float* W1 = (const float*)d_in[3];
  const float* b1 = (const float*)d_in[4];
  const float* W2 = (const float*)d_in[5];
  const float* b2 = (const float*)d_in[6];
  float* out = (float*)d_out;

  // Workspace layout:
  //   [0, 25.6MB)    h1 [50000][128] fp32 -- ALIASED by Hs/Hd (dead before
  //                                          h1's first write in gather1m)
  //   [25.6, 76.8MB) Y bf16: layer1 [50000][4][128]; layer2 [50000][4][64]
  //                  (layer2 aliases the same base; layer1 Y dead by then)
  //   tail: dso | dsi | cnt_m | row_ptr_m | chunkSums | sorted_m
  char* wsb = (char*)d_ws;
  float* h1 = (float*)wsb;
  unsigned short* Hs = (unsigned short*)wsb;                 // 12.8MB
  unsigned short* Hd = Hs + (size_t)N_REL * EB * N_NODES;    // 12.8MB
  unsigned short* Y = (unsigned short*)(wsb + (size_t)N_NODES * 128 * 4);
  char* tail = wsb + (size_t)N_NODES * 128 * 4 + (size_t)N_NODES * 512 * 2;
  float* dso = (float*)tail;                                 // 800KB
  float* dsi = dso + N_REL * N_NODES;                        // 800KB
  int* cnt_m = (int*)(dsi + N_REL * N_NODES);                // 200KB
  int* row_ptr = cnt_m + N_NODES;                            // 200KB
  int* chunkSums = row_ptr + (N_NODES + 1);                  // ~200B
  int* sorted = chunkSums + 64;                              // 6.4MB

  k_hist<<<N_REL * EB * NR, 256, 0, stream>>>(src, dst, Hs, Hd);
  k_reduce_m<<<(N_NODES + 255) / 256, 256, 0, stream>>>(Hs, Hd, cnt_m, dso,
                                                        dsi);
  k_chunk_sums<<<NCHUNK, 256, 0, stream>>>(cnt_m, chunkSums);
  k_scan_chunks<<<1, 64, 0, stream>>>(chunkSums, row_ptr);
  k_scan_within<<<NCHUNK, 256, 0, stream>>>(cnt_m, chunkSums, row_ptr);
  k_fill2m<<<N_REL * EB * NR, 256, 0, stream>>>(src, dst, Hd, row_ptr, sorted);

  const int gemmGrid = (N_NODES + 63) / 64;
  // Layer 1: two relation-pair GEMMs into Y [node][4][128], then ONE gather
  for (int p = 0; p < 2; ++p) {
    k_gemm_fused<128, 2><<<gemmGrid, 256, 0, stream>>>(
        x, W1 + (size_t)p * 2 * 128 * 128, dso + p * 2 * N_NODES,
        Y + p * 256, 512, N_NODES);
  }
  k_gather1m<<<(N_NODES + 3) / 4, 256, 0, stream>>>(Y, row_ptr, sorted, dsi,
                                                    b1, h1);
  // Layer 2: one GEMM into Y [node][4][64], one gather
  k_gemm_fused<64, 4><<<gemmGrid, 256, 0, stream>>>(h1, W2, dso, Y, 256,
                                                    N_NODES);
  k_gather2m<<<(N_NODES + 3) / 4, 256, 0, stream>>>(Y, row_ptr, sorted, dsi,
                                                    b2, out);
}

// Round 8
// 299.308 us; speedup vs baseline: 15.2478x; 1.2405x over previous
//
#include <hip/hip_runtime.h>
#include <hip/hip_bf16.h>

#define N_NODES 50000
#define N_REL 4
#define N_EDGES 400000
#define CHUNK 1024
#define NCHUNK ((N_NODES + CHUNK - 1) / CHUNK)  // 49

#define EB 32                 // edge chunks per relation
#define ECH (N_EDGES / EB)    // 12500 edges per chunk
#define NR 8                  // node ranges
#define RNG (N_NODES / NR)    // 6250 nodes per range

using short8 = __attribute__((ext_vector_type(8))) short;
using f32x4 = __attribute__((ext_vector_type(4))) float;

// bf16 helpers (RNE pack, shift-unpack)
static __device__ inline unsigned short f2bf(float f) {
  unsigned u = __float_as_uint(f);
  unsigned r = (u + 0x7FFFu + ((u >> 16) & 1u)) >> 16;
  return (unsigned short)r;
}
static __device__ inline float bf2f(unsigned short b) {
  return __uint_as_float(((unsigned)b) << 16);
}

// ---------------------------------------------------------------------------
// Atomic-free histograms per (rel, edge-chunk, node-range); packed 16-bit LDS.
// ---------------------------------------------------------------------------
__global__ __launch_bounds__(256) void k_hist(const int* __restrict__ src,
                                              const int* __restrict__ dst,
                                              unsigned short* __restrict__ Hs,
                                              unsigned short* __restrict__ Hd) {
  const int range = blockIdx.x % NR;
  const int chunk = (blockIdx.x / NR) % EB;
  const int rel = blockIdx.x / (NR * EB);
  __shared__ unsigned int ldsS[RNG / 2], ldsD[RNG / 2];
  for (int i = threadIdx.x; i < RNG / 2; i += 256) {
    ldsS[i] = 0u;
    ldsD[i] = 0u;
  }
  __syncthreads();
  const int n0 = range * RNG;
  const int* sp = src + (size_t)rel * N_EDGES + chunk * ECH;
  const int* dp = dst + (size_t)rel * N_EDGES + chunk * ECH;
  for (int e = threadIdx.x; e < ECH; e += 256) {
    int s = sp[e] - n0;
    if ((unsigned)s < RNG) atomicAdd(&ldsS[s >> 1], 1u << ((s & 1) * 16));
    int d = dp[e] - n0;
    if ((unsigned)d < RNG) atomicAdd(&ldsD[d >> 1], 1u << ((d & 1) * 16));
  }
  __syncthreads();
  unsigned int* HsO =
      (unsigned int*)(Hs + ((size_t)rel * EB + chunk) * N_NODES + n0);
  unsigned int* HdO =
      (unsigned int*)(Hd + ((size_t)rel * EB + chunk) * N_NODES + n0);
  for (int i = threadIdx.x; i < RNG / 2; i += 256) {
    HsO[i] = ldsS[i];
    HdO[i] = ldsD[i];
  }
}

// ---------------------------------------------------------------------------
// Per node: dso/dsi rsqrt degrees, merged count, in-place merged prefix of Hd.
// ---------------------------------------------------------------------------
__global__ __launch_bounds__(256) void k_reduce_m(
    const unsigned short* __restrict__ Hs, unsigned short* __restrict__ Hd,
    int* __restrict__ cnt_m, float* __restrict__ dso,
    float* __restrict__ dsi) {
  int n = blockIdx.x * 256 + threadIdx.x;
  if (n >= N_NODES) return;
#pragma unroll
  for (int r = 0; r < N_REL; ++r) {
    int so = 0;
#pragma unroll
    for (int b = 0; b < EB; ++b) so += Hs[((size_t)r * EB + b) * N_NODES + n];
    dso[r * N_NODES + n] = rsqrtf((float)(so < 1 ? 1 : so));
  }
  int run = 0;
#pragma unroll
  for (int r = 0; r < N_REL; ++r) {
    int start = run;
#pragma unroll
    for (int b = 0; b < EB; ++b) {
      size_t off = ((size_t)r * EB + b) * N_NODES + n;
      int v = Hd[off];
      Hd[off] = (unsigned short)run;
      run += v;
    }
    int di = run - start;
    dsi[r * N_NODES + n] = rsqrtf((float)(di < 1 ? 1 : di));
  }
  cnt_m[n] = run;
}

// ---------------------------------------------------------------------------
// 3-stage exclusive scan of merged counts -> row_ptr_m
// ---------------------------------------------------------------------------
__global__ __launch_bounds__(256) void k_chunk_sums(
    const int* __restrict__ cnt_m, int* __restrict__ chunkSums) {
  int c = blockIdx.x;
  int t = threadIdx.x;
  int base = c * CHUNK + t * 4;
  int s = 0;
#pragma unroll
  for (int j = 0; j < 4; ++j) {
    int n = base + j;
    if (n < N_NODES) s += cnt_m[n];
  }
  __shared__ int lds[256];
  lds[t] = s;
  __syncthreads();
  for (int off = 128; off > 0; off >>= 1) {
    if (t < off) lds[t] += lds[t + off];
    __syncthreads();
  }
  if (t == 0) chunkSums[c] = lds[0];
}

__global__ __launch_bounds__(64) void k_scan_chunks(int* __restrict__ chunkSums,
                                                    int* __restrict__ row_ptr) {
  if (threadIdx.x == 0) {
    int running = 0;
    for (int c = 0; c < NCHUNK; ++c) {
      int v = chunkSums[c];
      chunkSums[c] = running;
      running += v;
    }
    row_ptr[N_NODES] = N_REL * N_EDGES;
  }
}

__global__ __launch_bounds__(256) void k_scan_within(
    const int* __restrict__ cnt_m, const int* __restrict__ chunkOff,
    int* __restrict__ row_ptr) {
  int c = blockIdx.x;
  int t = threadIdx.x;
  int base = c * CHUNK + t * 4;
  int v[4];
#pragma unroll
  for (int j = 0; j < 4; ++j) {
    int n = base + j;
    v[j] = (n < N_NODES) ? cnt_m[n] : 0;
  }
  int total = v[0] + v[1] + v[2] + v[3];
  __shared__ int lds[256];
  lds[t] = total;
  __syncthreads();
  for (int off = 1; off < 256; off <<= 1) {
    int add = (t >= off) ? lds[t - off] : 0;
    __syncthreads();
    lds[t] += add;
    __syncthreads();
  }
  int thrExcl = lds[t] - total + chunkOff[c];
  int pre = 0;
#pragma unroll
  for (int j = 0; j < 4; ++j) {
    int n = base + j;
    if (n < N_NODES) row_ptr[n] = thrExcl + pre;
    pre += v[j];
  }
}

// ---------------------------------------------------------------------------
// Merged fill: sorted_m[...] = (src<<2)|rel
// ---------------------------------------------------------------------------
__global__ __launch_bounds__(256) void k_fill2m(
    const int* __restrict__ src, const int* __restrict__ dst,
    const unsigned short* __restrict__ Hd, const int* __restrict__ row_ptr,
    int* __restrict__ sorted) {
  const int range = blockIdx.x % NR;
  const int chunk = (blockIdx.x / NR) % EB;
  const int rel = blockIdx.x / (NR * EB);
  __shared__ unsigned int cur[RNG];
  const int n0 = range * RNG;
  const int* rp = row_ptr + n0;
  const unsigned short* pref = Hd + ((size_t)rel * EB + chunk) * N_NODES + n0;
  for (int i = threadIdx.x; i < RNG; i += 256)
    cur[i] = (unsigned)(rp[i] + pref[i]);
  __syncthreads();
  const int* sp = src + (size_t)rel * N_EDGES + chunk * ECH;
  const int* dp = dst + (size_t)rel * N_EDGES + chunk * ECH;
  for (int e = threadIdx.x; e < ECH; e += 256) {
    int d = dp[e] - n0;
    if ((unsigned)d < RNG) {
      unsigned pos = atomicAdd(&cur[d], 1u);
      sorted[pos] = (sp[e] << 2) | rel;
    }
  }
}

// ---------------------------------------------------------------------------
// Prep: x fp32 -> bf16 (8 elems/thread)
// ---------------------------------------------------------------------------
__global__ __launch_bounds__(256) void k_prep_x(const float* __restrict__ x,
                                                unsigned short* __restrict__ xb) {
  int i = blockIdx.x * 256 + threadIdx.x;
  if (i >= N_NODES * 16) return;  // 800000 groups of 8
  const float4* p = (const float4*)x + (size_t)i * 2;
  float4 v0 = p[0], v1 = p[1];
  unsigned short pk[8] = {f2bf(v0.x), f2bf(v0.y), f2bf(v0.z), f2bf(v0.w),
                          f2bf(v1.x), f2bf(v1.y), f2bf(v1.z), f2bf(v1.w)};
  *(uint4*)(xb + (size_t)i * 8) = *(uint4*)pk;
}

// ---------------------------------------------------------------------------
// Prep: W1/W2 fp32 -> bf16 transposed Wt[col][k].
// Wt1[p][c][k] = W1[p*2 + c>>7][k][c&127]; Wt2[c][k] = W2[c>>6][k][c&63].
// ---------------------------------------------------------------------------
__global__ __launch_bounds__(128) void k_prep_w(const float* __restrict__ W1,
                                                const float* __restrict__ W2,
                                                unsigned short* __restrict__ Wt1,
                                                unsigned short* __restrict__ Wt2) {
  int b = blockIdx.x;   // 0..767
  int k = threadIdx.x;  // 0..127
  if (b < 512) {
    int p = b >> 8, c = b & 255;
    int r = p * 2 + (c >> 7), cc = c & 127;
    Wt1[(size_t)b * 128 + k] = f2bf(W1[(size_t)r * 16384 + k * 128 + cc]);
  } else {
    int c = b - 512;
    int r = c >> 6, cc = c & 63;
    Wt2[(size_t)c * 128 + k] = f2bf(W2[(size_t)r * 8192 + k * 64 + cc]);
  }
}

// ---------------------------------------------------------------------------
// bf16 MFMA GEMM: C[row][col] = bf16((A[row] . Wt[col]) * dso[col/RC][row])
// 64-row tile x 256 cols; 4 waves, each 64 rows x 64 cols via 4x4 MFMA accs.
// LDS: A 16KB + Wt 64KB, XOR-swizzled 16B chunks (kg ^= row&7) -> no bank
// conflicts on stage or ds_read_b128. Fragments per cdna4 Sec.3 mapping.
// ---------------------------------------------------------------------------
template <int REL_COLS>
__global__ __launch_bounds__(256, 2) void k_gemm_mfma(
    const unsigned short* __restrict__ A, const unsigned short* __restrict__ Wt,
    const float* __restrict__ dsoBase, unsigned short* __restrict__ C,
    int cstride, int M) {
  __shared__ unsigned short Alds[64 * 128];
  __shared__ unsigned short Wlds[256 * 128];
  const int tid = threadIdx.x;
  const int wid = tid >> 6, lane = tid & 63;
  const int rowBase = blockIdx.x * 64;

#pragma unroll
  for (int i = 0; i < 4; ++i) {  // A: 64 rows x 16 chunks of 16B
    int cid = tid + i * 256;
    int row = cid >> 4, kg = cid & 15;
    int grow = rowBase + row;
    uint4 v = make_uint4(0, 0, 0, 0);
    if (grow < M) v = *(const uint4*)(A + (size_t)grow * 128 + kg * 8);
    *(uint4*)(Alds + row * 128 + ((kg ^ (row & 7)) * 8)) = v;
  }
#pragma unroll
  for (int i = 0; i < 16; ++i) {  // Wt: 256 rows x 16 chunks
    int cid = tid + i * 256;
    int row = cid >> 4, kg = cid & 15;
    uint4 v = *(const uint4*)(Wt + (size_t)row * 128 + kg * 8);
    *(uint4*)(Wlds + row * 128 + ((kg ^ (row & 7)) * 8)) = v;
  }
  __syncthreads();

  f32x4 acc[4][4];
#pragma unroll
  for (int i = 0; i < 4; ++i)
#pragma unroll
    for (int j = 0; j < 4; ++j) acc[i][j] = (f32x4){0.f, 0.f, 0.f, 0.f};

  const int lrow = lane & 15;
  const int khalf = lane >> 4;
#pragma unroll
  for (int k0 = 0; k0 < 4; ++k0) {
    int kg = k0 * 4 + khalf;  // lane's 8-elem k chunk: k = kg*8..kg*8+7
    short8 a[4], b[4];
#pragma unroll
    for (int i = 0; i < 4; ++i) {
      int row = i * 16 + lrow;
      a[i] = *(const short8*)(Alds + row * 128 + ((kg ^ (row & 7)) * 8));
    }
#pragma unroll
    for (int j = 0; j < 4; ++j) {
      int wrow = wid * 64 + j * 16 + lrow;
      b[j] = *(const short8*)(Wlds + wrow * 128 + ((kg ^ (wrow & 7)) * 8));
    }
#pragma unroll
    for (int i = 0; i < 4; ++i)
#pragma unroll
      for (int j = 0; j < 4; ++j)
        acc[i][j] = __builtin_amdgcn_mfma_f32_16x16x32_bf16(a[i], b[j],
                                                            acc[i][j], 0, 0, 0);
  }

#pragma unroll
  for (int i = 0; i < 4; ++i) {
#pragma unroll
    for (int j = 0; j < 4; ++j) {
      int col = wid * 64 + j * 16 + (lane & 15);
      const float* dsoCol = dsoBase + (size_t)(col / REL_COLS) * N_NODES;
#pragma unroll
      for (int r = 0; r < 4; ++r) {
        int grow = rowBase + i * 16 + (lane >> 4) * 4 + r;
        if (grow < M)
          C[(size_t)grow * cstride + col] = f2bf(acc[i][j][r] * dsoCol[grow]);
      }
    }
  }
}

// dsi select by rel bits (uniform across the wave)
static __device__ inline float dsel(int r, float d0, float d1, float d2,
                                    float d3) {
  float lo = (r & 1) ? d1 : d0;
  float hi = (r & 1) ? d3 : d2;
  return (r & 2) ? hi : lo;
}

// ---------------------------------------------------------------------------
// Merged gather layer 1: Y [node][4][128] bf16 -> h1 bf16 (+bias+ReLU)
// ---------------------------------------------------------------------------
__global__ __launch_bounds__(256) void k_gather1m(
    const unsigned short* __restrict__ Y, const int* __restrict__ row_ptr,
    const int* __restrict__ sortedm, const float* __restrict__ dsi,
    const float* __restrict__ b1, unsigned int* __restrict__ h1) {
  int wave = threadIdx.x >> 6, lane = threadIdx.x & 63;
  int node = blockIdx.x * 4 + wave;
  if (node >= N_NODES) return;
  int beg = row_ptr[node], end = row_ptr[node + 1];
  float d0 = dsi[node], d1 = dsi[N_NODES + node];
  float d2 = dsi[2 * N_NODES + node], d3 = dsi[3 * N_NODES + node];
  const ushort2* Y2 = (const ushort2*)Y;
  float ax[8] = {0, 0, 0, 0, 0, 0, 0, 0}, ay[8] = {0, 0, 0, 0, 0, 0, 0, 0};
  for (int base = beg; base < end; base += 64) {
    int n = end - base;
    if (n > 64) n = 64;
    int my = (lane < n) ? sortedm[base + lane] : 0;
    int j = 0;
    for (; j + 7 < n; j += 8) {
#pragma unroll
      for (int k = 0; k < 8; ++k) {
        int u = __shfl(my, j + k);
        float ds = dsel(u & 3, d0, d1, d2, d3);
        ushort2 y = Y2[(size_t)u * 64 + lane];
        ax[k] = fmaf(bf2f(y.x), ds, ax[k]);
        ay[k] = fmaf(bf2f(y.y), ds, ay[k]);
      }
    }
    for (; j < n; ++j) {
      int u = __shfl(my, j);
      float ds = dsel(u & 3, d0, d1, d2, d3);
      ushort2 y = Y2[(size_t)u * 64 + lane];
      ax[0] = fmaf(bf2f(y.x), ds, ax[0]);
      ay[0] = fmaf(bf2f(y.y), ds, ay[0]);
    }
  }
  float tx = ((ax[0] + ax[1]) + (ax[2] + ax[3])) +
             ((ax[4] + ax[5]) + (ax[6] + ax[7]));
  float ty = ((ay[0] + ay[1]) + (ay[2] + ay[3])) +
             ((ay[4] + ay[5]) + (ay[6] + ay[7]));
  const float2* B = (const float2*)b1;
  float bx = 0.f, by = 0.f;
#pragma unroll
  for (int r = 0; r < 4; ++r) {
    float2 bb = B[r * 64 + lane];
    bx += bb.x;
    by += bb.y;
  }
  unsigned pk = (unsigned)f2bf(fmaxf(tx + bx, 0.f)) |
                ((unsigned)f2bf(fmaxf(ty + by, 0.f)) << 16);
  h1[(size_t)node * 64 + lane] = pk;
}

// ---------------------------------------------------------------------------
// Merged gather layer 2: Y [node][4][64] bf16; + bias; single fp32 write.
// ---------------------------------------------------------------------------
__global__ __launch_bounds__(256) void k_gather2m(
    const unsigned short* __restrict__ Y, const int* __restrict__ row_ptr,
    const int* __restrict__ sortedm, const float* __restrict__ dsi,
    const float* __restrict__ b2, float* __restrict__ out) {
  int wave = threadIdx.x >> 6, lane = threadIdx.x & 63;
  int node = blockIdx.x * 4 + wave;
  if (node >= N_NODES) return;
  int beg = row_ptr[node], end = row_ptr[node + 1];
  float d0 = dsi[node], d1 = dsi[N_NODES + node];
  float d2 = dsi[2 * N_NODES + node], d3 = dsi[3 * N_NODES + node];
  float a[8] = {0, 0, 0, 0, 0, 0, 0, 0};
  for (int base = beg; base < end; base += 64) {
    int n = end - base;
    if (n > 64) n = 64;
    int my = (lane < n) ? sortedm[base + lane] : 0;
    int j = 0;
    for (; j + 7 < n; j += 8) {
#pragma unroll
      for (int k = 0; k < 8; ++k) {
        int u = __shfl(my, j + k);
        float ds = dsel(u & 3, d0, d1, d2, d3);
        a[k] = fmaf(bf2f(Y[(size_t)u * 64 + lane]), ds, a[k]);
      }
    }
    for (; j < n; ++j) {
      int u = __shfl(my, j);
      float ds = dsel(u & 3, d0, d1, d2, d3);
      a[0] = fmaf(bf2f(Y[(size_t)u * 64 + lane]), ds, a[0]);
    }
  }
  float tot = ((a[0] + a[1]) + (a[2] + a[3])) + ((a[4] + a[5]) + (a[6] + a[7]));
  float b = b2[lane] + b2[64 + lane] + b2[128 + lane] + b2[192 + lane];
  out[(size_t)node * 64 + lane] = tot + b;
}

extern "C" void kernel_launch(void* const* d_in, const int* in_sizes, int n_in,
                              void* d_out, int out_size, void* d_ws,
                              size_t ws_size, hipStream_t stream) {
  const float* x  = (const float*)d_in[0];
  const int* src  = (const int*)d_in[1];
  const int* dst  = (const int*)d_in[2];
  const float* W1 = (const float*)d_in[3];
  const float* b1 = (const float*)d_in[4];
  const float* W2 = (const float*)d_in[5];
  const float* b2 = (const float*)d_in[6];
  float* out = (float*)d_out;

  // Workspace layout:
  //   [0, 12.8MB)     h1 bf16 [50000][128] -- aliases Hs (dead after reduce)
  //   [12.8, 25.6MB)  Hd (alive until fill2m)
  //   [25.6, 38.4MB)  xb bf16 [50000][128]
  //   [38.4, 89.6MB)  Y bf16: L1 [50000][4][128]; L2 [50000][4][64] (aliased)
  //   tail: Wt1 | Wt2 | dso | dsi | cnt_m | row_ptr | chunkSums | sorted
  char* wsb = (char*)d_ws;
  unsigned short* Hs = (unsigned short*)wsb;                 // 12.8MB
  unsigned int* h1 = (unsigned int*)wsb;                     // bf16 pairs
  unsigned short* Hd = Hs + (size_t)N_REL * EB * N_NODES;    // 12.8MB
  unsigned short* xb = Hd + (size_t)N_REL * EB * N_NODES;    // 12.8MB
  unsigned short* Y = xb + (size_t)N_NODES * 128;            // 51.2MB
  char* tail = (char*)(Y + (size_t)N_NODES * 512);
  unsigned short* Wt1 = (unsigned short*)tail;               // 128KB
  unsigned short* Wt2 = Wt1 + 512 * 128;                     // 64KB
  float* dso = (float*)(Wt2 + 256 * 128);                    // 800KB
  float* dsi = dso + N_REL * N_NODES;                        // 800KB
  int* cnt_m = (int*)(dsi + N_REL * N_NODES);                // 200KB
  int* row_ptr = cnt_m + N_NODES;                            // 200KB
  int* chunkSums = row_ptr + (N_NODES + 1);                  // ~200B
  int* sorted = chunkSums + 64;                              // 6.4MB

  k_prep_x<<<(N_NODES * 16 + 255) / 256, 256, 0, stream>>>(x, xb);
  k_prep_w<<<768, 128, 0, stream>>>(W1, W2, Wt1, Wt2);
  k_hist<<<N_REL * EB * NR, 256, 0, stream>>>(src, dst, Hs, Hd);
  k_reduce_m<<<(N_NODES + 255) / 256, 256, 0, stream>>>(Hs, Hd, cnt_m, dso,
                                                        dsi);
  k_chunk_sums<<<NCHUNK, 256, 0, stream>>>(cnt_m, chunkSums);
  k_scan_chunks<<<1, 64, 0, stream>>>(chunkSums, row_ptr);
  k_scan_within<<<NCHUNK, 256, 0, stream>>>(cnt_m, chunkSums, row_ptr);
  k_fill2m<<<N_REL * EB * NR, 256, 0, stream>>>(src, dst, Hd, row_ptr, sorted);

  const int gemmGrid = (N_NODES + 63) / 64;
  // Layer 1: two relation-pair MFMA GEMMs into Y [node][4][128]
  for (int p = 0; p < 2; ++p) {
    k_gemm_mfma<128><<<gemmGrid, 256, 0, stream>>>(
        xb, Wt1 + (size_t)p * 256 * 128, dso + p * 2 * N_NODES, Y + p * 256,
        512, N_NODES);
  }
  k_gather1m<<<(N_NODES + 3) / 4, 256, 0, stream>>>(Y, row_ptr, sorted, dsi,
                                                    b1, h1);
  // Layer 2: one MFMA GEMM into Y [node][4][64], one gather
  k_gemm_mfma<64><<<gemmGrid, 256, 0, stream>>>((unsigned short*)h1, Wt2, dso,
                                                Y, 256, N_NODES);
  k_gather2m<<<(N_NODES + 3) / 4, 256, 0, stream>>>(Y, row_ptr, sorted, dsi,
                                                    b2, out);
}

// Round 9
// 295.579 us; speedup vs baseline: 15.4402x; 1.0126x over previous
//
#include <hip/hip_runtime.h>
#include <hip/hip_bf16.h>

#define N_NODES 50000
#define N_REL 4
#define N_EDGES 400000
#define CHUNK 1024
#define NCHUNK ((N_NODES + CHUNK - 1) / CHUNK)  // 49

#define EB 32                 // edge chunks per relation
#define ECH (N_EDGES / EB)    // 12500 edges per chunk
#define NR 8                  // node ranges
#define RNG (N_NODES / NR)    // 6250 nodes per range

using short8 = __attribute__((ext_vector_type(8))) short;
using f32x4 = __attribute__((ext_vector_type(4))) float;

// bf16 helpers (RNE pack, shift-unpack)
static __device__ inline unsigned short f2bf(float f) {
  unsigned u = __float_as_uint(f);
  unsigned r = (u + 0x7FFFu + ((u >> 16) & 1u)) >> 16;
  return (unsigned short)r;
}
static __device__ inline float bf2f(unsigned short b) {
  return __uint_as_float(((unsigned)b) << 16);
}
// fused unpack of a bf16 pair + scaled accumulate (lo needs shift, hi only AND)
static __device__ inline void fma_bf2(unsigned w, float ds, float& a0,
                                      float& a1) {
  float lo = __uint_as_float(w << 16);
  float hi = __uint_as_float(w & 0xffff0000u);
  a0 = fmaf(lo, ds, a0);
  a1 = fmaf(hi, ds, a1);
}

// ---------------------------------------------------------------------------
// Atomic-free histograms per (rel, edge-chunk, node-range); packed 16-bit LDS.
// ---------------------------------------------------------------------------
__global__ __launch_bounds__(256) void k_hist(const int* __restrict__ src,
                                              const int* __restrict__ dst,
                                              unsigned short* __restrict__ Hs,
                                              unsigned short* __restrict__ Hd) {
  const int range = blockIdx.x % NR;
  const int chunk = (blockIdx.x / NR) % EB;
  const int rel = blockIdx.x / (NR * EB);
  __shared__ unsigned int ldsS[RNG / 2], ldsD[RNG / 2];
  for (int i = threadIdx.x; i < RNG / 2; i += 256) {
    ldsS[i] = 0u;
    ldsD[i] = 0u;
  }
  __syncthreads();
  const int n0 = range * RNG;
  const int* sp = src + (size_t)rel * N_EDGES + chunk * ECH;
  const int* dp = dst + (size_t)rel * N_EDGES + chunk * ECH;
  for (int e = threadIdx.x; e < ECH; e += 256) {
    int s = sp[e] - n0;
    if ((unsigned)s < RNG) atomicAdd(&ldsS[s >> 1], 1u << ((s & 1) * 16));
    int d = dp[e] - n0;
    if ((unsigned)d < RNG) atomicAdd(&ldsD[d >> 1], 1u << ((d & 1) * 16));
  }
  __syncthreads();
  unsigned int* HsO =
      (unsigned int*)(Hs + ((size_t)rel * EB + chunk) * N_NODES + n0);
  unsigned int* HdO =
      (unsigned int*)(Hd + ((size_t)rel * EB + chunk) * N_NODES + n0);
  for (int i = threadIdx.x; i < RNG / 2; i += 256) {
    HsO[i] = ldsS[i];
    HdO[i] = ldsD[i];
  }
}

// ---------------------------------------------------------------------------
// Per node: dso/dsi rsqrt degrees, merged count, in-place merged prefix of Hd.
// ---------------------------------------------------------------------------
__global__ __launch_bounds__(256) void k_reduce_m(
    const unsigned short* __restrict__ Hs, unsigned short* __restrict__ Hd,
    int* __restrict__ cnt_m, float* __restrict__ dso,
    float* __restrict__ dsi) {
  int n = blockIdx.x * 256 + threadIdx.x;
  if (n >= N_NODES) return;
#pragma unroll
  for (int r = 0; r < N_REL; ++r) {
    int so = 0;
#pragma unroll
    for (int b = 0; b < EB; ++b) so += Hs[((size_t)r * EB + b) * N_NODES + n];
    dso[r * N_NODES + n] = rsqrtf((float)(so < 1 ? 1 : so));
  }
  int run = 0;
#pragma unroll
  for (int r = 0; r < N_REL; ++r) {
    int start = run;
#pragma unroll
    for (int b = 0; b < EB; ++b) {
      size_t off = ((size_t)r * EB + b) * N_NODES + n;
      int v = Hd[off];
      Hd[off] = (unsigned short)run;
      run += v;
    }
    int di = run - start;
    dsi[r * N_NODES + n] = rsqrtf((float)(di < 1 ? 1 : di));
  }
  cnt_m[n] = run;
}

// ---------------------------------------------------------------------------
// 3-stage exclusive scan of merged counts -> row_ptr_m
// ---------------------------------------------------------------------------
__global__ __launch_bounds__(256) void k_chunk_sums(
    const int* __restrict__ cnt_m, int* __restrict__ chunkSums) {
  int c = blockIdx.x;
  int t = threadIdx.x;
  int base = c * CHUNK + t * 4;
  int s = 0;
#pragma unroll
  for (int j = 0; j < 4; ++j) {
    int n = base + j;
    if (n < N_NODES) s += cnt_m[n];
  }
  __shared__ int lds[256];
  lds[t] = s;
  __syncthreads();
  for (int off = 128; off > 0; off >>= 1) {
    if (t < off) lds[t] += lds[t + off];
    __syncthreads();
  }
  if (t == 0) chunkSums[c] = lds[0];
}

__global__ __launch_bounds__(64) void k_scan_chunks(int* __restrict__ chunkSums,
                                                    int* __restrict__ row_ptr) {
  if (threadIdx.x == 0) {
    int running = 0;
    for (int c = 0; c < NCHUNK; ++c) {
      int v = chunkSums[c];
      chunkSums[c] = running;
      running += v;
    }
    row_ptr[N_NODES] = N_REL * N_EDGES;
  }
}

__global__ __launch_bounds__(256) void k_scan_within(
    const int* __restrict__ cnt_m, const int* __restrict__ chunkOff,
    int* __restrict__ row_ptr) {
  int c = blockIdx.x;
  int t = threadIdx.x;
  int base = c * CHUNK + t * 4;
  int v[4];
#pragma unroll
  for (int j = 0; j < 4; ++j) {
    int n = base + j;
    v[j] = (n < N_NODES) ? cnt_m[n] : 0;
  }
  int total = v[0] + v[1] + v[2] + v[3];
  __shared__ int lds[256];
  lds[t] = total;
  __syncthreads();
  for (int off = 1; off < 256; off <<= 1) {
    int add = (t >= off) ? lds[t - off] : 0;
    __syncthreads();
    lds[t] += add;
    __syncthreads();
  }
  int thrExcl = lds[t] - total + chunkOff[c];
  int pre = 0;
#pragma unroll
  for (int j = 0; j < 4; ++j) {
    int n = base + j;
    if (n < N_NODES) row_ptr[n] = thrExcl + pre;
    pre += v[j];
  }
}

// ---------------------------------------------------------------------------
// Merged fill: sorted_m[...] = (src<<2)|rel
// ---------------------------------------------------------------------------
__global__ __launch_bounds__(256) void k_fill2m(
    const int* __restrict__ src, const int* __restrict__ dst,
    const unsigned short* __restrict__ Hd, const int* __restrict__ row_ptr,
    int* __restrict__ sorted) {
  const int range = blockIdx.x % NR;
  const int chunk = (blockIdx.x / NR) % EB;
  const int rel = blockIdx.x / (NR * EB);
  __shared__ unsigned int cur[RNG];
  const int n0 = range * RNG;
  const int* rp = row_ptr + n0;
  const unsigned short* pref = Hd + ((size_t)rel * EB + chunk) * N_NODES + n0;
  for (int i = threadIdx.x; i < RNG; i += 256)
    cur[i] = (unsigned)(rp[i] + pref[i]);
  __syncthreads();
  const int* sp = src + (size_t)rel * N_EDGES + chunk * ECH;
  const int* dp = dst + (size_t)rel * N_EDGES + chunk * ECH;
  for (int e = threadIdx.x; e < ECH; e += 256) {
    int d = dp[e] - n0;
    if ((unsigned)d < RNG) {
      unsigned pos = atomicAdd(&cur[d], 1u);
      sorted[pos] = (sp[e] << 2) | rel;
    }
  }
}

// ---------------------------------------------------------------------------
// Prep: x fp32 -> bf16 (8 elems/thread)
// ---------------------------------------------------------------------------
__global__ __launch_bounds__(256) void k_prep_x(const float* __restrict__ x,
                                                unsigned short* __restrict__ xb) {
  int i = blockIdx.x * 256 + threadIdx.x;
  if (i >= N_NODES * 16) return;
  const float4* p = (const float4*)x + (size_t)i * 2;
  float4 v0 = p[0], v1 = p[1];
  unsigned short pk[8] = {f2bf(v0.x), f2bf(v0.y), f2bf(v0.z), f2bf(v0.w),
                          f2bf(v1.x), f2bf(v1.y), f2bf(v1.z), f2bf(v1.w)};
  *(uint4*)(xb + (size_t)i * 8) = *(uint4*)pk;
}

// ---------------------------------------------------------------------------
// Prep: W1/W2 fp32 -> bf16 transposed Wt[col][k].
// ---------------------------------------------------------------------------
__global__ __launch_bounds__(128) void k_prep_w(const float* __restrict__ W1,
                                                const float* __restrict__ W2,
                                                unsigned short* __restrict__ Wt1,
                                                unsigned short* __restrict__ Wt2) {
  int b = blockIdx.x;   // 0..767
  int k = threadIdx.x;  // 0..127
  if (b < 512) {
    int p = b >> 8, c = b & 255;
    int r = p * 2 + (c >> 7), cc = c & 127;
    Wt1[(size_t)b * 128 + k] = f2bf(W1[(size_t)r * 16384 + k * 128 + cc]);
  } else {
    int c = b - 512;
    int r = c >> 6, cc = c & 63;
    Wt2[(size_t)c * 128 + k] = f2bf(W2[(size_t)r * 8192 + k * 64 + cc]);
  }
}

// ---------------------------------------------------------------------------
// bf16 MFMA GEMM (blockIdx.y selects the relation-pair for layer 1).
// ---------------------------------------------------------------------------
template <int REL_COLS>
__global__ __launch_bounds__(256, 2) void k_gemm_mfma(
    const unsigned short* __restrict__ A, const unsigned short* __restrict__ Wt,
    const float* __restrict__ dsoBase, unsigned short* __restrict__ C,
    int cstride, int M) {
  __shared__ unsigned short Alds[64 * 128];
  __shared__ unsigned short Wlds[256 * 128];
  const int tid = threadIdx.x;
  const int wid = tid >> 6, lane = tid & 63;
  const int rowBase = blockIdx.x * 64;
  const unsigned short* WtP = Wt + (size_t)blockIdx.y * 256 * 128;
  const float* dsoP = dsoBase + (size_t)blockIdx.y * 2 * N_NODES;
  unsigned short* CP = C + (size_t)blockIdx.y * 256;

#pragma unroll
  for (int i = 0; i < 4; ++i) {  // A: 64 rows x 16 chunks of 16B
    int cid = tid + i * 256;
    int row = cid >> 4, kg = cid & 15;
    int grow = rowBase + row;
    uint4 v = make_uint4(0, 0, 0, 0);
    if (grow < M) v = *(const uint4*)(A + (size_t)grow * 128 + kg * 8);
    *(uint4*)(Alds + row * 128 + ((kg ^ (row & 7)) * 8)) = v;
  }
#pragma unroll
  for (int i = 0; i < 16; ++i) {  // Wt: 256 rows x 16 chunks
    int cid = tid + i * 256;
    int row = cid >> 4, kg = cid & 15;
    uint4 v = *(const uint4*)(WtP + (size_t)row * 128 + kg * 8);
    *(uint4*)(Wlds + row * 128 + ((kg ^ (row & 7)) * 8)) = v;
  }
  __syncthreads();

  f32x4 acc[4][4];
#pragma unroll
  for (int i = 0; i < 4; ++i)
#pragma unroll
    for (int j = 0; j < 4; ++j) acc[i][j] = (f32x4){0.f, 0.f, 0.f, 0.f};

  const int lrow = lane & 15;
  const int khalf = lane >> 4;
#pragma unroll
  for (int k0 = 0; k0 < 4; ++k0) {
    int kg = k0 * 4 + khalf;
    short8 a[4], b[4];
#pragma unroll
    for (int i = 0; i < 4; ++i) {
      int row = i * 16 + lrow;
      a[i] = *(const short8*)(Alds + row * 128 + ((kg ^ (row & 7)) * 8));
    }
#pragma unroll
    for (int j = 0; j < 4; ++j) {
      int wrow = wid * 64 + j * 16 + lrow;
      b[j] = *(const short8*)(Wlds + wrow * 128 + ((kg ^ (wrow & 7)) * 8));
    }
#pragma unroll
    for (int i = 0; i < 4; ++i)
#pragma unroll
      for (int j = 0; j < 4; ++j)
        acc[i][j] = __builtin_amdgcn_mfma_f32_16x16x32_bf16(a[i], b[j],
                                                            acc[i][j], 0, 0, 0);
  }

#pragma unroll
  for (int i = 0; i < 4; ++i) {
#pragma unroll
    for (int j = 0; j < 4; ++j) {
      int col = wid * 64 + j * 16 + (lane & 15);
      const float* dsoCol = dsoP + (size_t)(col / REL_COLS) * N_NODES;
#pragma unroll
      for (int r = 0; r < 4; ++r) {
        int grow = rowBase + i * 16 + (lane >> 4) * 4 + r;
        if (grow < M)
          CP[(size_t)grow * cstride + col] = f2bf(acc[i][j][r] * dsoCol[grow]);
      }
    }
  }
}

// dsi select by rel bits (uniform across the group)
static __device__ inline float dsel(int r, float d0, float d1, float d2,
                                    float d3) {
  float lo = (r & 1) ? d1 : d0;
  float hi = (r & 1) ? d3 : d2;
  return (r & 2) ? hi : lo;
}

// ---------------------------------------------------------------------------
// Merged gather layer 1: Y [node][4][128] bf16 -> h1 bf16 (+bias+ReLU).
// 32 lanes per node (2 nodes/wave); 8 B (4 feats) per lane per edge.
// ---------------------------------------------------------------------------
__global__ __launch_bounds__(256) void k_gather1m(
    const unsigned short* __restrict__ Y, const int* __restrict__ row_ptr,
    const int* __restrict__ sortedm, const float* __restrict__ dsi,
    const float* __restrict__ b1, unsigned int* __restrict__ h1) {
  const int wave = threadIdx.x >> 6, lane = threadIdx.x & 63;
  const int g = lane & 31;                                 // lane in group
  const int node = blockIdx.x * 8 + wave * 2 + (lane >> 5);  // exact: 50000=8*6250
  const int beg = row_ptr[node], end = row_ptr[node + 1];
  const float d0 = dsi[node], d1 = dsi[N_NODES + node];
  const float d2 = dsi[2 * N_NODES + node], d3 = dsi[3 * N_NODES + node];
  float a0[8] = {0, 0, 0, 0, 0, 0, 0, 0}, a1[8] = {0, 0, 0, 0, 0, 0, 0, 0};
  float a2[8] = {0, 0, 0, 0, 0, 0, 0, 0}, a3[8] = {0, 0, 0, 0, 0, 0, 0, 0};
  for (int base = beg; base < end; base += 32) {
    int n = end - base;
    if (n > 32) n = 32;
    int my = (g < n) ? sortedm[base + g] : 0;
    int j = 0;
    for (; j + 7 < n; j += 8) {
#pragma unroll
      for (int k = 0; k < 8; ++k) {
        int u = __shfl(my, j + k, 32);
        float ds = dsel(u & 3, d0, d1, d2, d3);
        uint2 w = *(const uint2*)(Y + (size_t)u * 128 + g * 4);
        fma_bf2(w.x, ds, a0[k], a1[k]);
        fma_bf2(w.y, ds, a2[k], a3[k]);
      }
    }
    for (; j < n; ++j) {
      int u = __shfl(my, j, 32);
      float ds = dsel(u & 3, d0, d1, d2, d3);
      uint2 w = *(const uint2*)(Y + (size_t)u * 128 + g * 4);
      fma_bf2(w.x, ds, a0[0], a1[0]);
      fma_bf2(w.y, ds, a2[0], a3[0]);
    }
  }
  float t0 = ((a0[0] + a0[1]) + (a0[2] + a0[3])) + ((a0[4] + a0[5]) + (a0[6] + a0[7]));
  float t1 = ((a1[0] + a1[1]) + (a1[2] + a1[3])) + ((a1[4] + a1[5]) + (a1[6] + a1[7]));
  float t2 = ((a2[0] + a2[1]) + (a2[2] + a2[3])) + ((a2[4] + a2[5]) + (a2[6] + a2[7]));
  float t3 = ((a3[0] + a3[1]) + (a3[2] + a3[3])) + ((a3[4] + a3[5]) + (a3[6] + a3[7]));
#pragma unroll
  for (int r = 0; r < 4; ++r) {
    float4 bb = *(const float4*)(b1 + r * 128 + g * 4);
    t0 += bb.x;
    t1 += bb.y;
    t2 += bb.z;
    t3 += bb.w;
  }
  uint2 pk;
  pk.x = (unsigned)f2bf(fmaxf(t0, 0.f)) | ((unsigned)f2bf(fmaxf(t1, 0.f)) << 16);
  pk.y = (unsigned)f2bf(fmaxf(t2, 0.f)) | ((unsigned)f2bf(fmaxf(t3, 0.f)) << 16);
  *((uint2*)h1 + (size_t)node * 32 + g) = pk;
}

// ---------------------------------------------------------------------------
// Merged gather layer 2: Y [node][4][64] bf16 -> out fp32 (+bias).
// 16 lanes per node (4 nodes/wave); 8 B (4 feats) per lane per edge.
// ---------------------------------------------------------------------------
__global__ __launch_bounds__(256) void k_gather2m(
    const unsigned short* __restrict__ Y, const int* __restrict__ row_ptr,
    const int* __restrict__ sortedm, const float* __restrict__ dsi,
    const float* __restrict__ b2, float* __restrict__ out) {
  const int wave = threadIdx.x >> 6, lane = threadIdx.x & 63;
  const int g = lane & 15;
  const int node = blockIdx.x * 16 + wave * 4 + (lane >> 4);  // 50000=16*3125
  const int beg = row_ptr[node], end = row_ptr[node + 1];
  const float d0 = dsi[node], d1 = dsi[N_NODES + node];
  const float d2 = dsi[2 * N_NODES + node], d3 = dsi[3 * N_NODES + node];
  float a0[8] = {0, 0, 0, 0, 0, 0, 0, 0}, a1[8] = {0, 0, 0, 0, 0, 0, 0, 0};
  float a2[8] = {0, 0, 0, 0, 0, 0, 0, 0}, a3[8] = {0, 0, 0, 0, 0, 0, 0, 0};
  for (int base = beg; base < end; base += 16) {
    int n = end - base;
    if (n > 16) n = 16;
    int my = (g < n) ? sortedm[base + g] : 0;
    int j = 0;
    for (; j + 7 < n; j += 8) {
#pragma unroll
      for (int k = 0; k < 8; ++k) {
        int u = __shfl(my, j + k, 16);
        float ds = dsel(u & 3, d0, d1, d2, d3);
        uint2 w = *(const uint2*)(Y + (size_t)u * 64 + g * 4);
        fma_bf2(w.x, ds, a0[k], a1[k]);
        fma_bf2(w.y, ds, a2[k], a3[k]);
      }
    }
    for (; j < n; ++j) {
      int u = __shfl(my, j, 16);
      float ds = dsel(u & 3, d0, d1, d2, d3);
      uint2 w = *(const uint2*)(Y + (size_t)u * 64 + g * 4);
      fma_bf2(w.x, ds, a0[0], a1[0]);
      fma_bf2(w.y, ds, a2[0], a3[0]);
    }
  }
  float t0 = ((a0[0] + a0[1]) + (a0[2] + a0[3])) + ((a0[4] + a0[5]) + (a0[6] + a0[7]));
  float t1 = ((a1[0] + a1[1]) + (a1[2] + a1[3])) + ((a1[4] + a1[5]) + (a1[6] + a1[7]));
  float t2 = ((a2[0] + a2[1]) + (a2[2] + a2[3])) + ((a2[4] + a2[5]) + (a2[6] + a2[7]));
  float t3 = ((a3[0] + a3[1]) + (a3[2] + a3[3])) + ((a3[4] + a3[5]) + (a3[6] + a3[7]));
#pragma unroll
  for (int r = 0; r < 4; ++r) {
    float4 bb = *(const float4*)(b2 + r * 64 + g * 4);
    t0 += bb.x;
    t1 += bb.y;
    t2 += bb.z;
    t3 += bb.w;
  }
  *(float4*)(out + (size_t)node * 64 + g * 4) = make_float4(t0, t1, t2, t3);
}

extern "C" void kernel_launch(void* const* d_in, const int* in_sizes, int n_in,
                              void* d_out, int out_size, void* d_ws,
                              size_t ws_size, hipStream_t stream) {
  const float* x  = (const float*)d_in[0];
  const int* src  = (const int*)d_in[1];
  const int* dst  = (const int*)d_in[2];
  const float* W1 = (const float*)d_in[3];
  const float* b1 = (const float*)d_in[4];
  const float* W2 = (const float*)d_in[5];
  const float* b2 = (const float*)d_in[6];
  float* out = (float*)d_out;

  // Workspace layout (same as round 8):
  //   [0, 12.8MB)     h1 bf16 [50000][128] -- aliases Hs (dead after reduce)
  //   [12.8, 25.6MB)  Hd (alive until fill2m)
  //   [25.6, 38.4MB)  xb bf16 [50000][128]
  //   [38.4, 89.6MB)  Y bf16: L1 [50000][4][128]; L2 [50000][4][64] (aliased)
  //   tail: Wt1 | Wt2 | dso | dsi | cnt_m | row_ptr | chunkSums | sorted
  char* wsb = (char*)d_ws;
  unsigned short* Hs = (unsigned short*)wsb;                 // 12.8MB
  unsigned int* h1 = (unsigned int*)wsb;                     // bf16 pairs
  unsigned short* Hd = Hs + (size_t)N_REL * EB * N_NODES;    // 12.8MB
  unsigned short* xb = Hd + (size_t)N_REL * EB * N_NODES;    // 12.8MB
  unsigned short* Y = xb + (size_t)N_NODES * 128;            // 51.2MB
  char* tail = (char*)(Y + (size_t)N_NODES * 512);
  unsigned short* Wt1 = (unsigned short*)tail;               // 128KB
  unsigned short* Wt2 = Wt1 + 512 * 128;                     // 64KB
  float* dso = (float*)(Wt2 + 256 * 128);                    // 800KB
  float* dsi = dso + N_REL * N_NODES;                        // 800KB
  int* cnt_m = (int*)(dsi + N_REL * N_NODES);                // 200KB
  int* row_ptr = cnt_m + N_NODES;                            // 200KB
  int* chunkSums = row_ptr + (N_NODES + 1);                  // ~200B
  int* sorted = chunkSums + 64;                              // 6.4MB

  k_prep_x<<<(N_NODES * 16 + 255) / 256, 256, 0, stream>>>(x, xb);
  k_prep_w<<<768, 128, 0, stream>>>(W1, W2, Wt1, Wt2);
  k_hist<<<N_REL * EB * NR, 256, 0, stream>>>(src, dst, Hs, Hd);
  k_reduce_m<<<(N_NODES + 255) / 256, 256, 0, stream>>>(Hs, Hd, cnt_m, dso,
                                                        dsi);
  k_chunk_sums<<<NCHUNK, 256, 0, stream>>>(cnt_m, chunkSums);
  k_scan_chunks<<<1, 64, 0, stream>>>(chunkSums, row_ptr);
  k_scan_within<<<NCHUNK, 256, 0, stream>>>(cnt_m, chunkSums, row_ptr);
  k_fill2m<<<N_REL * EB * NR, 256, 0, stream>>>(src, dst, Hd, row_ptr, sorted);

  const int gemmGrid = (N_NODES + 63) / 64;
  // Layer 1: both relation-pairs in ONE launch (blockIdx.y = pair)
  k_gemm_mfma<128><<<dim3(gemmGrid, 2), 256, 0, stream>>>(xb, Wt1, dso, Y, 512,
                                                          N_NODES);
  k_gather1m<<<N_NODES / 8, 256, 0, stream>>>(Y, row_ptr, sorted, dsi, b1, h1);
  // Layer 2: one GEMM into Y [node][4][64], one gather
  k_gemm_mfma<64><<<dim3(gemmGrid, 1), 256, 0, stream>>>(
      (unsigned short*)h1, Wt2, dso, Y, 256, N_NODES);
  k_gather2m<<<N_NODES / 16, 256, 0, stream>>>(Y, row_ptr, sorted, dsi, b2,
                                               out);
}

// Round 10
// 275.236 us; speedup vs baseline: 16.5814x; 1.0739x over previous
//
#include <hip/hip_runtime.h>
#include <hip/hip_bf16.h>

#define N_NODES 50000
#define N_REL 4
#define N_EDGES 400000
#define CHUNK 1024
#define NCHUNK ((N_NODES + CHUNK - 1) / CHUNK)  // 49

#define EB 32                 // edge chunks per relation
#define ECH (N_EDGES / EB)    // 12500 edges per chunk
#define NR 8                  // node ranges
#define RNG (N_NODES / NR)    // 6250 nodes per range

using short8 = __attribute__((ext_vector_type(8))) short;
using f32x4 = __attribute__((ext_vector_type(4))) float;

// bf16 helpers (RNE pack, shift-unpack)
static __device__ inline unsigned short f2bf(float f) {
  unsigned u = __float_as_uint(f);
  unsigned r = (u + 0x7FFFu + ((u >> 16) & 1u)) >> 16;
  return (unsigned short)r;
}
static __device__ inline float bf2f(unsigned short b) {
  return __uint_as_float(((unsigned)b) << 16);
}
// fused unpack of a bf16 pair + scaled accumulate
static __device__ inline void fma_bf2(unsigned w, float ds, float& a0,
                                      float& a1) {
  float lo = __uint_as_float(w << 16);
  float hi = __uint_as_float(w & 0xffff0000u);
  a0 = fmaf(lo, ds, a0);
  a1 = fmaf(hi, ds, a1);
}

// ---------------------------------------------------------------------------
// Atomic-free histograms per (rel, edge-chunk, node-range); packed 16-bit LDS.
// ---------------------------------------------------------------------------
__global__ __launch_bounds__(256) void k_hist(const int* __restrict__ src,
                                              const int* __restrict__ dst,
                                              unsigned short* __restrict__ Hs,
                                              unsigned short* __restrict__ Hd) {
  const int range = blockIdx.x % NR;
  const int chunk = (blockIdx.x / NR) % EB;
  const int rel = blockIdx.x / (NR * EB);
  __shared__ unsigned int ldsS[RNG / 2], ldsD[RNG / 2];
  for (int i = threadIdx.x; i < RNG / 2; i += 256) {
    ldsS[i] = 0u;
    ldsD[i] = 0u;
  }
  __syncthreads();
  const int n0 = range * RNG;
  const int* sp = src + (size_t)rel * N_EDGES + chunk * ECH;
  const int* dp = dst + (size_t)rel * N_EDGES + chunk * ECH;
  for (int e = threadIdx.x; e < ECH; e += 256) {
    int s = sp[e] - n0;
    if ((unsigned)s < RNG) atomicAdd(&ldsS[s >> 1], 1u << ((s & 1) * 16));
    int d = dp[e] - n0;
    if ((unsigned)d < RNG) atomicAdd(&ldsD[d >> 1], 1u << ((d & 1) * 16));
  }
  __syncthreads();
  unsigned int* HsO =
      (unsigned int*)(Hs + ((size_t)rel * EB + chunk) * N_NODES + n0);
  unsigned int* HdO =
      (unsigned int*)(Hd + ((size_t)rel * EB + chunk) * N_NODES + n0);
  for (int i = threadIdx.x; i < RNG / 2; i += 256) {
    HsO[i] = ldsS[i];
    HdO[i] = ldsD[i];
  }
}

// ---------------------------------------------------------------------------
// Per node: dso/dsi rsqrt degrees, merged count, in-place merged prefix of Hd,
// and relOff[node][4] = exclusive per-rel start offset within the node's
// merged CSR segment (ushort4).
// ---------------------------------------------------------------------------
__global__ __launch_bounds__(256) void k_reduce_m(
    const unsigned short* __restrict__ Hs, unsigned short* __restrict__ Hd,
    int* __restrict__ cnt_m, float* __restrict__ dso, float* __restrict__ dsi,
    ushort4* __restrict__ relOff) {
  int n = blockIdx.x * 256 + threadIdx.x;
  if (n >= N_NODES) return;
#pragma unroll
  for (int r = 0; r < N_REL; ++r) {
    int so = 0;
#pragma unroll
    for (int b = 0; b < EB; ++b) so += Hs[((size_t)r * EB + b) * N_NODES + n];
    dso[r * N_NODES + n] = rsqrtf((float)(so < 1 ? 1 : so));
  }
  int run = 0;
  unsigned short rs[4];
#pragma unroll
  for (int r = 0; r < N_REL; ++r) {
    rs[r] = (unsigned short)run;
#pragma unroll
    for (int b = 0; b < EB; ++b) {
      size_t off = ((size_t)r * EB + b) * N_NODES + n;
      int v = Hd[off];
      Hd[off] = (unsigned short)run;
      run += v;
    }
    int di = run - rs[r];
    dsi[r * N_NODES + n] = rsqrtf((float)(di < 1 ? 1 : di));
  }
  cnt_m[n] = run;
  relOff[n] = make_ushort4(rs[0], rs[1], rs[2], rs[3]);
}

// ---------------------------------------------------------------------------
// 3-stage exclusive scan of merged counts -> row_ptr_m
// ---------------------------------------------------------------------------
__global__ __launch_bounds__(256) void k_chunk_sums(
    const int* __restrict__ cnt_m, int* __restrict__ chunkSums) {
  int c = blockIdx.x;
  int t = threadIdx.x;
  int base = c * CHUNK + t * 4;
  int s = 0;
#pragma unroll
  for (int j = 0; j < 4; ++j) {
    int n = base + j;
    if (n < N_NODES) s += cnt_m[n];
  }
  __shared__ int lds[256];
  lds[t] = s;
  __syncthreads();
  for (int off = 128; off > 0; off >>= 1) {
    if (t < off) lds[t] += lds[t + off];
    __syncthreads();
  }
  if (t == 0) chunkSums[c] = lds[0];
}

__global__ __launch_bounds__(64) void k_scan_chunks(int* __restrict__ chunkSums,
                                                    int* __restrict__ row_ptr) {
  if (threadIdx.x == 0) {
    int running = 0;
    for (int c = 0; c < NCHUNK; ++c) {
      int v = chunkSums[c];
      chunkSums[c] = running;
      running += v;
    }
    row_ptr[N_NODES] = N_REL * N_EDGES;
  }
}

__global__ __launch_bounds__(256) void k_scan_within(
    const int* __restrict__ cnt_m, const int* __restrict__ chunkOff,
    int* __restrict__ row_ptr) {
  int c = blockIdx.x;
  int t = threadIdx.x;
  int base = c * CHUNK + t * 4;
  int v[4];
#pragma unroll
  for (int j = 0; j < 4; ++j) {
    int n = base + j;
    v[j] = (n < N_NODES) ? cnt_m[n] : 0;
  }
  int total = v[0] + v[1] + v[2] + v[3];
  __shared__ int lds[256];
  lds[t] = total;
  __syncthreads();
  for (int off = 1; off < 256; off <<= 1) {
    int add = (t >= off) ? lds[t - off] : 0;
    __syncthreads();
    lds[t] += add;
    __syncthreads();
  }
  int thrExcl = lds[t] - total + chunkOff[c];
  int pre = 0;
#pragma unroll
  for (int j = 0; j < 4; ++j) {
    int n = base + j;
    if (n < N_NODES) row_ptr[n] = thrExcl + pre;
    pre += v[j];
  }
}

// ---------------------------------------------------------------------------
// Merged fill: sorted_m[...] = src (plain; rel implied by segment)
// ---------------------------------------------------------------------------
__global__ __launch_bounds__(256) void k_fill2m(
    const int* __restrict__ src, const int* __restrict__ dst,
    const unsigned short* __restrict__ Hd, const int* __restrict__ row_ptr,
    int* __restrict__ sorted) {
  const int range = blockIdx.x % NR;
  const int chunk = (blockIdx.x / NR) % EB;
  const int rel = blockIdx.x / (NR * EB);
  __shared__ unsigned int cur[RNG];
  const int n0 = range * RNG;
  const int* rp = row_ptr + n0;
  const unsigned short* pref = Hd + ((size_t)rel * EB + chunk) * N_NODES + n0;
  for (int i = threadIdx.x; i < RNG; i += 256)
    cur[i] = (unsigned)(rp[i] + pref[i]);
  __syncthreads();
  const int* sp = src + (size_t)rel * N_EDGES + chunk * ECH;
  const int* dp = dst + (size_t)rel * N_EDGES + chunk * ECH;
  for (int e = threadIdx.x; e < ECH; e += 256) {
    int d = dp[e] - n0;
    if ((unsigned)d < RNG) {
      unsigned pos = atomicAdd(&cur[d], 1u);
      sorted[pos] = sp[e];
    }
  }
}

// ---------------------------------------------------------------------------
// Prep: x fp32 -> bf16
// ---------------------------------------------------------------------------
__global__ __launch_bounds__(256) void k_prep_x(const float* __restrict__ x,
                                                unsigned short* __restrict__ xb) {
  int i = blockIdx.x * 256 + threadIdx.x;
  if (i >= N_NODES * 16) return;
  const float4* p = (const float4*)x + (size_t)i * 2;
  float4 v0 = p[0], v1 = p[1];
  unsigned short pk[8] = {f2bf(v0.x), f2bf(v0.y), f2bf(v0.z), f2bf(v0.w),
                          f2bf(v1.x), f2bf(v1.y), f2bf(v1.z), f2bf(v1.w)};
  *(uint4*)(xb + (size_t)i * 8) = *(uint4*)pk;
}

// ---------------------------------------------------------------------------
// Prep: Wt1cat[c][k512] (k = r*128+kk -> W1[r][kk][c]),  Wt2[c][k]
// ---------------------------------------------------------------------------
__global__ __launch_bounds__(128) void k_prep_w(const float* __restrict__ W1,
                                                const float* __restrict__ W2,
                                                unsigned short* __restrict__ Wt1,
                                                unsigned short* __restrict__ Wt2) {
  int b = blockIdx.x;   // 0..383
  int kk = threadIdx.x; // 0..127
  if (b < 128) {
    int c = b;
#pragma unroll
    for (int r = 0; r < 4; ++r)
      Wt1[(size_t)c * 512 + r * 128 + kk] =
          f2bf(W1[(size_t)r * 16384 + kk * 128 + c]);
  } else {
    int c = b - 128;  // 0..255
    int r = c >> 6, cc = c & 63;
    Wt2[(size_t)c * 128 + kk] = f2bf(W2[(size_t)r * 8192 + kk * 64 + cc]);
  }
}

// ---------------------------------------------------------------------------
// Aggregate-first layer 1 gather: per node, per rel segment:
//   agg[node][r][:] = dsi_r[node] * sum_e dso_r[s]*x[s]
// 32 lanes/node (2 nodes/wave), 4 feats (uint2) per lane.
// ---------------------------------------------------------------------------
__global__ __launch_bounds__(256) void k_gather1a(
    const unsigned short* __restrict__ xb, const int* __restrict__ row_ptr,
    const ushort4* __restrict__ relOff, const int* __restrict__ sortedm,
    const float* __restrict__ dso, const float* __restrict__ dsi,
    unsigned int* __restrict__ agg) {
  const int wave = threadIdx.x >> 6, lane = threadIdx.x & 63;
  const int g = lane & 31;
  const int node = blockIdx.x * 8 + wave * 2 + (lane >> 5);  // 50000 = 8*6250
  const int rp = row_ptr[node], rp1 = row_ptr[node + 1];
  const ushort4 ro = relOff[node];
  const int beg[4] = {rp + ro.x, rp + ro.y, rp + ro.z, rp + ro.w};
  const int end4[4] = {rp + ro.y, rp + ro.z, rp + ro.w, rp1};
#pragma unroll
  for (int r = 0; r < 4; ++r) {
    const float* dsoR = dso + (size_t)r * N_NODES;
    float a0[4] = {0, 0, 0, 0}, a1[4] = {0, 0, 0, 0};
    float a2[4] = {0, 0, 0, 0}, a3[4] = {0, 0, 0, 0};
    for (int base = beg[r]; base < end4[r]; base += 32) {
      int n = end4[r] - base;
      if (n > 32) n = 32;
      int my = (g < n) ? sortedm[base + g] : 0;
      int j = 0;
      for (; j + 3 < n; j += 4) {
#pragma unroll
        for (int k = 0; k < 4; ++k) {
          int s = __shfl(my, j + k, 32);
          float ds = dsoR[s];
          uint2 w = *(const uint2*)(xb + (size_t)s * 128 + g * 4);
          fma_bf2(w.x, ds, a0[k], a1[k]);
          fma_bf2(w.y, ds, a2[k], a3[k]);
        }
      }
      for (; j < n; ++j) {
        int s = __shfl(my, j, 32);
        float ds = dsoR[s];
        uint2 w = *(const uint2*)(xb + (size_t)s * 128 + g * 4);
        fma_bf2(w.x, ds, a0[0], a1[0]);
        fma_bf2(w.y, ds, a2[0], a3[0]);
      }
    }
    float di = dsi[(size_t)r * N_NODES + node];
    float t0 = ((a0[0] + a0[1]) + (a0[2] + a0[3])) * di;
    float t1 = ((a1[0] + a1[1]) + (a1[2] + a1[3])) * di;
    float t2 = ((a2[0] + a2[1]) + (a2[2] + a2[3])) * di;
    float t3 = ((a3[0] + a3[1]) + (a3[2] + a3[3])) * di;
    uint2 pk;
    pk.x = (unsigned)f2bf(t0) | ((unsigned)f2bf(t1) << 16);
    pk.y = (unsigned)f2bf(t2) | ((unsigned)f2bf(t3) << 16);
    *((uint2*)agg + ((size_t)node * 4 + r) * 32 + g) = pk;
  }
}

// ---------------------------------------------------------------------------
// h1 = relu(agg[50000][512] @ Wt1cat^T + sum_r b1[r])  -> bf16 [50000][128]
// BM=64, BN=128, BK=128, 4 waves each 64x32 (acc[4][2]).
// ---------------------------------------------------------------------------
__global__ __launch_bounds__(256, 2) void k_gemm_h1(
    const unsigned short* __restrict__ agg, const unsigned short* __restrict__ Wt,
    const float* __restrict__ b1, unsigned short* __restrict__ h1, int M) {
  __shared__ unsigned short Alds[64 * 128];
  __shared__ unsigned short Wlds[128 * 128];
  const int tid = threadIdx.x;
  const int wid = tid >> 6, lane = tid & 63;
  const int rowBase = blockIdx.x * 64;
  const int lrow = lane & 15;
  const int quarter = lane >> 4;

  f32x4 acc[4][2];
#pragma unroll
  for (int i = 0; i < 4; ++i)
#pragma unroll
    for (int j = 0; j < 2; ++j) acc[i][j] = (f32x4){0.f, 0.f, 0.f, 0.f};

  for (int k0 = 0; k0 < 4; ++k0) {
    __syncthreads();
#pragma unroll
    for (int it = 0; it < 4; ++it) {  // A: 64 rows x 16 chunks
      int cid = tid + it * 256;
      int row = cid >> 4, kg = cid & 15;
      int grow = rowBase + row;
      uint4 v = make_uint4(0, 0, 0, 0);
      if (grow < M)
        v = *(const uint4*)(agg + (size_t)grow * 512 + k0 * 128 + kg * 8);
      *(uint4*)(Alds + row * 128 + ((kg ^ (row & 7)) * 8)) = v;
    }
#pragma unroll
    for (int it = 0; it < 8; ++it) {  // W: 128 cols x 16 chunks
      int cid = tid + it * 256;
      int c = cid >> 4, kg = cid & 15;
      uint4 v = *(const uint4*)(Wt + (size_t)c * 512 + k0 * 128 + kg * 8);
      *(uint4*)(Wlds + c * 128 + ((kg ^ (c & 7)) * 8)) = v;
    }
    __syncthreads();
#pragma unroll
    for (int kk = 0; kk < 4; ++kk) {
      int kg = kk * 4 + quarter;
      short8 a[4], b[2];
#pragma unroll
      for (int i = 0; i < 4; ++i) {
        int row = i * 16 + lrow;
        a[i] = *(const short8*)(Alds + row * 128 + ((kg ^ (row & 7)) * 8));
      }
#pragma unroll
      for (int j = 0; j < 2; ++j) {
        int c = wid * 32 + j * 16 + lrow;
        b[j] = *(const short8*)(Wlds + c * 128 + ((kg ^ (c & 7)) * 8));
      }
#pragma unroll
      for (int i = 0; i < 4; ++i)
#pragma unroll
        for (int j = 0; j < 2; ++j)
          acc[i][j] = __builtin_amdgcn_mfma_f32_16x16x32_bf16(a[i], b[j],
                                                              acc[i][j], 0, 0, 0);
    }
  }

#pragma unroll
  for (int j = 0; j < 2; ++j) {
    int c = wid * 32 + j * 16 + lrow;
    float bs = b1[c] + b1[128 + c] + b1[256 + c] + b1[384 + c];
#pragma unroll
    for (int i = 0; i < 4; ++i) {
#pragma unroll
      for (int r = 0; r < 4; ++r) {
        int grow = rowBase + i * 16 + quarter * 4 + r;
        if (grow < M)
          h1[(size_t)grow * 128 + c] = f2bf(fmaxf(acc[i][j][r] + bs, 0.f));
      }
    }
  }
}

// ---------------------------------------------------------------------------
// Layer-2 bf16 MFMA GEMM (transform-first): Y2 = (h1 @ Wt2^T)*dso, bf16.
// ---------------------------------------------------------------------------
template <int REL_COLS>
__global__ __launch_bounds__(256, 2) void k_gemm_mfma(
    const unsigned short* __restrict__ A, const unsigned short* __restrict__ Wt,
    const float* __restrict__ dsoBase, unsigned short* __restrict__ C,
    int cstride, int M) {
  __shared__ unsigned short Alds[64 * 128];
  __shared__ unsigned short Wlds[256 * 128];
  const int tid = threadIdx.x;
  const int wid = tid >> 6, lane = tid & 63;
  const int rowBase = blockIdx.x * 64;

#pragma unroll
  for (int i = 0; i < 4; ++i) {
    int cid = tid + i * 256;
    int row = cid >> 4, kg = cid & 15;
    int grow = rowBase + row;
    uint4 v = make_uint4(0, 0, 0, 0);
    if (grow < M) v = *(const uint4*)(A + (size_t)grow * 128 + kg * 8);
    *(uint4*)(Alds + row * 128 + ((kg ^ (row & 7)) * 8)) = v;
  }
#pragma unroll
  for (int i = 0; i < 16; ++i) {
    int cid = tid + i * 256;
    int row = cid >> 4, kg = cid & 15;
    uint4 v = *(const uint4*)(Wt + (size_t)row * 128 + kg * 8);
    *(uint4*)(Wlds + row * 128 + ((kg ^ (row & 7)) * 8)) = v;
  }
  __syncthreads();

  f32x4 acc[4][4];
#pragma unroll
  for (int i = 0; i < 4; ++i)
#pragma unroll
    for (int j = 0; j < 4; ++j) acc[i][j] = (f32x4){0.f, 0.f, 0.f, 0.f};

  const int lrow = lane & 15;
  const int khalf = lane >> 4;
#pragma unroll
  for (int k0 = 0; k0 < 4; ++k0) {
    int kg = k0 * 4 + khalf;
    short8 a[4], b[4];
#pragma unroll
    for (int i = 0; i < 4; ++i) {
      int row = i * 16 + lrow;
      a[i] = *(const short8*)(Alds + row * 128 + ((kg ^ (row & 7)) * 8));
    }
#pragma unroll
    for (int j = 0; j < 4; ++j) {
      int wrow = wid * 64 + j * 16 + lrow;
      b[j] = *(const short8*)(Wlds + wrow * 128 + ((kg ^ (wrow & 7)) * 8));
    }
#pragma unroll
    for (int i = 0; i < 4; ++i)
#pragma unroll
      for (int j = 0; j < 4; ++j)
        acc[i][j] = __builtin_amdgcn_mfma_f32_16x16x32_bf16(a[i], b[j],
                                                            acc[i][j], 0, 0, 0);
  }

#pragma unroll
  for (int i = 0; i < 4; ++i) {
#pragma unroll
    for (int j = 0; j < 4; ++j) {
      int col = wid * 64 + j * 16 + (lane & 15);
      const float* dsoCol = dsoBase + (size_t)(col / REL_COLS) * N_NODES;
#pragma unroll
      for (int r = 0; r < 4; ++r) {
        int grow = rowBase + i * 16 + (lane >> 4) * 4 + r;
        if (grow < M)
          C[(size_t)grow * cstride + col] = f2bf(acc[i][j][r] * dsoCol[grow]);
      }
    }
  }
}

// ---------------------------------------------------------------------------
// Layer-2 gather (per-rel segments): Y2 [node][4][64] bf16 -> out fp32 (+bias)
// 16 lanes/node (4 nodes/wave).
// ---------------------------------------------------------------------------
__global__ __launch_bounds__(256) void k_gather2m(
    const unsigned short* __restrict__ Y, const int* __restrict__ row_ptr,
    const ushort4* __restrict__ relOff, const int* __restrict__ sortedm,
    const float* __restrict__ dsi, const float* __restrict__ b2,
    float* __restrict__ out) {
  const int wave = threadIdx.x >> 6, lane = threadIdx.x & 63;
  const int g = lane & 15;
  const int node = blockIdx.x * 16 + wave * 4 + (lane >> 4);  // 50000=16*3125
  const int rp = row_ptr[node], rp1 = row_ptr[node + 1];
  const ushort4 ro = relOff[node];
  const int beg[4] = {rp + ro.x, rp + ro.y, rp + ro.z, rp + ro.w};
  const int end4[4] = {rp + ro.y, rp + ro.z, rp + ro.w, rp1};
  float t0 = 0.f, t1 = 0.f, t2 = 0.f, t3 = 0.f;
#pragma unroll
  for (int r = 0; r < 4; ++r) {
    float a0[4] = {0, 0, 0, 0}, a1[4] = {0, 0, 0, 0};
    float a2[4] = {0, 0, 0, 0}, a3[4] = {0, 0, 0, 0};
    for (int base = beg[r]; base < end4[r]; base += 16) {
      int n = end4[r] - base;
      if (n > 16) n = 16;
      int my = (g < n) ? sortedm[base + g] : 0;
      int j = 0;
      for (; j + 3 < n; j += 4) {
#pragma unroll
        for (int k = 0; k < 4; ++k) {
          int s = __shfl(my, j + k, 16);
          uint2 w = *(const uint2*)(Y + ((size_t)s * 4 + r) * 64 + g * 4);
          fma_bf2(w.x, 1.f, a0[k], a1[k]);
          fma_bf2(w.y, 1.f, a2[k], a3[k]);
        }
      }
      for (; j < n; ++j) {
        int s = __shfl(my, j, 16);
        uint2 w = *(const uint2*)(Y + ((size_t)s * 4 + r) * 64 + g * 4);
        fma_bf2(w.x, 1.f, a0[0], a1[0]);
        fma_bf2(w.y, 1.f, a2[0], a3[0]);
      }
    }
    float di = dsi[(size_t)r * N_NODES + node];
    t0 = fmaf((a0[0] + a0[1]) + (a0[2] + a0[3]), di, t0);
    t1 = fmaf((a1[0] + a1[1]) + (a1[2] + a1[3]), di, t1);
    t2 = fmaf((a2[0] + a2[1]) + (a2[2] + a2[3]), di, t2);
    t3 = fmaf((a3[0] + a3[1]) + (a3[2] + a3[3]), di, t3);
  }
#pragma unroll
  for (int r = 0; r < 4; ++r) {
    float4 bb = *(const float4*)(b2 + r * 64 + g * 4);
    t0 += bb.x;
    t1 += bb.y;
    t2 += bb.z;
    t3 += bb.w;
  }
  *(float4*)(out + (size_t)node * 64 + g * 4) = make_float4(t0, t1, t2, t3);
}

extern "C" void kernel_launch(void* const* d_in, const int* in_sizes, int n_in,
                              void* d_out, int out_size, void* d_ws,
                              size_t ws_size, hipStream_t stream) {
  const float* x  = (const float*)d_in[0];
  const int* src  = (const int*)d_in[1];
  const int* dst  = (const int*)d_in[2];
  const float* W1 = (const float*)d_in[3];
  const float* b1 = (const float*)d_in[4];
  const float* W2 = (const float*)d_in[5];
  const float* b2 = (const float*)d_in[6];
  float* out = (float*)d_out;

  // Workspace layout:
  //   [0, 12.8MB)     Hs -- aliased by h1 bf16 [50000][128] (Hs dead after
  //                         reduce_m; h1 written by gemm_h1 later)
  //   [12.8, 25.6MB)  Hd (alive until fill2m)
  //   [25.6, 38.4MB)  xb bf16 [50000][128]
  //   [38.4, 89.6MB)  agg bf16 [50000][4][128]; later Y2 [50000][4][64]
  //                   (Y2 aliases agg; agg dead after gemm_h1)
  //   tail: Wt1 | Wt2 | dso | dsi | relOff | cnt_m | row_ptr | chunkSums | sorted
  char* wsb = (char*)d_ws;
  unsigned short* Hs = (unsigned short*)wsb;                 // 12.8MB
  unsigned short* h1 = (unsigned short*)wsb;                 // alias
  unsigned short* Hd = Hs + (size_t)N_REL * EB * N_NODES;    // 12.8MB
  unsigned short* xb = Hd + (size_t)N_REL * EB * N_NODES;    // 12.8MB
  unsigned short* agg = xb + (size_t)N_NODES * 128;          // 51.2MB
  unsigned short* Y2 = agg;                                  // alias
  char* tail = (char*)(agg + (size_t)N_NODES * 512);
  unsigned short* Wt1 = (unsigned short*)tail;               // 128KB
  unsigned short* Wt2 = Wt1 + 128 * 512;                     // 64KB
  float* dso = (float*)(Wt2 + 256 * 128);                    // 800KB
  float* dsi = dso + N_REL * N_NODES;                        // 800KB
  ushort4* relOff = (ushort4*)(dsi + N_REL * N_NODES);       // 400KB
  int* cnt_m = (int*)(relOff + N_NODES);                     // 200KB
  int* row_ptr = cnt_m + N_NODES;                            // 200KB
  int* chunkSums = row_ptr + (N_NODES + 1);                  // ~200B
  int* sorted = chunkSums + 64;                              // 6.4MB

  k_prep_x<<<(N_NODES * 16 + 255) / 256, 256, 0, stream>>>(x, xb);
  k_prep_w<<<384, 128, 0, stream>>>(W1, W2, Wt1, Wt2);
  k_hist<<<N_REL * EB * NR, 256, 0, stream>>>(src, dst, Hs, Hd);
  k_reduce_m<<<(N_NODES + 255) / 256, 256, 0, stream>>>(Hs, Hd, cnt_m, dso,
                                                        dsi, relOff);
  k_chunk_sums<<<NCHUNK, 256, 0, stream>>>(cnt_m, chunkSums);
  k_scan_chunks<<<1, 64, 0, stream>>>(chunkSums, row_ptr);
  k_scan_within<<<NCHUNK, 256, 0, stream>>>(cnt_m, chunkSums, row_ptr);
  k_fill2m<<<N_REL * EB * NR, 256, 0, stream>>>(src, dst, Hd, row_ptr, sorted);

  // Layer 1: aggregate-first gather, then one K=512 MFMA GEMM (+bias+ReLU)
  k_gather1a<<<N_NODES / 8, 256, 0, stream>>>(xb, row_ptr, relOff, sorted, dso,
                                              dsi, (unsigned int*)agg);
  k_gemm_h1<<<(N_NODES + 63) / 64, 256, 0, stream>>>(agg, Wt1, b1, h1,
                                                     N_NODES);
  // Layer 2: transform-first GEMM into Y2 [node][4][64], then gather
  k_gemm_mfma<64><<<(N_NODES + 63) / 64, 256, 0, stream>>>(h1, Wt2, dso, Y2,
                                                           256, N_NODES);
  k_gather2m<<<N_NODES / 16, 256, 0, stream>>>(Y2, row_ptr, relOff, sorted,
                                               dsi, b2, out);
}

// Round 11
// 267.161 us; speedup vs baseline: 17.0826x; 1.0302x over previous
//
#include <hip/hip_runtime.h>
#include <hip/hip_bf16.h>

#define N_NODES 50000
#define N_REL 4
#define N_EDGES 400000
#define CHUNK 1024
#define NCHUNK ((N_NODES + CHUNK - 1) / CHUNK)  // 49

#define EB 32                 // edge chunks per relation
#define ECH (N_EDGES / EB)    // 12500 edges per chunk
#define NR 8                  // node ranges
#define RNG (N_NODES / NR)    // 6250 nodes per range

#define PX_BLOCKS 3125        // prep_x: 50000*16/256
#define PW_BLOCKS 192         // prep_w: 384 half-blocks / 2
#define HIST_BLOCKS (N_REL * EB * NR)

using short8 = __attribute__((ext_vector_type(8))) short;
using f32x4 = __attribute__((ext_vector_type(4))) float;

static __device__ inline unsigned short f2bf(float f) {
  unsigned u = __float_as_uint(f);
  unsigned r = (u + 0x7FFFu + ((u >> 16) & 1u)) >> 16;
  return (unsigned short)r;
}
static __device__ inline float bf2f(unsigned short b) {
  return __uint_as_float(((unsigned)b) << 16);
}
static __device__ inline void fma_bf2(unsigned w, float ds, float& a0,
                                      float& a1) {
  float lo = __uint_as_float(w << 16);
  float hi = __uint_as_float(w & 0xffff0000u);
  a0 = fmaf(lo, ds, a0);
  a1 = fmaf(hi, ds, a1);
}

// ---------------------------------------------------------------------------
// Fused prep: [0,PX) x->bf16 (+zero chunkSums), [PX,PX+PW) W->bf16^T,
// [PX+PW, ...) per-(rel,chunk,range) histograms into packed 16-bit LDS.
// ---------------------------------------------------------------------------
__global__ __launch_bounds__(256) void k_prep_fused(
    const float* __restrict__ x, const float* __restrict__ W1,
    const float* __restrict__ W2, const int* __restrict__ src,
    const int* __restrict__ dst, unsigned short* __restrict__ xb,
    unsigned short* __restrict__ Wt1, unsigned short* __restrict__ Wt2,
    unsigned short* __restrict__ Hs, unsigned short* __restrict__ Hd,
    int* __restrict__ chunkSums) {
  __shared__ unsigned int ldsS[RNG / 2], ldsD[RNG / 2];
  const int b = blockIdx.x;
  const int tid = threadIdx.x;
  if (b < PX_BLOCKS) {
    if (b == 0 && tid < 64) chunkSums[tid] = 0;
    int i = b * 256 + tid;  // 800000 groups of 8
    const float4* p = (const float4*)x + (size_t)i * 2;
    float4 v0 = p[0], v1 = p[1];
    unsigned short pk[8] = {f2bf(v0.x), f2bf(v0.y), f2bf(v0.z), f2bf(v0.w),
                            f2bf(v1.x), f2bf(v1.y), f2bf(v1.z), f2bf(v1.w)};
    *(uint4*)(xb + (size_t)i * 8) = *(uint4*)pk;
    return;
  }
  if (b < PX_BLOCKS + PW_BLOCKS) {
    int ob = (b - PX_BLOCKS) * 2 + (tid >> 7);  // 0..383
    int kk = tid & 127;
    if (ob < 128) {
      int c = ob;
#pragma unroll
      for (int r = 0; r < 4; ++r)
        Wt1[(size_t)c * 512 + r * 128 + kk] =
            f2bf(W1[(size_t)r * 16384 + kk * 128 + c]);
    } else {
      int c = ob - 128;  // 0..255
      int r = c >> 6, cc = c & 63;
      Wt2[(size_t)c * 128 + kk] = f2bf(W2[(size_t)r * 8192 + kk * 64 + cc]);
    }
    return;
  }
  // histogram part
  const int hb = b - PX_BLOCKS - PW_BLOCKS;
  const int range = hb % NR;
  const int chunk = (hb / NR) % EB;
  const int rel = hb / (NR * EB);
  for (int i = tid; i < RNG / 2; i += 256) {
    ldsS[i] = 0u;
    ldsD[i] = 0u;
  }
  __syncthreads();
  const int n0 = range * RNG;
  const int* sp = src + (size_t)rel * N_EDGES + chunk * ECH;
  const int* dp = dst + (size_t)rel * N_EDGES + chunk * ECH;
  for (int e = tid; e < ECH; e += 256) {
    int s = sp[e] - n0;
    if ((unsigned)s < RNG) atomicAdd(&ldsS[s >> 1], 1u << ((s & 1) * 16));
    int d = dp[e] - n0;
    if ((unsigned)d < RNG) atomicAdd(&ldsD[d >> 1], 1u << ((d & 1) * 16));
  }
  __syncthreads();
  unsigned int* HsO =
      (unsigned int*)(Hs + ((size_t)rel * EB + chunk) * N_NODES + n0);
  unsigned int* HdO =
      (unsigned int*)(Hd + ((size_t)rel * EB + chunk) * N_NODES + n0);
  for (int i = tid; i < RNG / 2; i += 256) {
    HsO[i] = ldsS[i];
    HdO[i] = ldsD[i];
  }
}

// ---------------------------------------------------------------------------
// Per node: dso/dsi, merged count, in-place merged prefix of Hd, relOff,
// and fused per-chunk sums (LDS reduce + one atomic per block).
// ---------------------------------------------------------------------------
__global__ __launch_bounds__(256) void k_reduce_m(
    const unsigned short* __restrict__ Hs, unsigned short* __restrict__ Hd,
    int* __restrict__ cnt_m, float* __restrict__ dso, float* __restrict__ dsi,
    ushort4* __restrict__ relOff, int* __restrict__ chunkSums) {
  int n = blockIdx.x * 256 + threadIdx.x;
  int run = 0;
  if (n < N_NODES) {
#pragma unroll
    for (int r = 0; r < N_REL; ++r) {
      int so = 0;
#pragma unroll
      for (int b = 0; b < EB; ++b)
        so += Hs[((size_t)r * EB + b) * N_NODES + n];
      dso[r * N_NODES + n] = rsqrtf((float)(so < 1 ? 1 : so));
    }
    unsigned short rs[4];
#pragma unroll
    for (int r = 0; r < N_REL; ++r) {
      rs[r] = (unsigned short)run;
#pragma unroll
      for (int b = 0; b < EB; ++b) {
        size_t off = ((size_t)r * EB + b) * N_NODES + n;
        int v = Hd[off];
        Hd[off] = (unsigned short)run;
        run += v;
      }
      int di = run - rs[r];
      dsi[r * N_NODES + n] = rsqrtf((float)(di < 1 ? 1 : di));
    }
    cnt_m[n] = run;
    relOff[n] = make_ushort4(rs[0], rs[1], rs[2], rs[3]);
  }
  __shared__ int red[256];
  red[threadIdx.x] = run;
  __syncthreads();
  for (int off = 128; off > 0; off >>= 1) {
    if (threadIdx.x < off) red[threadIdx.x] += red[threadIdx.x + off];
    __syncthreads();
  }
  if (threadIdx.x == 0) atomicAdd(&chunkSums[blockIdx.x >> 2], red[0]);
}

__global__ __launch_bounds__(64) void k_scan_chunks(int* __restrict__ chunkSums,
                                                    int* __restrict__ row_ptr) {
  if (threadIdx.x == 0) {
    int running = 0;
    for (int c = 0; c < NCHUNK; ++c) {
      int v = chunkSums[c];
      chunkSums[c] = running;
      running += v;
    }
    row_ptr[N_NODES] = N_REL * N_EDGES;
  }
}

__global__ __launch_bounds__(256) void k_scan_within(
    const int* __restrict__ cnt_m, const int* __restrict__ chunkOff,
    int* __restrict__ row_ptr) {
  int c = blockIdx.x;
  int t = threadIdx.x;
  int base = c * CHUNK + t * 4;
  int v[4];
#pragma unroll
  for (int j = 0; j < 4; ++j) {
    int n = base + j;
    v[j] = (n < N_NODES) ? cnt_m[n] : 0;
  }
  int total = v[0] + v[1] + v[2] + v[3];
  __shared__ int lds[256];
  lds[t] = total;
  __syncthreads();
  for (int off = 1; off < 256; off <<= 1) {
    int add = (t >= off) ? lds[t - off] : 0;
    __syncthreads();
    lds[t] += add;
    __syncthreads();
  }
  int thrExcl = lds[t] - total + chunkOff[c];
  int pre = 0;
#pragma unroll
  for (int j = 0; j < 4; ++j) {
    int n = base + j;
    if (n < N_NODES) row_ptr[n] = thrExcl + pre;
    pre += v[j];
  }
}

// ---------------------------------------------------------------------------
// Merged fill: sorted_m[...] = src (rel implied by segment position)
// ---------------------------------------------------------------------------
__global__ __launch_bounds__(256) void k_fill2m(
    const int* __restrict__ src, const int* __restrict__ dst,
    const unsigned short* __restrict__ Hd, const int* __restrict__ row_ptr,
    int* __restrict__ sorted) {
  const int range = blockIdx.x % NR;
  const int chunk = (blockIdx.x / NR) % EB;
  const int rel = blockIdx.x / (NR * EB);
  __shared__ unsigned int cur[RNG];
  const int n0 = range * RNG;
  const int* rp = row_ptr + n0;
  const unsigned short* pref = Hd + ((size_t)rel * EB + chunk) * N_NODES + n0;
  for (int i = threadIdx.x; i < RNG; i += 256)
    cur[i] = (unsigned)(rp[i] + pref[i]);
  __syncthreads();
  const int* sp = src + (size_t)rel * N_EDGES + chunk * ECH;
  const int* dp = dst + (size_t)rel * N_EDGES + chunk * ECH;
  for (int e = threadIdx.x; e < ECH; e += 256) {
    int d = dp[e] - n0;
    if ((unsigned)d < RNG) {
      unsigned pos = atomicAdd(&cur[d], 1u);
      sorted[pos] = sp[e];
    }
  }
}

// ---------------------------------------------------------------------------
// Aggregate-first layer-1 gather, merged-window form:
// one 32-wide index load per window, rel tracked by boundary counters,
// compile-time-indexed flush of ILP accumulators into per-rel runsums.
// ---------------------------------------------------------------------------
__global__ __launch_bounds__(256) void k_gather1a(
    const unsigned short* __restrict__ xb, const int* __restrict__ row_ptr,
    const ushort4* __restrict__ relOff, const int* __restrict__ sortedm,
    const float* __restrict__ dso, const float* __restrict__ dsi,
    unsigned int* __restrict__ agg) {
  const int wave = threadIdx.x >> 6, lane = threadIdx.x & 63;
  const int g = lane & 31;
  const int node = blockIdx.x * 8 + wave * 2 + (lane >> 5);  // 50000 = 8*6250
  const int rp = row_ptr[node];
  const int nt = row_ptr[node + 1] - rp;
  const ushort4 ro4 = relOff[node];
  const int rb1 = ro4.y, rb2 = ro4.z, rb3 = ro4.w;

  float rs[4][4];  // [rel][feat] runsums
#pragma unroll
  for (int r = 0; r < 4; ++r)
#pragma unroll
    for (int f = 0; f < 4; ++f) rs[r][f] = 0.f;
  float acc[4][4];  // [feat][ilp]
#pragma unroll
  for (int f = 0; f < 4; ++f)
#pragma unroll
    for (int k = 0; k < 4; ++k) acc[f][k] = 0.f;

#define FLUSH1(RR)                                                     \
  {                                                                    \
    rs[RR][0] += (acc[0][0] + acc[0][1]) + (acc[0][2] + acc[0][3]);    \
    rs[RR][1] += (acc[1][0] + acc[1][1]) + (acc[1][2] + acc[1][3]);    \
    rs[RR][2] += (acc[2][0] + acc[2][1]) + (acc[2][2] + acc[2][3]);    \
    rs[RR][3] += (acc[3][0] + acc[3][1]) + (acc[3][2] + acc[3][3]);    \
    _Pragma("unroll") for (int f = 0; f < 4; ++f)                      \
        _Pragma("unroll") for (int k = 0; k < 4; ++k) acc[f][k] = 0.f; \
  }

  int r = 0;
  int rend = rb1;
  for (int w0 = 0; w0 < nt; w0 += 32) {
    int wn = nt - w0;
    if (wn > 32) wn = 32;
    int my = (g < wn) ? sortedm[rp + w0 + g] : 0;
    int j = 0;
    while (j < wn) {
      while (w0 + j >= rend) {  // advance rel (flushes tail of prev rel)
        switch (r) {
          case 0: FLUSH1(0); break;
          case 1: FLUSH1(1); break;
          default: FLUSH1(2); break;
        }
        ++r;
        rend = (r == 1) ? rb2 : (r == 2) ? rb3 : nt;
      }
      int lim = rend - w0;
      if (lim > wn) lim = wn;
      const float* dsoR = dso + (size_t)r * N_NODES;
      for (; j + 3 < lim; j += 4) {
#pragma unroll
        for (int k = 0; k < 4; ++k) {
          int s = __shfl(my, j + k, 32);
          float ds = dsoR[s];
          uint2 w = *(const uint2*)(xb + (size_t)s * 128 + g * 4);
          fma_bf2(w.x, ds, acc[0][k], acc[1][k]);
          fma_bf2(w.y, ds, acc[2][k], acc[3][k]);
        }
      }
      for (; j < lim; ++j) {
        int s = __shfl(my, j, 32);
        float ds = dsoR[s];
        uint2 w = *(const uint2*)(xb + (size_t)s * 128 + g * 4);
        fma_bf2(w.x, ds, acc[0][0], acc[1][0]);
        fma_bf2(w.y, ds, acc[2][0], acc[3][0]);
      }
    }
  }
  switch (r) {  // final flush (tail of last active rel)
    case 0: FLUSH1(0); break;
    case 1: FLUSH1(1); break;
    case 2: FLUSH1(2); break;
    default: FLUSH1(3); break;
  }
#undef FLUSH1

  float dia[4] = {dsi[node], dsi[N_NODES + node], dsi[2 * N_NODES + node],
                  dsi[3 * N_NODES + node]};
#pragma unroll
  for (int rr = 0; rr < 4; ++rr) {
    float di = dia[rr];
    uint2 pk;
    pk.x = (unsigned)f2bf(rs[rr][0] * di) |
           ((unsigned)f2bf(rs[rr][1] * di) << 16);
    pk.y = (unsigned)f2bf(rs[rr][2] * di) |
           ((unsigned)f2bf(rs[rr][3] * di) << 16);
    *((uint2*)agg + ((size_t)node * 4 + rr) * 32 + g) = pk;
  }
}

// ---------------------------------------------------------------------------
// h1 = relu(agg[50000][512] @ Wt1cat^T + sum_r b1[r]) -> bf16 (unchanged)
// ---------------------------------------------------------------------------
__global__ __launch_bounds__(256, 2) void k_gemm_h1(
    const unsigned short* __restrict__ agg, const unsigned short* __restrict__ Wt,
    const float* __restrict__ b1, unsigned short* __restrict__ h1, int M) {
  __shared__ unsigned short Alds[64 * 128];
  __shared__ unsigned short Wlds[128 * 128];
  const int tid = threadIdx.x;
  const int wid = tid >> 6, lane = tid & 63;
  const int rowBase = blockIdx.x * 64;
  const int lrow = lane & 15;
  const int quarter = lane >> 4;

  f32x4 acc[4][2];
#pragma unroll
  for (int i = 0; i < 4; ++i)
#pragma unroll
    for (int j = 0; j < 2; ++j) acc[i][j] = (f32x4){0.f, 0.f, 0.f, 0.f};

  for (int k0 = 0; k0 < 4; ++k0) {
    __syncthreads();
#pragma unroll
    for (int it = 0; it < 4; ++it) {
      int cid = tid + it * 256;
      int row = cid >> 4, kg = cid & 15;
      int grow = rowBase + row;
      uint4 v = make_uint4(0, 0, 0, 0);
      if (grow < M)
        v = *(const uint4*)(agg + (size_t)grow * 512 + k0 * 128 + kg * 8);
      *(uint4*)(Alds + row * 128 + ((kg ^ (row & 7)) * 8)) = v;
    }
#pragma unroll
    for (int it = 0; it < 8; ++it) {
      int cid = tid + it * 256;
      int c = cid >> 4, kg = cid & 15;
      uint4 v = *(const uint4*)(Wt + (size_t)c * 512 + k0 * 128 + kg * 8);
      *(uint4*)(Wlds + c * 128 + ((kg ^ (c & 7)) * 8)) = v;
    }
    __syncthreads();
#pragma unroll
    for (int kk = 0; kk < 4; ++kk) {
      int kg = kk * 4 + quarter;
      short8 a[4], b[2];
#pragma unroll
      for (int i = 0; i < 4; ++i) {
        int row = i * 16 + lrow;
        a[i] = *(const short8*)(Alds + row * 128 + ((kg ^ (row & 7)) * 8));
      }
#pragma unroll
      for (int j = 0; j < 2; ++j) {
        int c = wid * 32 + j * 16 + lrow;
        b[j] = *(const short8*)(Wlds + c * 128 + ((kg ^ (c & 7)) * 8));
      }
#pragma unroll
      for (int i = 0; i < 4; ++i)
#pragma unroll
        for (int j = 0; j < 2; ++j)
          acc[i][j] = __builtin_amdgcn_mfma_f32_16x16x32_bf16(a[i], b[j],
                                                              acc[i][j], 0, 0, 0);
    }
  }

#pragma unroll
  for (int j = 0; j < 2; ++j) {
    int c = wid * 32 + j * 16 + lrow;
    float bs = b1[c] + b1[128 + c] + b1[256 + c] + b1[384 + c];
#pragma unroll
    for (int i = 0; i < 4; ++i) {
#pragma unroll
      for (int r = 0; r < 4; ++r) {
        int grow = rowBase + i * 16 + quarter * 4 + r;
        if (grow < M)
          h1[(size_t)grow * 128 + c] = f2bf(fmaxf(acc[i][j][r] + bs, 0.f));
      }
    }
  }
}

// ---------------------------------------------------------------------------
// Layer-2 bf16 MFMA GEMM: Y2 = (h1 @ Wt2^T)*dso, bf16 (unchanged)
// ---------------------------------------------------------------------------
template <int REL_COLS>
__global__ __launch_bounds__(256, 2) void k_gemm_mfma(
    const unsigned short* __restrict__ A, const unsigned short* __restrict__ Wt,
    const float* __restrict__ dsoBase, unsigned short* __restrict__ C,
    int cstride, int M) {
  __shared__ unsigned short Alds[64 * 128];
  __shared__ unsigned short Wlds[256 * 128];
  const int tid = threadIdx.x;
  const int wid = tid >> 6, lane = tid & 63;
  const int rowBase = blockIdx.x * 64;

#pragma unroll
  for (int i = 0; i < 4; ++i) {
    int cid = tid + i * 256;
    int row = cid >> 4, kg = cid & 15;
    int grow = rowBase + row;
    uint4 v = make_uint4(0, 0, 0, 0);
    if (grow < M) v = *(const uint4*)(A + (size_t)grow * 128 + kg * 8);
    *(uint4*)(Alds + row * 128 + ((kg ^ (row & 7)) * 8)) = v;
  }
#pragma unroll
  for (int i = 0; i < 16; ++i) {
    int cid = tid + i * 256;
    int row = cid >> 4, kg = cid & 15;
    uint4 v = *(const uint4*)(Wt + (size_t)row * 128 + kg * 8);
    *(uint4*)(Wlds + row * 128 + ((kg ^ (row & 7)) * 8)) = v;
  }
  __syncthreads();

  f32x4 acc[4][4];
#pragma unroll
  for (int i = 0; i < 4; ++i)
#pragma unroll
    for (int j = 0; j < 4; ++j) acc[i][j] = (f32x4){0.f, 0.f, 0.f, 0.f};

  const int lrow = lane & 15;
  const int khalf = lane >> 4;
#pragma unroll
  for (int k0 = 0; k0 < 4; ++k0) {
    int kg = k0 * 4 + khalf;
    short8 a[4], b[4];
#pragma unroll
    for (int i = 0; i < 4; ++i) {
      int row = i * 16 + lrow;
      a[i] = *(const short8*)(Alds + row * 128 + ((kg ^ (row & 7)) * 8));
    }
#pragma unroll
    for (int j = 0; j < 4; ++j) {
      int wrow = wid * 64 + j * 16 + lrow;
      b[j] = *(const short8*)(Wlds + wrow * 128 + ((kg ^ (wrow & 7)) * 8));
    }
#pragma unroll
    for (int i = 0; i < 4; ++i)
#pragma unroll
      for (int j = 0; j < 4; ++j)
        acc[i][j] = __builtin_amdgcn_mfma_f32_16x16x32_bf16(a[i], b[j],
                                                            acc[i][j], 0, 0, 0);
  }

#pragma unroll
  for (int i = 0; i < 4; ++i) {
#pragma unroll
    for (int j = 0; j < 4; ++j) {
      int col = wid * 64 + j * 16 + (lane & 15);
      const float* dsoCol = dsoBase + (size_t)(col / REL_COLS) * N_NODES;
#pragma unroll
      for (int r = 0; r < 4; ++r) {
        int grow = rowBase + i * 16 + (lane >> 4) * 4 + r;
        if (grow < M)
          C[(size_t)grow * cstride + col] = f2bf(acc[i][j][r] * dsoCol[grow]);
      }
    }
  }
}

// ---------------------------------------------------------------------------
// Layer-2 gather, merged-window form: 16 lanes/node, flat runsums
// (t[f] += relSum * dsi_r at each rel flush).
// ---------------------------------------------------------------------------
__global__ __launch_bounds__(256) void k_gather2m(
    const unsigned short* __restrict__ Y, const int* __restrict__ row_ptr,
    const ushort4* __restrict__ relOff, const int* __restrict__ sortedm,
    const float* __restrict__ dsi, const float* __restrict__ b2,
    float* __restrict__ out) {
  const int wave = threadIdx.x >> 6, lane = threadIdx.x & 63;
  const int g = lane & 15;
  const int node = blockIdx.x * 16 + wave * 4 + (lane >> 4);  // 50000=16*3125
  const int rp = row_ptr[node];
  const int nt = row_ptr[node + 1] - rp;
  const ushort4 ro4 = relOff[node];
  const int rb1 = ro4.y, rb2 = ro4.z, rb3 = ro4.w;
  const float dia[4] = {dsi[node], dsi[N_NODES + node],
                        dsi[2 * N_NODES + node], dsi[3 * N_NODES + node]};

  float t[4] = {0.f, 0.f, 0.f, 0.f};
  float acc[4][4];
#pragma unroll
  for (int f = 0; f < 4; ++f)
#pragma unroll
    for (int k = 0; k < 4; ++k) acc[f][k] = 0.f;

#define FLUSH2(RR)                                                          \
  {                                                                         \
    float di = dia[RR];                                                     \
    t[0] = fmaf((acc[0][0] + acc[0][1]) + (acc[0][2] + acc[0][3]), di, t[0]); \
    t[1] = fmaf((acc[1][0] + acc[1][1]) + (acc[1][2] + acc[1][3]), di, t[1]); \
    t[2] = fmaf((acc[2][0] + acc[2][1]) + (acc[2][2] + acc[2][3]), di, t[2]); \
    t[3] = fmaf((acc[3][0] + acc[3][1]) + (acc[3][2] + acc[3][3]), di, t[3]); \
    _Pragma("unroll") for (int f = 0; f < 4; ++f)                           \
        _Pragma("unroll") for (int k = 0; k < 4; ++k) acc[f][k] = 0.f;      \
  }

  int r = 0;
  int rend = rb1;
  for (int w0 = 0; w0 < nt; w0 += 16) {
    int wn = nt - w0;
    if (wn > 16) wn = 16;
    int my = (g < wn) ? sortedm[rp + w0 + g] : 0;
    int j = 0;
    while (j < wn) {
      while (w0 + j >= rend) {
        switch (r) {
          case 0: FLUSH2(0); break;
          case 1: FLUSH2(1); break;
          default: FLUSH2(2); break;
        }
        ++r;
        rend = (r == 1) ? rb2 : (r == 2) ? rb3 : nt;
      }
      int lim = rend - w0;
      if (lim > wn) lim = wn;
      for (; j + 3 < lim; j += 4) {
#pragma unroll
        for (int k = 0; k < 4; ++k) {
          int s = __shfl(my, j + k, 16);
          uint2 w = *(const uint2*)(Y + ((size_t)s * 4 + r) * 64 + g * 4);
          fma_bf2(w.x, 1.f, acc[0][k], acc[1][k]);
          fma_bf2(w.y, 1.f, acc[2][k], acc[3][k]);
        }
      }
      for (; j < lim; ++j) {
        int s = __shfl(my, j, 16);
        uint2 w = *(const uint2*)(Y + ((size_t)s * 4 + r) * 64 + g * 4);
        fma_bf2(w.x, 1.f, acc[0][0], acc[1][0]);
        fma_bf2(w.y, 1.f, acc[2][0], acc[3][0]);
      }
    }
  }
  switch (r) {
    case 0: FLUSH2(0); break;
    case 1: FLUSH2(1); break;
    case 2: FLUSH2(2); break;
    default: FLUSH2(3); break;
  }
#undef FLUSH2

#pragma unroll
  for (int rr = 0; rr < 4; ++rr) {
    float4 bb = *(const float4*)(b2 + rr * 64 + g * 4);
    t[0] += bb.x;
    t[1] += bb.y;
    t[2] += bb.z;
    t[3] += bb.w;
  }
  *(float4*)(out + (size_t)node * 64 + g * 4) =
      make_float4(t[0], t[1], t[2], t[3]);
}

extern "C" void kernel_launch(void* const* d_in, const int* in_sizes, int n_in,
                              void* d_out, int out_size, void* d_ws,
                              size_t ws_size, hipStream_t stream) {
  const float* x  = (const float*)d_in[0];
  const int* src  = (const int*)d_in[1];
  const int* dst  = (const int*)d_in[2];
  const float* W1 = (const float*)d_in[3];
  const float* b1 = (const float*)d_in[4];
  const float* W2 = (const float*)d_in[5];
  const float* b2 = (const float*)d_in[6];
  float* out = (float*)d_out;

  // Workspace layout (same as round 10):
  //   [0, 12.8MB)     Hs -- aliased by h1 bf16 (Hs dead after reduce_m)
  //   [12.8, 25.6MB)  Hd (alive until fill2m)
  //   [25.6, 38.4MB)  xb bf16 [50000][128]
  //   [38.4, 89.6MB)  agg bf16 [50000][4][128]; later Y2 [50000][4][64] alias
  //   tail: Wt1 | Wt2 | dso | dsi | relOff | cnt_m | row_ptr | chunkSums | sorted
  char* wsb = (char*)d_ws;
  unsigned short* Hs = (unsigned short*)wsb;                 // 12.8MB
  unsigned short* h1 = (unsigned short*)wsb;                 // alias
  unsigned short* Hd = Hs + (size_t)N_REL * EB * N_NODES;    // 12.8MB
  unsigned short* xb = Hd + (size_t)N_REL * EB * N_NODES;    // 12.8MB
  unsigned short* agg = xb + (size_t)N_NODES * 128;          // 51.2MB
  unsigned short* Y2 = agg;                                  // alias
  char* tail = (char*)(agg + (size_t)N_NODES * 512);
  unsigned short* Wt1 = (unsigned short*)tail;               // 128KB
  unsigned short* Wt2 = Wt1 + 128 * 512;                     // 64KB
  float* dso = (float*)(Wt2 + 256 * 128);                    // 800KB
  float* dsi = dso + N_REL * N_NODES;                        // 800KB
  ushort4* relOff = (ushort4*)(dsi + N_REL * N_NODES);       // 400KB
  int* cnt_m = (int*)(relOff + N_NODES);                     // 200KB
  int* row_ptr = cnt_m + N_NODES;                            // 200KB
  int* chunkSums = row_ptr + (N_NODES + 1);                  // ~256B
  int* sorted = chunkSums + 64;                              // 6.4MB

  k_prep_fused<<<PX_BLOCKS + PW_BLOCKS + HIST_BLOCKS, 256, 0, stream>>>(
      x, W1, W2, src, dst, xb, Wt1, Wt2, Hs, Hd, chunkSums);
  k_reduce_m<<<(N_NODES + 255) / 256, 256, 0, stream>>>(Hs, Hd, cnt_m, dso,
                                                        dsi, relOff, chunkSums);
  k_scan_chunks<<<1, 64, 0, stream>>>(chunkSums, row_ptr);
  k_scan_within<<<NCHUNK, 256, 0, stream>>>(cnt_m, chunkSums, row_ptr);
  k_fill2m<<<N_REL * EB * NR, 256, 0, stream>>>(src, dst, Hd, row_ptr, sorted);

  // Layer 1: aggregate-first gather, then one K=512 MFMA GEMM (+bias+ReLU)
  k_gather1a<<<N_NODES / 8, 256, 0, stream>>>(xb, row_ptr, relOff, sorted, dso,
                                              dsi, (unsigned int*)agg);
  k_gemm_h1<<<(N_NODES + 63) / 64, 256, 0, stream>>>(agg, Wt1, b1, h1,
                                                     N_NODES);
  // Layer 2: transform-first GEMM into Y2 [node][4][64], then gather
  k_gemm_mfma<64><<<(N_NODES + 63) / 64, 256, 0, stream>>>(h1, Wt2, dso, Y2,
                                                           256, N_NODES);
  k_gather2m<<<N_NODES / 16, 256, 0, stream>>>(Y2, row_ptr, relOff, sorted,
                                               dsi, b2, out);
}